// Round 7
// baseline (1444.183 us; speedup 1.0000x reference)
//
#include <hip/hip_runtime.h>

#define DEVINL __device__ __forceinline__

typedef __attribute__((ext_vector_type(8))) short bf16x8;
typedef __attribute__((ext_vector_type(8))) unsigned short u16x8;
typedef __attribute__((ext_vector_type(4))) float f32x4;

// RNE f32 -> bf16 bits (no NaN handling needed for this workload)
DEVINL unsigned short f2bh(float f){
  unsigned u = __float_as_uint(f);
  return (unsigned short)((u + 0x7FFFu + ((u >> 16) & 1u)) >> 16);
}
DEVINL float bh2f(unsigned short h){ return __uint_as_float(((unsigned)h) << 16); }

// Wave64 max-reduce of a u64 key via DPP (VALU latency, no DS pipe).
DEVINL unsigned long long dpp_max_u64(unsigned long long k) {
#define DPP_STEP(ctrl)                                                        \
  {                                                                           \
    int hi = (int)(k >> 32), lo = (int)(unsigned)k;                           \
    int oh = __builtin_amdgcn_update_dpp(0, hi, ctrl, 0xF, 0xF, 1);           \
    int ol = __builtin_amdgcn_update_dpp(0, lo, ctrl, 0xF, 0xF, 1);           \
    unsigned long long ok =                                                   \
        ((unsigned long long)(unsigned)oh << 32) | (unsigned)ol;              \
    if (ok > k) k = ok;                                                       \
  }
  DPP_STEP(0x111)  // row_shr:1
  DPP_STEP(0x112)  // row_shr:2
  DPP_STEP(0x114)  // row_shr:4
  DPP_STEP(0x118)  // row_shr:8
  DPP_STEP(0x142)  // row_bcast:15
  DPP_STEP(0x143)  // row_bcast:31
#undef DPP_STEP
  return k;
}

// ---------------------------------------------------------------- FPS
// R4-proven per-batch body (293 us @ NT=256). This round: NB independent
// batches interleaved per block (ILP hides the serial per-step chain of one
// batch under the other's instructions; one barrier serves both).
// Distance arithmetic and tie-break bit-identical to the verified r1 version.
template<int N, int NP, int NT, int NB>
__global__ __launch_bounds__(NT) void fps_kernel(const float* __restrict__ xyz,
                                                 float* __restrict__ nxyz) {
  constexpr int PTS = N / NT;
  constexpr int NW = NT / 64;
  const int b0 = blockIdx.x * NB, t = threadIdx.x;
  __shared__ float xs[NB][N], ys[NB][N], zs[NB][N];
  __shared__ int farr[NB][NP];
  __shared__ unsigned long long sk[2][NB][(NW > 1 ? NW : 1)];
  float px[NB][PTS], py[NB][PTS], pz[NB][PTS], dst[NB][PTS];
#pragma unroll
  for (int nb = 0; nb < NB; ++nb) {
    const float* base = xyz + (size_t)(b0 + nb) * N * 3;
#pragma unroll
    for (int j = 0; j < PTS; ++j) {
      int i = t + j * NT;
      float x = base[i * 3 + 0], y = base[i * 3 + 1], z = base[i * 3 + 2];
      px[nb][j] = x; py[nb][j] = y; pz[nb][j] = z;
      xs[nb][i] = x; ys[nb][i] = y; zs[nb][i] = z;
      dst[nb][j] = 1e10f;
    }
  }
  __syncthreads();
  int far[NB];
#pragma unroll
  for (int nb = 0; nb < NB; ++nb) far[nb] = 0;
  const int wv = t >> 6, ln = t & 63;
  for (int s = 0; s < NP; ++s) {
    float cx[NB], cy[NB], cz[NB];
#pragma unroll
    for (int nb = 0; nb < NB; ++nb) {
      cx[nb] = xs[nb][far[nb]]; cy[nb] = ys[nb][far[nb]]; cz[nb] = zs[nb][far[nb]];
    }
    if (t == 0) {
#pragma unroll
      for (int nb = 0; nb < NB; ++nb) farr[nb][s] = far[nb];
    }
    unsigned long long key[NB];
#pragma unroll
    for (int nb = 0; nb < NB; ++nb) {
      float bv = -1.f; int bj = 0;
#pragma unroll
      for (int j = 0; j < PTS; ++j) {
        // no-fma, left-to-right: matches numpy elementwise + sum order
        float dx = __fsub_rn(px[nb][j], cx[nb]);
        float dy = __fsub_rn(py[nb][j], cy[nb]);
        float dz = __fsub_rn(pz[nb][j], cz[nb]);
        float d = __fadd_rn(__fadd_rn(__fmul_rn(dx, dx), __fmul_rn(dy, dy)), __fmul_rn(dz, dz));
        float nd = fminf(dst[nb][j], d);
        dst[nb][j] = nd;
        if (nd > bv) { bv = nd; bj = j; }  // strict >: first max kept per thread
      }
      int bi = t + bj * NT;
      // pack: max key == max dist, tie -> larger ~idx == smaller idx
      key[nb] = ((unsigned long long)__float_as_uint(bv) << 32) | (unsigned)(~bi);
    }
#pragma unroll
    for (int nb = 0; nb < NB; ++nb) key[nb] = dpp_max_u64(key[nb]);
    if constexpr (NW == 1) {
#pragma unroll
      for (int nb = 0; nb < NB; ++nb) {
        int rl = __builtin_amdgcn_readlane((int)(unsigned)key[nb], 63);
        far[nb] = (int)(~(unsigned)rl);
      }
    } else {
      const int p = s & 1;
      if (ln == 63) {
#pragma unroll
        for (int nb = 0; nb < NB; ++nb) sk[p][nb][wv] = key[nb];
      }
      __syncthreads();
#pragma unroll
      for (int nb = 0; nb < NB; ++nb) {
        unsigned long long m = sk[p][nb][0];
#pragma unroll
        for (int q = 1; q < NW; ++q) {
          unsigned long long qk = sk[p][nb][q];
          if (qk > m) m = qk;
        }
        far[nb] = (int)(~(unsigned)m);
      }
    }
  }
  __syncthreads();
  for (int u = t; u < NB * NP; u += NT) {
    int nb = u / NP, s2 = u - nb * NP;
    int fi = farr[nb][s2];
    float* o = nxyz + ((size_t)(b0 + nb) * NP + s2) * 3;
    o[0] = xs[nb][fi]; o[1] = ys[nb][fi]; o[2] = zs[nb][fi];
  }
}

// ---------------------------------------------------------------- ball query (unchanged)
template<int N, int NS>
__global__ __launch_bounds__(256) void bq_kernel(const float* __restrict__ pts,
                                                 const float* __restrict__ centers,
                                                 int* __restrict__ gidx, int Q, float r2) {
  const int wv = threadIdx.x >> 6, ln = threadIdx.x & 63;
  const int g = blockIdx.x * 4 + wv;
  const int b = g / Q, q = g % Q;
  const float* pb = pts + (size_t)b * N * 3;
  const float* c = centers + ((size_t)b * Q + q) * 3;
  const float cx = c[0], cy = c[1], cz = c[2];
  __shared__ int gbuf[4][NS];
  int taken = 0;
  for (int base = 0; base < N; base += 64) {
    if (taken >= NS) break;
    int i = base + ln;
    float dx = __fsub_rn(pb[i * 3 + 0], cx), dy = __fsub_rn(pb[i * 3 + 1], cy),
          dz = __fsub_rn(pb[i * 3 + 2], cz);
    float d = __fadd_rn(__fadd_rn(__fmul_rn(dx, dx), __fmul_rn(dy, dy)), __fmul_rn(dz, dz));
    bool in = (d <= r2);
    unsigned long long mk = __ballot(in);
    int rank = __popcll(mk & ((1ull << ln) - 1ull));
    int pos = taken + rank;
    if (in && pos < NS) gbuf[wv][pos] = i;
    taken += (int)__popcll(mk);
  }
  int total = taken < NS ? taken : NS;
  int first = gbuf[wv][0];
  int* out = gidx + ((size_t)b * Q + q) * NS;
  for (int j = ln; j < NS; j += 64) out[j] = (j < total) ? gbuf[wv][j] : first;
}

// ---------------------------------------------------------------- weight prep (all 8 matrices, one launch)
struct WPEnt { const float* W; unsigned short* hi; unsigned short* lo; int K, N, row0, beg, end; };
struct WPTab { WPEnt e[8]; };
__global__ __launch_bounds__(256) void wprep8_kernel(WPTab tab) {
  int idx = blockIdx.x * 256 + threadIdx.x;
#pragma unroll
  for (int i = 0; i < 8; ++i) {
    const WPEnt& E = tab.e[i];
    if (idx >= E.beg && idx < E.end) {
      int local = idx - E.beg;
      int k = local / E.N, n = local - k * E.N;
      float v = E.W[(size_t)(E.row0 + k) * E.N + n];
      unsigned short h = f2bh(v);
      E.hi[(size_t)n * E.K + k] = h;
      E.lo[(size_t)n * E.K + k] = f2bh(v - bh2f(h));
    }
  }
}

// ---------------------------------------------------------------- split-bf16 MFMA layer, W frags direct from global
// A (f32, LDS, [64][AS]) rows are WAVE-PRIVATE (wave wv owns rows wv*16..+15),
// so no barriers are needed between layers. W is prepped transposed [n][k]
// hi/lo in global (L2-resident); frag reads are per-lane 16B (sa3f-proven).
template<int K, int N, int AS, bool XYZC>
DEVINL void do_layer_g(const unsigned short* __restrict__ Ghi,
                       const unsigned short* __restrict__ Glo,
                       const float* __restrict__ Wxyz,
                       const float* __restrict__ A, const float* __restrict__ sxyz,
                       f32x4* acc, int t) {
  constexpr int KT = K / 32;
  const int l = t & 63, wv = t >> 6;
  bf16x8 ahi[KT], alo[KT];
  {
    const int row = wv * 16 + (l & 15);
    const float* ap = A + row * AS + (l >> 4) * 8;
#pragma unroll
    for (int kt = 0; kt < KT; ++kt) {
      float4 v0 = *reinterpret_cast<const float4*>(ap + kt * 32);
      float4 v1 = *reinterpret_cast<const float4*>(ap + kt * 32 + 4);
      float f[8] = {v0.x, v0.y, v0.z, v0.w, v1.x, v1.y, v1.z, v1.w};
      bf16x8 h, lo2;
#pragma unroll
      for (int j = 0; j < 8; ++j) {
        unsigned short hb = f2bh(f[j]);
        h[j] = (short)hb;
        lo2[j] = (short)f2bh(f[j] - bh2f(hb));
      }
      ahi[kt] = h; alo[kt] = lo2;
    }
  }
#pragma unroll
  for (int i = 0; i < N / 16; ++i) acc[i] = f32x4{0.f, 0.f, 0.f, 0.f};

#pragma unroll
  for (int c = 0; c < N / 64; ++c) {
#pragma unroll
    for (int ct = 0; ct < 4; ++ct) {
      const int col = c * 64 + ct * 16 + (l & 15);
      const unsigned short* hp = Ghi + (size_t)col * K + (l >> 4) * 8;
      const unsigned short* lp = Glo + (size_t)col * K + (l >> 4) * 8;
      f32x4 a = acc[c * 4 + ct];
#pragma unroll
      for (int kt = 0; kt < KT; ++kt) {
        bf16x8 wh = *reinterpret_cast<const bf16x8*>(hp + kt * 32);
        bf16x8 wl = *reinterpret_cast<const bf16x8*>(lp + kt * 32);
        a = __builtin_amdgcn_mfma_f32_16x16x32_bf16(ahi[kt], wh, a, 0, 0, 0);
        a = __builtin_amdgcn_mfma_f32_16x16x32_bf16(alo[kt], wh, a, 0, 0, 0);
        a = __builtin_amdgcn_mfma_f32_16x16x32_bf16(ahi[kt], wl, a, 0, 0, 0);
      }
      acc[c * 4 + ct] = a;
    }
  }
  if constexpr (XYZC) {  // exact f32 correction for the 3 xyz input dims
    float xr[4][3];
#pragma unroll
    for (int r = 0; r < 4; ++r) {
      int row = wv * 16 + (l >> 4) * 4 + r;
      xr[r][0] = sxyz[row * 4 + 0];
      xr[r][1] = sxyz[row * 4 + 1];
      xr[r][2] = sxyz[row * 4 + 2];
    }
#pragma unroll
    for (int gt = 0; gt < N / 16; ++gt) {
      int col = gt * 16 + (l & 15);
      float w0 = Wxyz[col], w1 = Wxyz[N + col], w2 = Wxyz[2 * N + col];
#pragma unroll
      for (int r = 0; r < 4; ++r)
        acc[gt][r] += xr[r][0] * w0 + xr[r][1] * w1 + xr[r][2] * w2;
    }
  }
}

// ---------------------------------------------------------------- fused SA stage (gather + 3 layers + maxpool)
template<int NPTS, int Q, int M, int GPB, int FD, int C1, int C2, int C3>
__global__ __launch_bounds__(256) void sa_mfma_kernel(
    const float* __restrict__ pts, const float* __restrict__ centers,
    const int* __restrict__ gidx, const float* __restrict__ feats,
    const float* __restrict__ W0, const float* __restrict__ B0,
    const unsigned short* __restrict__ G0h, const unsigned short* __restrict__ G0l,
    const unsigned short* __restrict__ G1h, const unsigned short* __restrict__ G1l,
    const float* __restrict__ B1,
    const unsigned short* __restrict__ G2h, const unsigned short* __restrict__ G2l,
    const float* __restrict__ B2,
    float* __restrict__ fout) {
  static_assert(M * GPB == 64, "");
  constexpr int MK1 = (FD > C1 ? FD : C1);
  constexpr int MAXK = (MK1 > C2 ? MK1 : C2);
  constexpr int AS = MAXK + 8;
  __shared__ __align__(16) float A[64 * AS];
  __shared__ float sxyz[64 * 4];
  __shared__ int idxs[64];
  __shared__ float ctr[GPB][4];
  __shared__ float red[4][C3];

  const int t = threadIdx.x;
  const int blk = blockIdx.x;
  const int b = blk / (Q / GPB);
  const int q0 = (blk % (Q / GPB)) * GPB;
  const int l = t & 63, wv = t >> 6;

  if (t < GPB * 3) {
    int g = t / 3, c2 = t % 3;
    ctr[g][c2] = centers[((size_t)b * Q + q0 + g) * 3 + c2];
  }
  for (int m = t; m < 64; m += 256)
    idxs[m] = gidx[((size_t)b * Q + q0 + (m / M)) * M + (m % M)];
  __syncthreads();
  const float* pb = pts + (size_t)b * NPTS * 3;
  for (int m = t; m < 64; m += 256) {
    int g = m / M, i = idxs[m];
    sxyz[m * 4 + 0] = pb[i * 3 + 0] - ctr[g][0];
    sxyz[m * 4 + 1] = pb[i * 3 + 1] - ctr[g][1];
    sxyz[m * 4 + 2] = pb[i * 3 + 2] - ctr[g][2];
  }
  if constexpr (FD > 0) {
    const int m = t >> 2, co = (t & 3) * (FD / 4);
    const float* src = feats + ((size_t)b * NPTS + idxs[m]) * FD + co;
    float* dst = A + m * AS + co;
#pragma unroll
    for (int j = 0; j < FD / 4; j += 4)
      *reinterpret_cast<float4*>(dst + j) = *reinterpret_cast<const float4*>(src + j);
  }
  __syncthreads();

  f32x4 acc[C3 / 16];

  if constexpr (FD == 0) {
    // layer0: 3 -> C1 in exact f32 VALU (K=3 too small for MFMA)
    for (int u = t; u < 64 * C1; u += 256) {
      int m = u / C1, c2 = u - m * C1;
      float v = B0[c2] + sxyz[m * 4 + 0] * W0[0 * C1 + c2]
                       + sxyz[m * 4 + 1] * W0[1 * C1 + c2]
                       + sxyz[m * 4 + 2] * W0[2 * C1 + c2];
      A[m * AS + c2] = fmaxf(v, 0.f);
    }
    __syncthreads();  // cross-wave A writes above
  } else {
    do_layer_g<FD, C1, AS, true>(G0h, G0l, W0, A, sxyz, acc, t);
#pragma unroll
    for (int gt = 0; gt < C1 / 16; ++gt) {
      int col = gt * 16 + (l & 15);
      float bia = B0[col];
#pragma unroll
      for (int r = 0; r < 4; ++r)
        A[(wv * 16 + (l >> 4) * 4 + r) * AS + col] = fmaxf(acc[gt][r] + bia, 0.f);
    }
    // no barrier: A rows are wave-private
  }

  do_layer_g<C1, C2, AS, false>(G1h, G1l, nullptr, A, sxyz, acc, t);
#pragma unroll
  for (int gt = 0; gt < C2 / 16; ++gt) {
    int col = gt * 16 + (l & 15);
    float bia = B1[col];
#pragma unroll
    for (int r = 0; r < 4; ++r)
      A[(wv * 16 + (l >> 4) * 4 + r) * AS + col] = fmaxf(acc[gt][r] + bia, 0.f);
  }

  do_layer_g<C2, C3, AS, false>(G2h, G2l, nullptr, A, sxyz, acc, t);
  // maxpool epilogue: max over rows within each group, then +bias, relu
#pragma unroll
  for (int gt = 0; gt < C3 / 16; ++gt) {
    int col = gt * 16 + (l & 15);
    float v = fmaxf(fmaxf(acc[gt][0], acc[gt][1]), fmaxf(acc[gt][2], acc[gt][3]));
    v = fmaxf(v, __shfl_xor(v, 16, 64));
    v = fmaxf(v, __shfl_xor(v, 32, 64));
    if (l < 16) red[wv][col] = v + B2[col];
  }
  __syncthreads();
  constexpr int WPG = 4 / GPB;
  for (int u = t; u < GPB * C3; u += 256) {
    int g = u / C3, c2 = u - g * C3;
    float v = red[g * WPG][c2];
#pragma unroll
    for (int w = 1; w < WPG; ++w) v = fmaxf(v, red[g * WPG + w][c2]);
    fout[((size_t)b * Q + q0 + g) * C3 + c2] = fmaxf(v, 0.f);
  }
}

// ---------------------------------------------------------------- SA3 fused (split-bf16 MFMA, W frags from global)
DEVINL void sa3_frags(const float* __restrict__ A, int l, int KT, bf16x8* ahi, bf16x8* alo) {
  const float* ap = A + (l & 15) * 529 + (l >> 4) * 8;
  for (int kt = 0; kt < KT; ++kt) {
    float4 v0 = *reinterpret_cast<const float4*>(ap + kt * 32);
    float4 v1 = *reinterpret_cast<const float4*>(ap + kt * 32 + 4);
    float f[8] = {v0.x, v0.y, v0.z, v0.w, v1.x, v1.y, v1.z, v1.w};
    bf16x8 h, lo2;
#pragma unroll
    for (int j = 0; j < 8; ++j) {
      unsigned short hb = f2bh(f[j]);
      h[j] = (short)hb;
      lo2[j] = (short)f2bh(f[j] - bh2f(hb));
    }
    ahi[kt] = h; alo[kt] = lo2;
  }
}

template<int K>
DEVINL void sa3_mm64(const unsigned short* __restrict__ Gh, const unsigned short* __restrict__ Gl,
                     int ncol0, int l, const bf16x8* ahi, const bf16x8* alo, f32x4* acc4) {
  constexpr int KT = K / 32;
#pragma unroll
  for (int ct = 0; ct < 4; ++ct) {
    const unsigned short* hp = Gh + (size_t)(ncol0 + ct * 16 + (l & 15)) * K + (l >> 4) * 8;
    const unsigned short* lp = Gl + (size_t)(ncol0 + ct * 16 + (l & 15)) * K + (l >> 4) * 8;
    f32x4 a = acc4[ct];
#pragma unroll
    for (int kt = 0; kt < KT; ++kt) {
      bf16x8 wh = *reinterpret_cast<const bf16x8*>(hp + kt * 32);
      bf16x8 wl = *reinterpret_cast<const bf16x8*>(lp + kt * 32);
      a = __builtin_amdgcn_mfma_f32_16x16x32_bf16(ahi[kt], wh, a, 0, 0, 0);
      a = __builtin_amdgcn_mfma_f32_16x16x32_bf16(alo[kt], wh, a, 0, 0, 0);
      a = __builtin_amdgcn_mfma_f32_16x16x32_bf16(ahi[kt], wl, a, 0, 0, 0);
    }
    acc4[ct] = a;
  }
}

__global__ __launch_bounds__(256) void sa3f_kernel(
    const float* __restrict__ nx2, const float* __restrict__ f2,
    const float* __restrict__ W0full,
    const unsigned short* __restrict__ G0h, const unsigned short* __restrict__ G0l,
    const float* __restrict__ B0,
    const unsigned short* __restrict__ G1h, const unsigned short* __restrict__ G1l,
    const float* __restrict__ B1,
    const unsigned short* __restrict__ G2h, const unsigned short* __restrict__ G2l,
    const float* __restrict__ B2,
    float* __restrict__ partial) {
  constexpr int AS = 529;
  __shared__ __align__(16) float A[16 * AS];
  __shared__ float sxyz[16][4];
  const int t = threadIdx.x, l = t & 63, w = t >> 6;
  const int b = blockIdx.x >> 3, rb = blockIdx.x & 7;
  const int row0 = rb * 16;
  {
    int r = t >> 4, cc = (t & 15) * 16;
    const float* src = f2 + ((size_t)b * 128 + row0 + r) * 256 + cc;
    float* dstp = A + r * AS + cc;
#pragma unroll
    for (int j = 0; j < 16; j += 4)
      *reinterpret_cast<float4*>(dstp + j) = *reinterpret_cast<const float4*>(src + j);
    if (t < 16) {
      const float* s = nx2 + ((size_t)b * 128 + row0 + t) * 3;
      sxyz[t][0] = s[0]; sxyz[t][1] = s[1]; sxyz[t][2] = s[2];
    }
  }
  __syncthreads();

  {  // L1: K=256 MFMA + xyz f32 correction -> N=256 (wave cols 64)
    bf16x8 ah[8], al[8];
    sa3_frags(A, l, 8, ah, al);
    __syncthreads();
    f32x4 acc[4];
#pragma unroll
    for (int i = 0; i < 4; ++i) acc[i] = f32x4{0.f, 0.f, 0.f, 0.f};
    sa3_mm64<256>(G0h, G0l, w * 64, l, ah, al, acc);
    float xr[4][3];
#pragma unroll
    for (int r = 0; r < 4; ++r) {
      int row = (l >> 4) * 4 + r;
      xr[r][0] = sxyz[row][0]; xr[r][1] = sxyz[row][1]; xr[r][2] = sxyz[row][2];
    }
#pragma unroll
    for (int ct = 0; ct < 4; ++ct) {
      int col = w * 64 + ct * 16 + (l & 15);
      float w0 = W0full[col], w1 = W0full[256 + col], w2 = W0full[512 + col];
      float bia = B0[col];
#pragma unroll
      for (int r = 0; r < 4; ++r) {
        int row = (l >> 4) * 4 + r;
        float v = acc[ct][r] + xr[r][0] * w0 + xr[r][1] * w1 + xr[r][2] * w2 + bia;
        A[row * AS + col] = fmaxf(v, 0.f);
      }
    }
    __syncthreads();
  }

  {  // L2: K=256 -> N=512 (wave cols 128)
    bf16x8 ah[8], al[8];
    sa3_frags(A, l, 8, ah, al);
    __syncthreads();
    f32x4 acc[8];
#pragma unroll
    for (int i = 0; i < 8; ++i) acc[i] = f32x4{0.f, 0.f, 0.f, 0.f};
    sa3_mm64<256>(G1h, G1l, w * 128, l, ah, al, acc);
    sa3_mm64<256>(G1h, G1l, w * 128 + 64, l, ah, al, acc + 4);
#pragma unroll
    for (int cc = 0; cc < 8; ++cc) {
      int col = w * 128 + cc * 16 + (l & 15);
      float bia = B1[col];
#pragma unroll
      for (int r = 0; r < 4; ++r) {
        int row = (l >> 4) * 4 + r;
        A[row * AS + col] = fmaxf(acc[cc][r] + bia, 0.f);
      }
    }
    __syncthreads();
  }

  {  // L3: K=512 -> N=1024 (wave cols 256), maxpool 16 rows -> partial
    bf16x8 ah[16], al[16];
    sa3_frags(A, l, 16, ah, al);
    float* pout = partial + ((size_t)(b * 8 + rb)) * 1024;
#pragma unroll
    for (int sub = 0; sub < 4; ++sub) {
      f32x4 acc[4];
#pragma unroll
      for (int i = 0; i < 4; ++i) acc[i] = f32x4{0.f, 0.f, 0.f, 0.f};
      sa3_mm64<512>(G2h, G2l, w * 256 + sub * 64, l, ah, al, acc);
#pragma unroll
      for (int ct = 0; ct < 4; ++ct) {
        int col = w * 256 + sub * 64 + ct * 16 + (l & 15);
        float v = fmaxf(fmaxf(acc[ct][0], acc[ct][1]), fmaxf(acc[ct][2], acc[ct][3]));
        v = fmaxf(v, __shfl_xor(v, 16, 64));
        v = fmaxf(v, __shfl_xor(v, 32, 64));
        if (l < 16) pout[col] = v + B2[col];  // relu deferred to heads (monotone)
      }
    }
  }
}

// ---------------------------------------------------------------- heads (8-way partial max + relu + dots)
__global__ __launch_bounds__(256) void heads_kernel(const float* __restrict__ partial,
                                                    const float* __restrict__ cw,
                                                    const float* __restrict__ cb,
                                                    const float* __restrict__ rw,
                                                    const float* __restrict__ rb,
                                                    float* __restrict__ out) {
  const int b = blockIdx.x, t = threadIdx.x;
  const float* pb = partial + (size_t)b * 8 * 1024;
  float a0 = 0, a1 = 0, a2 = 0, a3 = 0, a4 = 0;
  for (int k = t; k < 1024; k += 256) {
    float m = pb[k];
#pragma unroll
    for (int p = 1; p < 8; ++p) m = fmaxf(m, pb[p * 1024 + k]);
    float f = fmaxf(m, 0.f);
    a0 += f * cw[k];
    const float* r = rw + (size_t)k * 4;
    a1 += f * r[0]; a2 += f * r[1]; a3 += f * r[2]; a4 += f * r[3];
  }
#pragma unroll
  for (int m = 32; m >= 1; m >>= 1) {
    a0 += __shfl_xor(a0, m, 64); a1 += __shfl_xor(a1, m, 64);
    a2 += __shfl_xor(a2, m, 64); a3 += __shfl_xor(a3, m, 64);
    a4 += __shfl_xor(a4, m, 64);
  }
  __shared__ float red[4][5];
  const int wv = t >> 6, ln = t & 63;
  if (ln == 0) { red[wv][0] = a0; red[wv][1] = a1; red[wv][2] = a2; red[wv][3] = a3; red[wv][4] = a4; }
  __syncthreads();
  if (t == 0) {
    float s0 = red[0][0] + red[1][0] + red[2][0] + red[3][0];
    float s1 = red[0][1] + red[1][1] + red[2][1] + red[3][1];
    float s2 = red[0][2] + red[1][2] + red[2][2] + red[3][2];
    float s3 = red[0][3] + red[1][3] + red[2][3] + red[3][3];
    float s4 = red[0][4] + red[1][4] + red[2][4] + red[3][4];
    out[b] = s0 + cb[0];
    out[32 + b * 4 + 0] = s1 + rb[0];
    out[32 + b * 4 + 1] = s2 + rb[1];
    out[32 + b * 4 + 2] = s3 + rb[2];
    out[32 + b * 4 + 3] = s4 + rb[3];
  }
}

// ---------------------------------------------------------------- launch
extern "C" void kernel_launch(void* const* d_in, const int* in_sizes, int n_in,
                              void* d_out, int out_size, void* d_ws, size_t ws_size,
                              hipStream_t stream) {
  (void)in_sizes; (void)n_in; (void)out_size; (void)ws_size;
  const float* xyz  = (const float*)d_in[0];
  const float* s1w0 = (const float*)d_in[1];  const float* s1b0 = (const float*)d_in[2];
  const float* s1w1 = (const float*)d_in[3];  const float* s1b1 = (const float*)d_in[4];
  const float* s1w2 = (const float*)d_in[5];  const float* s1b2 = (const float*)d_in[6];
  const float* s2w0 = (const float*)d_in[7];  const float* s2b0 = (const float*)d_in[8];
  const float* s2w1 = (const float*)d_in[9];  const float* s2b1 = (const float*)d_in[10];
  const float* s2w2 = (const float*)d_in[11]; const float* s2b2 = (const float*)d_in[12];
  const float* s3w0 = (const float*)d_in[13]; const float* s3b0 = (const float*)d_in[14];
  const float* s3w1 = (const float*)d_in[15]; const float* s3b1 = (const float*)d_in[16];
  const float* s3w2 = (const float*)d_in[17]; const float* s3b2 = (const float*)d_in[18];
  const float* clsw = (const float*)d_in[19]; const float* clsb = (const float*)d_in[20];
  const float* regw = (const float*)d_in[21]; const float* regb = (const float*)d_in[22];

  char* ws = (char*)d_ws;
  float* nx1   = (float*)(ws + 0);          // 32*512*3
  int*   gidx1 = (int*)  (ws + 196608);     // 32*512*32
  float* f1    = (float*)(ws + 2293760);    // 32*512*128
  float* nx2   = (float*)(ws + 10682368);   // 32*128*3
  int*   gidx2 = (int*)  (ws + 10731520);   // 32*128*64
  float* f2    = (float*)(ws + 11780096);   // 32*128*256

  // SA1/SA2 prepped weights (u16 hi/lo, transposed [n][k])
  unsigned short* wt = (unsigned short*)(ws + 20168704);
  unsigned short* g11h = wt;            // 64*64
  unsigned short* g11l = wt + 4096;
  unsigned short* g12h = wt + 8192;     // 128*64
  unsigned short* g12l = wt + 16384;
  unsigned short* g20h = wt + 24576;    // 128*128 (rows 3..130 of s2w0)
  unsigned short* g20l = wt + 40960;
  unsigned short* g21h = wt + 57344;    // 128*128
  unsigned short* g21l = wt + 73728;
  unsigned short* g22h = wt + 90112;    // 256*128
  unsigned short* g22l = wt + 122880;   // ends at byte 20168704+311296 = 20480000
  // SA3 prepped weights
  unsigned short* g30h = (unsigned short*)(ws + 20480000);  // 256x256
  unsigned short* g30l = (unsigned short*)(ws + 20611072);
  unsigned short* g31h = (unsigned short*)(ws + 20742144);  // 512x256
  unsigned short* g31l = (unsigned short*)(ws + 21004288);
  unsigned short* g32h = (unsigned short*)(ws + 21266432);  // 1024x512
  unsigned short* g32l = (unsigned short*)(ws + 22315008);
  float* partial = (float*)(ws + 23363584);                 // 32*8*1024 f32 -> ends 24412160

  const float r21 = (float)(0.2 * 0.2);
  const float r22 = (float)(0.4 * 0.4);

  WPTab tab;
  int off = 0;
  auto set = [&](int i, const float* W, unsigned short* hi, unsigned short* lo,
                 int K, int N, int row0) {
    tab.e[i] = WPEnt{W, hi, lo, K, N, row0, off, off + K * N};
    off += K * N;
  };
  set(0, s1w1, g11h, g11l, 64, 64, 0);
  set(1, s1w2, g12h, g12l, 64, 128, 0);
  set(2, s2w0, g20h, g20l, 128, 128, 3);
  set(3, s2w1, g21h, g21l, 128, 128, 0);
  set(4, s2w2, g22h, g22l, 128, 256, 0);
  set(5, s3w0, g30h, g30l, 256, 256, 3);
  set(6, s3w1, g31h, g31l, 256, 512, 0);
  set(7, s3w2, g32h, g32l, 512, 1024, 0);
  wprep8_kernel<<<(off + 255) / 256, 256, 0, stream>>>(tab);

  fps_kernel<4096, 512, 256, 2><<<16, 256, 0, stream>>>(xyz, nx1);
  bq_kernel<4096, 32><<<4096, 256, 0, stream>>>(xyz, nx1, gidx1, 512, r21);
  sa_mfma_kernel<4096, 512, 32, 2, 0, 64, 64, 128><<<8192, 256, 0, stream>>>(
      xyz, nx1, gidx1, (const float*)nullptr, s1w0, s1b0,
      nullptr, nullptr, g11h, g11l, s1b1, g12h, g12l, s1b2, f1);
  fps_kernel<512, 128, 64, 2><<<16, 64, 0, stream>>>(nx1, nx2);
  bq_kernel<512, 64><<<1024, 256, 0, stream>>>(nx1, nx2, gidx2, 128, r22);
  sa_mfma_kernel<512, 128, 64, 1, 128, 128, 128, 256><<<4096, 256, 0, stream>>>(
      nx1, nx2, gidx2, f1, s2w0, s2b0,
      g20h, g20l, g21h, g21l, s2b1, g22h, g22l, s2b2, f2);
  sa3f_kernel<<<256, 256, 0, stream>>>(nx2, f2, s3w0, g30h, g30l, s3b0,
                                       g31h, g31l, s3b1, g32h, g32l, s3b2, partial);
  heads_kernel<<<32, 256, 0, stream>>>(partial, clsw, clsb, regw, regb, (float*)d_out);
}

// Round 8
// 1026.097 us; speedup vs baseline: 1.4075x; 1.4075x over previous
//
#include <hip/hip_runtime.h>

#define DEVINL __device__ __forceinline__

typedef __attribute__((ext_vector_type(8))) short bf16x8;
typedef __attribute__((ext_vector_type(8))) unsigned short u16x8;
typedef __attribute__((ext_vector_type(4))) float f32x4;

// RNE f32 -> bf16 bits (no NaN handling needed for this workload)
DEVINL unsigned short f2bh(float f){
  unsigned u = __float_as_uint(f);
  return (unsigned short)((u + 0x7FFFu + ((u >> 16) & 1u)) >> 16);
}
DEVINL float bh2f(unsigned short h){ return __uint_as_float(((unsigned)h) << 16); }

// Wave64 max-reduce of a u64 key via DPP (VALU latency, no DS pipe).
DEVINL unsigned long long dpp_max_u64(unsigned long long k) {
#define DPP_STEP(ctrl)                                                        \
  {                                                                           \
    int hi = (int)(k >> 32), lo = (int)(unsigned)k;                           \
    int oh = __builtin_amdgcn_update_dpp(0, hi, ctrl, 0xF, 0xF, 1);           \
    int ol = __builtin_amdgcn_update_dpp(0, lo, ctrl, 0xF, 0xF, 1);           \
    unsigned long long ok =                                                   \
        ((unsigned long long)(unsigned)oh << 32) | (unsigned)ol;              \
    if (ok > k) k = ok;                                                       \
  }
  DPP_STEP(0x111)  // row_shr:1
  DPP_STEP(0x112)  // row_shr:2
  DPP_STEP(0x114)  // row_shr:4
  DPP_STEP(0x118)  // row_shr:8
  DPP_STEP(0x142)  // row_bcast:15
  DPP_STEP(0x143)  // row_bcast:31
#undef DPP_STEP
  return k;
}

// ---------------------------------------------------------------- FPS
// R4-proven per-batch body; NB independent batches interleaved per block.
template<int N, int NP, int NT, int NB>
__global__ __launch_bounds__(NT) void fps_kernel(const float* __restrict__ xyz,
                                                 float* __restrict__ nxyz) {
  constexpr int PTS = N / NT;
  constexpr int NW = NT / 64;
  const int b0 = blockIdx.x * NB, t = threadIdx.x;
  __shared__ float xs[NB][N], ys[NB][N], zs[NB][N];
  __shared__ int farr[NB][NP];
  __shared__ unsigned long long sk[2][NB][(NW > 1 ? NW : 1)];
  float px[NB][PTS], py[NB][PTS], pz[NB][PTS], dst[NB][PTS];
#pragma unroll
  for (int nb = 0; nb < NB; ++nb) {
    const float* base = xyz + (size_t)(b0 + nb) * N * 3;
#pragma unroll
    for (int j = 0; j < PTS; ++j) {
      int i = t + j * NT;
      float x = base[i * 3 + 0], y = base[i * 3 + 1], z = base[i * 3 + 2];
      px[nb][j] = x; py[nb][j] = y; pz[nb][j] = z;
      xs[nb][i] = x; ys[nb][i] = y; zs[nb][i] = z;
      dst[nb][j] = 1e10f;
    }
  }
  __syncthreads();
  int far[NB];
#pragma unroll
  for (int nb = 0; nb < NB; ++nb) far[nb] = 0;
  const int wv = t >> 6, ln = t & 63;
  for (int s = 0; s < NP; ++s) {
    float cx[NB], cy[NB], cz[NB];
#pragma unroll
    for (int nb = 0; nb < NB; ++nb) {
      cx[nb] = xs[nb][far[nb]]; cy[nb] = ys[nb][far[nb]]; cz[nb] = zs[nb][far[nb]];
    }
    if (t == 0) {
#pragma unroll
      for (int nb = 0; nb < NB; ++nb) farr[nb][s] = far[nb];
    }
    unsigned long long key[NB];
#pragma unroll
    for (int nb = 0; nb < NB; ++nb) {
      float bv = -1.f; int bj = 0;
#pragma unroll
      for (int j = 0; j < PTS; ++j) {
        // no-fma, left-to-right: matches numpy elementwise + sum order
        float dx = __fsub_rn(px[nb][j], cx[nb]);
        float dy = __fsub_rn(py[nb][j], cy[nb]);
        float dz = __fsub_rn(pz[nb][j], cz[nb]);
        float d = __fadd_rn(__fadd_rn(__fmul_rn(dx, dx), __fmul_rn(dy, dy)), __fmul_rn(dz, dz));
        float nd = fminf(dst[nb][j], d);
        dst[nb][j] = nd;
        if (nd > bv) { bv = nd; bj = j; }  // strict >: first max kept per thread
      }
      int bi = t + bj * NT;
      key[nb] = ((unsigned long long)__float_as_uint(bv) << 32) | (unsigned)(~bi);
    }
#pragma unroll
    for (int nb = 0; nb < NB; ++nb) key[nb] = dpp_max_u64(key[nb]);
    if constexpr (NW == 1) {
#pragma unroll
      for (int nb = 0; nb < NB; ++nb) {
        int rl = __builtin_amdgcn_readlane((int)(unsigned)key[nb], 63);
        far[nb] = (int)(~(unsigned)rl);
      }
    } else {
      const int p = s & 1;
      if (ln == 63) {
#pragma unroll
        for (int nb = 0; nb < NB; ++nb) sk[p][nb][wv] = key[nb];
      }
      __syncthreads();
#pragma unroll
      for (int nb = 0; nb < NB; ++nb) {
        unsigned long long m = sk[p][nb][0];
#pragma unroll
        for (int q = 1; q < NW; ++q) {
          unsigned long long qk = sk[p][nb][q];
          if (qk > m) m = qk;
        }
        far[nb] = (int)(~(unsigned)m);
      }
    }
  }
  __syncthreads();
  for (int u = t; u < NB * NP; u += NT) {
    int nb = u / NP, s2 = u - nb * NP;
    int fi = farr[nb][s2];
    float* o = nxyz + ((size_t)(b0 + nb) * NP + s2) * 3;
    o[0] = xs[nb][fi]; o[1] = ys[nb][fi]; o[2] = zs[nb][fi];
  }
}

// ---------------------------------------------------------------- ball query (unchanged)
template<int N, int NS>
__global__ __launch_bounds__(256) void bq_kernel(const float* __restrict__ pts,
                                                 const float* __restrict__ centers,
                                                 int* __restrict__ gidx, int Q, float r2) {
  const int wv = threadIdx.x >> 6, ln = threadIdx.x & 63;
  const int g = blockIdx.x * 4 + wv;
  const int b = g / Q, q = g % Q;
  const float* pb = pts + (size_t)b * N * 3;
  const float* c = centers + ((size_t)b * Q + q) * 3;
  const float cx = c[0], cy = c[1], cz = c[2];
  __shared__ int gbuf[4][NS];
  int taken = 0;
  for (int base = 0; base < N; base += 64) {
    if (taken >= NS) break;
    int i = base + ln;
    float dx = __fsub_rn(pb[i * 3 + 0], cx), dy = __fsub_rn(pb[i * 3 + 1], cy),
          dz = __fsub_rn(pb[i * 3 + 2], cz);
    float d = __fadd_rn(__fadd_rn(__fmul_rn(dx, dx), __fmul_rn(dy, dy)), __fmul_rn(dz, dz));
    bool in = (d <= r2);
    unsigned long long mk = __ballot(in);
    int rank = __popcll(mk & ((1ull << ln) - 1ull));
    int pos = taken + rank;
    if (in && pos < NS) gbuf[wv][pos] = i;
    taken += (int)__popcll(mk);
  }
  int total = taken < NS ? taken : NS;
  int first = gbuf[wv][0];
  int* out = gidx + ((size_t)b * Q + q) * NS;
  for (int j = ln; j < NS; j += 64) out[j] = (j < total) ? gbuf[wv][j] : first;
}

// ---------------------------------------------------------------- weight prep (all 8 matrices, one launch)
struct WPEnt { const float* W; unsigned short* hi; unsigned short* lo; int K, N, row0, beg, end; };
struct WPTab { WPEnt e[8]; };
__global__ __launch_bounds__(256) void wprep8_kernel(WPTab tab) {
  int idx = blockIdx.x * 256 + threadIdx.x;
#pragma unroll
  for (int i = 0; i < 8; ++i) {
    const WPEnt& E = tab.e[i];
    if (idx >= E.beg && idx < E.end) {
      int local = idx - E.beg;
      int k = local / E.N, n = local - k * E.N;
      float v = E.W[(size_t)(E.row0 + k) * E.N + n];
      unsigned short h = f2bh(v);
      E.hi[(size_t)n * E.K + k] = h;
      E.lo[(size_t)n * E.K + k] = f2bh(v - bh2f(h));
    }
  }
}

// ---------------------------------------------------------------- split-bf16 MFMA layer (R5-proven: W chunk-staged in LDS)
template<int K, int N, int AS, int WS, bool XYZC>
DEVINL void do_layer(const unsigned short* __restrict__ Ghi, const unsigned short* __restrict__ Glo,
                     const float* __restrict__ Wxyz,
                     const float* __restrict__ A, unsigned short* __restrict__ Whi,
                     unsigned short* __restrict__ Wlo, const float* __restrict__ sxyz,
                     f32x4* acc, int t) {
  constexpr int KT = K / 32;
  constexpr int NCH = N / 64;
  const int l = t & 63, wv = t >> 6;
  bf16x8 ahi[KT], alo[KT];
  {
    const int row = wv * 16 + (l & 15);
    const float* ap = A + row * AS + (l >> 4) * 8;
#pragma unroll
    for (int kt = 0; kt < KT; ++kt) {
      float4 v0 = *reinterpret_cast<const float4*>(ap + kt * 32);
      float4 v1 = *reinterpret_cast<const float4*>(ap + kt * 32 + 4);
      float f[8] = {v0.x, v0.y, v0.z, v0.w, v1.x, v1.y, v1.z, v1.w};
      bf16x8 h, lo2;
#pragma unroll
      for (int j = 0; j < 8; ++j) {
        unsigned short hb = f2bh(f[j]);
        h[j] = (short)hb;
        lo2[j] = (short)f2bh(f[j] - bh2f(hb));
      }
      ahi[kt] = h; alo[kt] = lo2;
    }
  }
#pragma unroll
  for (int i = 0; i < N / 16; ++i) acc[i] = f32x4{0.f, 0.f, 0.f, 0.f};

#pragma unroll
  for (int c = 0; c < NCH; ++c) {
    __syncthreads();
    {
      constexpr int K8 = K / 8;
      for (int u = t; u < 64 * K8; u += 256) {
        int nn = u / K8, k8 = (u - nn * K8) * 8;
        *reinterpret_cast<u16x8*>(Whi + nn * WS + k8) =
            *reinterpret_cast<const u16x8*>(Ghi + (size_t)(c * 64 + nn) * K + k8);
        *reinterpret_cast<u16x8*>(Wlo + nn * WS + k8) =
            *reinterpret_cast<const u16x8*>(Glo + (size_t)(c * 64 + nn) * K + k8);
      }
    }
    __syncthreads();
#pragma unroll
    for (int ct = 0; ct < 4; ++ct) {
      const unsigned short* wp = Whi + (ct * 16 + (l & 15)) * WS + (l >> 4) * 8;
      const unsigned short* wq = Wlo + (ct * 16 + (l & 15)) * WS + (l >> 4) * 8;
      f32x4 a = acc[c * 4 + ct];
#pragma unroll
      for (int kt = 0; kt < KT; ++kt) {
        bf16x8 wh = *reinterpret_cast<const bf16x8*>(wp + kt * 32);
        bf16x8 wl = *reinterpret_cast<const bf16x8*>(wq + kt * 32);
        a = __builtin_amdgcn_mfma_f32_16x16x32_bf16(ahi[kt], wh, a, 0, 0, 0);
        a = __builtin_amdgcn_mfma_f32_16x16x32_bf16(alo[kt], wh, a, 0, 0, 0);
        a = __builtin_amdgcn_mfma_f32_16x16x32_bf16(ahi[kt], wl, a, 0, 0, 0);
      }
      acc[c * 4 + ct] = a;
    }
  }
  if constexpr (XYZC) {
    float xr[4][3];
#pragma unroll
    for (int r = 0; r < 4; ++r) {
      int row = wv * 16 + (l >> 4) * 4 + r;
      xr[r][0] = sxyz[row * 4 + 0];
      xr[r][1] = sxyz[row * 4 + 1];
      xr[r][2] = sxyz[row * 4 + 2];
    }
#pragma unroll
    for (int gt = 0; gt < N / 16; ++gt) {
      int col = gt * 16 + (l & 15);
      float w0 = Wxyz[col], w1 = Wxyz[N + col], w2 = Wxyz[2 * N + col];
#pragma unroll
      for (int r = 0; r < 4; ++r)
        acc[gt][r] += xr[r][0] * w0 + xr[r][1] * w1 + xr[r][2] * w2;
    }
  }
}

// ---------------------------------------------------------------- SA2 fused (R5-proven structure)
template<int NPTS, int Q, int M, int GPB, int FD, int C1, int C2, int C3>
__global__ __launch_bounds__(256) void sa_mfma_kernel(
    const float* __restrict__ pts, const float* __restrict__ centers,
    const int* __restrict__ gidx, const float* __restrict__ feats,
    const float* __restrict__ W0, const float* __restrict__ B0,
    const unsigned short* __restrict__ G0h, const unsigned short* __restrict__ G0l,
    const unsigned short* __restrict__ G1h, const unsigned short* __restrict__ G1l,
    const float* __restrict__ B1,
    const unsigned short* __restrict__ G2h, const unsigned short* __restrict__ G2l,
    const float* __restrict__ B2,
    float* __restrict__ fout) {
  static_assert(M * GPB == 64, "");
  constexpr int MK1 = (FD > C1 ? FD : C1);
  constexpr int MAXK = (MK1 > C2 ? MK1 : C2);
  constexpr int AS = MAXK + 8;
  constexpr int WS = MAXK + 8;
  __shared__ __align__(16) float A[64 * AS];
  __shared__ __align__(16) unsigned short Whi[64 * WS];
  __shared__ __align__(16) unsigned short Wlo[64 * WS];
  __shared__ float sxyz[64 * 4];
  __shared__ int idxs[64];
  __shared__ float ctr[GPB][4];
  __shared__ float red[4][C3];

  const int t = threadIdx.x;
  const int blk = blockIdx.x;
  const int b = blk / (Q / GPB);
  const int q0 = (blk % (Q / GPB)) * GPB;
  const int l = t & 63, wv = t >> 6;

  if (t < GPB * 3) {
    int g = t / 3, c2 = t % 3;
    ctr[g][c2] = centers[((size_t)b * Q + q0 + g) * 3 + c2];
  }
  for (int m = t; m < 64; m += 256)
    idxs[m] = gidx[((size_t)b * Q + q0 + (m / M)) * M + (m % M)];
  __syncthreads();
  const float* pb = pts + (size_t)b * NPTS * 3;
  for (int m = t; m < 64; m += 256) {
    int g = m / M, i = idxs[m];
    sxyz[m * 4 + 0] = pb[i * 3 + 0] - ctr[g][0];
    sxyz[m * 4 + 1] = pb[i * 3 + 1] - ctr[g][1];
    sxyz[m * 4 + 2] = pb[i * 3 + 2] - ctr[g][2];
  }
  if constexpr (FD > 0) {
    const int m = t >> 2, co = (t & 3) * (FD / 4);
    const float* src = feats + ((size_t)b * NPTS + idxs[m]) * FD + co;
    float* dst = A + m * AS + co;
#pragma unroll
    for (int j = 0; j < FD / 4; j += 4)
      *reinterpret_cast<float4*>(dst + j) = *reinterpret_cast<const float4*>(src + j);
  }
  __syncthreads();

  f32x4 acc[C3 / 16];

  if constexpr (FD == 0) {
    for (int u = t; u < 64 * C1; u += 256) {
      int m = u / C1, c2 = u - m * C1;
      float v = B0[c2] + sxyz[m * 4 + 0] * W0[0 * C1 + c2]
                       + sxyz[m * 4 + 1] * W0[1 * C1 + c2]
                       + sxyz[m * 4 + 2] * W0[2 * C1 + c2];
      A[m * AS + c2] = fmaxf(v, 0.f);
    }
    __syncthreads();
  } else {
    do_layer<FD, C1, AS, WS, true>(G0h, G0l, W0, A, Whi, Wlo, sxyz, acc, t);
#pragma unroll
    for (int gt = 0; gt < C1 / 16; ++gt) {
      int col = gt * 16 + (l & 15);
      float bia = B0[col];
#pragma unroll
      for (int r = 0; r < 4; ++r)
        A[(wv * 16 + (l >> 4) * 4 + r) * AS + col] = fmaxf(acc[gt][r] + bia, 0.f);
    }
  }

  do_layer<C1, C2, AS, WS, false>(G1h, G1l, nullptr, A, Whi, Wlo, sxyz, acc, t);
#pragma unroll
  for (int gt = 0; gt < C2 / 16; ++gt) {
    int col = gt * 16 + (l & 15);
    float bia = B1[col];
#pragma unroll
    for (int r = 0; r < 4; ++r)
      A[(wv * 16 + (l >> 4) * 4 + r) * AS + col] = fmaxf(acc[gt][r] + bia, 0.f);
  }

  do_layer<C2, C3, AS, WS, false>(G2h, G2l, nullptr, A, Whi, Wlo, sxyz, acc, t);
#pragma unroll
  for (int gt = 0; gt < C3 / 16; ++gt) {
    int col = gt * 16 + (l & 15);
    float v = fmaxf(fmaxf(acc[gt][0], acc[gt][1]), fmaxf(acc[gt][2], acc[gt][3]));
    v = fmaxf(v, __shfl_xor(v, 16, 64));
    v = fmaxf(v, __shfl_xor(v, 32, 64));
    if (l < 16) red[wv][col] = v + B2[col];
  }
  __syncthreads();
  constexpr int WPG = 4 / GPB;
  for (int u = t; u < GPB * C3; u += 256) {
    int g = u / C3, c2 = u - g * C3;
    float v = red[g * WPG][c2];
#pragma unroll
    for (int w = 1; w < WPG; ++w) v = fmaxf(v, red[g * WPG + w][c2]);
    fout[((size_t)b * Q + q0 + g) * C3 + c2] = fmaxf(v, 0.f);
  }
}

// ---------------------------------------------------------------- SA1 fused, ALL weights staged in LDS once
// SA1 weights are small (L2 64x64 + L3 64x128, hi+lo = 54 KB): stage once,
// then layers run barrier-free (A rows wave-private, W read-only in LDS).
template<int NPTS, int Q, int M, int GPB>
__global__ __launch_bounds__(256) void sa1_kernel(
    const float* __restrict__ pts, const float* __restrict__ centers,
    const int* __restrict__ gidx,
    const float* __restrict__ W0, const float* __restrict__ B0,
    const unsigned short* __restrict__ G1h, const unsigned short* __restrict__ G1l,
    const float* __restrict__ B1,
    const unsigned short* __restrict__ G2h, const unsigned short* __restrict__ G2l,
    const float* __restrict__ B2,
    float* __restrict__ fout) {
  static_assert(M * GPB == 64, "");
  constexpr int C1 = 64, C2 = 64, C3 = 128;
  constexpr int AS = 72;   // A stride (f32)
  constexpr int WS = 72;   // W stride (u16); 144B: 16B-aligned rows, 2-way banks
  constexpr int NC = C2 + C3;  // 192 staged cols: [0,64)=L2, [64,192)=L3
  __shared__ __align__(16) float A[64 * AS];
  __shared__ __align__(16) unsigned short Wh[NC * WS];
  __shared__ __align__(16) unsigned short Wl[NC * WS];
  __shared__ float sxyz[64 * 4];
  __shared__ int idxs[64];
  __shared__ float ctr[GPB][4];
  __shared__ float red[4][C3];

  const int t = threadIdx.x, l = t & 63, wv = t >> 6;
  const int blk = blockIdx.x;
  const int b = blk / (Q / GPB);
  const int q0 = (blk % (Q / GPB)) * GPB;

  if (t < GPB * 3) {
    int g = t / 3, c2 = t % 3;
    ctr[g][c2] = centers[((size_t)b * Q + q0 + g) * 3 + c2];
  }
  for (int m = t; m < 64; m += 256)
    idxs[m] = gidx[((size_t)b * Q + q0 + (m / M)) * M + (m % M)];
  // stage ALL weights (K=64 per col -> 8 x u16x8 chunks per col)
  for (int u = t; u < NC * 8; u += 256) {
    int col = u >> 3, k8 = (u & 7) * 8;
    const unsigned short* sh = (col < C2) ? G1h + (size_t)col * 64 + k8
                                          : G2h + (size_t)(col - C2) * 64 + k8;
    const unsigned short* sl = (col < C2) ? G1l + (size_t)col * 64 + k8
                                          : G2l + (size_t)(col - C2) * 64 + k8;
    *reinterpret_cast<u16x8*>(Wh + col * WS + k8) = *reinterpret_cast<const u16x8*>(sh);
    *reinterpret_cast<u16x8*>(Wl + col * WS + k8) = *reinterpret_cast<const u16x8*>(sl);
  }
  __syncthreads();
  const float* pb = pts + (size_t)b * NPTS * 3;
  for (int m = t; m < 64; m += 256) {
    int g = m / M, i = idxs[m];
    sxyz[m * 4 + 0] = pb[i * 3 + 0] - ctr[g][0];
    sxyz[m * 4 + 1] = pb[i * 3 + 1] - ctr[g][1];
    sxyz[m * 4 + 2] = pb[i * 3 + 2] - ctr[g][2];
  }
  __syncthreads();

  // layer0: 3 -> 64 in exact f32 VALU (block-strided writes -> barrier after)
  for (int u = t; u < 64 * C1; u += 256) {
    int m = u / C1, c2 = u - m * C1;
    float v = B0[c2] + sxyz[m * 4 + 0] * W0[0 * C1 + c2]
                     + sxyz[m * 4 + 1] * W0[1 * C1 + c2]
                     + sxyz[m * 4 + 2] * W0[2 * C1 + c2];
    A[m * AS + c2] = fmaxf(v, 0.f);
  }
  __syncthreads();

  f32x4 acc[8];
  // ---- L2: 64 -> 64, W cols [0,64), barrier-free
  {
    bf16x8 ah[2], al[2];
    const float* ap = A + (wv * 16 + (l & 15)) * AS + (l >> 4) * 8;
#pragma unroll
    for (int kt = 0; kt < 2; ++kt) {
      float4 v0 = *reinterpret_cast<const float4*>(ap + kt * 32);
      float4 v1 = *reinterpret_cast<const float4*>(ap + kt * 32 + 4);
      float f[8] = {v0.x, v0.y, v0.z, v0.w, v1.x, v1.y, v1.z, v1.w};
      bf16x8 h, lo2;
#pragma unroll
      for (int j = 0; j < 8; ++j) {
        unsigned short hb = f2bh(f[j]);
        h[j] = (short)hb;
        lo2[j] = (short)f2bh(f[j] - bh2f(hb));
      }
      ah[kt] = h; al[kt] = lo2;
    }
#pragma unroll
    for (int i = 0; i < 4; ++i) acc[i] = f32x4{0.f, 0.f, 0.f, 0.f};
#pragma unroll
    for (int ct = 0; ct < 4; ++ct) {
      const unsigned short* wp = Wh + (ct * 16 + (l & 15)) * WS + (l >> 4) * 8;
      const unsigned short* wq = Wl + (ct * 16 + (l & 15)) * WS + (l >> 4) * 8;
      f32x4 a = acc[ct];
#pragma unroll
      for (int kt = 0; kt < 2; ++kt) {
        bf16x8 wh = *reinterpret_cast<const bf16x8*>(wp + kt * 32);
        bf16x8 wl = *reinterpret_cast<const bf16x8*>(wq + kt * 32);
        a = __builtin_amdgcn_mfma_f32_16x16x32_bf16(ah[kt], wh, a, 0, 0, 0);
        a = __builtin_amdgcn_mfma_f32_16x16x32_bf16(al[kt], wh, a, 0, 0, 0);
        a = __builtin_amdgcn_mfma_f32_16x16x32_bf16(ah[kt], wl, a, 0, 0, 0);
      }
      acc[ct] = a;
    }
#pragma unroll
    for (int gt = 0; gt < 4; ++gt) {
      int col = gt * 16 + (l & 15);
      float bia = B1[col];
#pragma unroll
      for (int r = 0; r < 4; ++r)
        A[(wv * 16 + (l >> 4) * 4 + r) * AS + col] = fmaxf(acc[gt][r] + bia, 0.f);
    }
    // no barrier: A rows wave-private
  }

  // ---- L3: 64 -> 128, W cols [64,192), maxpool epilogue
  {
    bf16x8 ah[2], al[2];
    const float* ap = A + (wv * 16 + (l & 15)) * AS + (l >> 4) * 8;
#pragma unroll
    for (int kt = 0; kt < 2; ++kt) {
      float4 v0 = *reinterpret_cast<const float4*>(ap + kt * 32);
      float4 v1 = *reinterpret_cast<const float4*>(ap + kt * 32 + 4);
      float f[8] = {v0.x, v0.y, v0.z, v0.w, v1.x, v1.y, v1.z, v1.w};
      bf16x8 h, lo2;
#pragma unroll
      for (int j = 0; j < 8; ++j) {
        unsigned short hb = f2bh(f[j]);
        h[j] = (short)hb;
        lo2[j] = (short)f2bh(f[j] - bh2f(hb));
      }
      ah[kt] = h; al[kt] = lo2;
    }
#pragma unroll
    for (int i = 0; i < 8; ++i) acc[i] = f32x4{0.f, 0.f, 0.f, 0.f};
#pragma unroll
    for (int gt = 0; gt < 8; ++gt) {
      const unsigned short* wp = Wh + (C2 + gt * 16 + (l & 15)) * WS + (l >> 4) * 8;
      const unsigned short* wq = Wl + (C2 + gt * 16 + (l & 15)) * WS + (l >> 4) * 8;
      f32x4 a = acc[gt];
#pragma unroll
      for (int kt = 0; kt < 2; ++kt) {
        bf16x8 wh = *reinterpret_cast<const bf16x8*>(wp + kt * 32);
        bf16x8 wl = *reinterpret_cast<const bf16x8*>(wq + kt * 32);
        a = __builtin_amdgcn_mfma_f32_16x16x32_bf16(ah[kt], wh, a, 0, 0, 0);
        a = __builtin_amdgcn_mfma_f32_16x16x32_bf16(al[kt], wh, a, 0, 0, 0);
        a = __builtin_amdgcn_mfma_f32_16x16x32_bf16(ah[kt], wl, a, 0, 0, 0);
      }
      acc[gt] = a;
    }
#pragma unroll
    for (int gt = 0; gt < 8; ++gt) {
      int col = gt * 16 + (l & 15);
      float v = fmaxf(fmaxf(acc[gt][0], acc[gt][1]), fmaxf(acc[gt][2], acc[gt][3]));
      v = fmaxf(v, __shfl_xor(v, 16, 64));
      v = fmaxf(v, __shfl_xor(v, 32, 64));
      if (l < 16) red[wv][col] = v + B2[col];
    }
  }
  __syncthreads();
  constexpr int WPG = 4 / GPB;
  for (int u = t; u < GPB * C3; u += 256) {
    int g = u / C3, c2 = u - g * C3;
    float v = red[g * WPG][c2];
#pragma unroll
    for (int w = 1; w < WPG; ++w) v = fmaxf(v, red[g * WPG + w][c2]);
    fout[((size_t)b * Q + q0 + g) * C3 + c2] = fmaxf(v, 0.f);
  }
}

// ---------------------------------------------------------------- SA3 fused (split-bf16 MFMA, W frags from global)
DEVINL void sa3_frags(const float* __restrict__ A, int l, int KT, bf16x8* ahi, bf16x8* alo) {
  const float* ap = A + (l & 15) * 529 + (l >> 4) * 8;
  for (int kt = 0; kt < KT; ++kt) {
    float4 v0 = *reinterpret_cast<const float4*>(ap + kt * 32);
    float4 v1 = *reinterpret_cast<const float4*>(ap + kt * 32 + 4);
    float f[8] = {v0.x, v0.y, v0.z, v0.w, v1.x, v1.y, v1.z, v1.w};
    bf16x8 h, lo2;
#pragma unroll
    for (int j = 0; j < 8; ++j) {
      unsigned short hb = f2bh(f[j]);
      h[j] = (short)hb;
      lo2[j] = (short)f2bh(f[j] - bh2f(hb));
    }
    ahi[kt] = h; alo[kt] = lo2;
  }
}

template<int K>
DEVINL void sa3_mm64(const unsigned short* __restrict__ Gh, const unsigned short* __restrict__ Gl,
                     int ncol0, int l, const bf16x8* ahi, const bf16x8* alo, f32x4* acc4) {
  constexpr int KT = K / 32;
#pragma unroll
  for (int ct = 0; ct < 4; ++ct) {
    const unsigned short* hp = Gh + (size_t)(ncol0 + ct * 16 + (l & 15)) * K + (l >> 4) * 8;
    const unsigned short* lp = Gl + (size_t)(ncol0 + ct * 16 + (l & 15)) * K + (l >> 4) * 8;
    f32x4 a = acc4[ct];
#pragma unroll
    for (int kt = 0; kt < KT; ++kt) {
      bf16x8 wh = *reinterpret_cast<const bf16x8*>(hp + kt * 32);
      bf16x8 wl = *reinterpret_cast<const bf16x8*>(lp + kt * 32);
      a = __builtin_amdgcn_mfma_f32_16x16x32_bf16(ahi[kt], wh, a, 0, 0, 0);
      a = __builtin_amdgcn_mfma_f32_16x16x32_bf16(alo[kt], wh, a, 0, 0, 0);
      a = __builtin_amdgcn_mfma_f32_16x16x32_bf16(ahi[kt], wl, a, 0, 0, 0);
    }
    acc4[ct] = a;
  }
}

__global__ __launch_bounds__(256) void sa3f_kernel(
    const float* __restrict__ nx2, const float* __restrict__ f2,
    const float* __restrict__ W0full,
    const unsigned short* __restrict__ G0h, const unsigned short* __restrict__ G0l,
    const float* __restrict__ B0,
    const unsigned short* __restrict__ G1h, const unsigned short* __restrict__ G1l,
    const float* __restrict__ B1,
    const unsigned short* __restrict__ G2h, const unsigned short* __restrict__ G2l,
    const float* __restrict__ B2,
    float* __restrict__ partial) {
  constexpr int AS = 529;
  __shared__ __align__(16) float A[16 * AS];
  __shared__ float sxyz[16][4];
  const int t = threadIdx.x, l = t & 63, w = t >> 6;
  const int b = blockIdx.x >> 3, rb = blockIdx.x & 7;
  const int row0 = rb * 16;
  {
    int r = t >> 4, cc = (t & 15) * 16;
    const float* src = f2 + ((size_t)b * 128 + row0 + r) * 256 + cc;
    float* dstp = A + r * AS + cc;
#pragma unroll
    for (int j = 0; j < 16; j += 4)
      *reinterpret_cast<float4*>(dstp + j) = *reinterpret_cast<const float4*>(src + j);
    if (t < 16) {
      const float* s = nx2 + ((size_t)b * 128 + row0 + t) * 3;
      sxyz[t][0] = s[0]; sxyz[t][1] = s[1]; sxyz[t][2] = s[2];
    }
  }
  __syncthreads();

  {  // L1: K=256 MFMA + xyz f32 correction -> N=256 (wave cols 64)
    bf16x8 ah[8], al[8];
    sa3_frags(A, l, 8, ah, al);
    __syncthreads();
    f32x4 acc[4];
#pragma unroll
    for (int i = 0; i < 4; ++i) acc[i] = f32x4{0.f, 0.f, 0.f, 0.f};
    sa3_mm64<256>(G0h, G0l, w * 64, l, ah, al, acc);
    float xr[4][3];
#pragma unroll
    for (int r = 0; r < 4; ++r) {
      int row = (l >> 4) * 4 + r;
      xr[r][0] = sxyz[row][0]; xr[r][1] = sxyz[row][1]; xr[r][2] = sxyz[row][2];
    }
#pragma unroll
    for (int ct = 0; ct < 4; ++ct) {
      int col = w * 64 + ct * 16 + (l & 15);
      float w0 = W0full[col], w1 = W0full[256 + col], w2 = W0full[512 + col];
      float bia = B0[col];
#pragma unroll
      for (int r = 0; r < 4; ++r) {
        int row = (l >> 4) * 4 + r;
        float v = acc[ct][r] + xr[r][0] * w0 + xr[r][1] * w1 + xr[r][2] * w2 + bia;
        A[row * AS + col] = fmaxf(v, 0.f);
      }
    }
    __syncthreads();
  }

  {  // L2: K=256 -> N=512 (wave cols 128)
    bf16x8 ah[8], al[8];
    sa3_frags(A, l, 8, ah, al);
    __syncthreads();
    f32x4 acc[8];
#pragma unroll
    for (int i = 0; i < 8; ++i) acc[i] = f32x4{0.f, 0.f, 0.f, 0.f};
    sa3_mm64<256>(G1h, G1l, w * 128, l, ah, al, acc);
    sa3_mm64<256>(G1h, G1l, w * 128 + 64, l, ah, al, acc + 4);
#pragma unroll
    for (int cc = 0; cc < 8; ++cc) {
      int col = w * 128 + cc * 16 + (l & 15);
      float bia = B1[col];
#pragma unroll
      for (int r = 0; r < 4; ++r) {
        int row = (l >> 4) * 4 + r;
        A[row * AS + col] = fmaxf(acc[cc][r] + bia, 0.f);
      }
    }
    __syncthreads();
  }

  {  // L3: K=512 -> N=1024 (wave cols 256), maxpool 16 rows -> partial
    bf16x8 ah[16], al[16];
    sa3_frags(A, l, 16, ah, al);
    float* pout = partial + ((size_t)(b * 8 + rb)) * 1024;
#pragma unroll
    for (int sub = 0; sub < 4; ++sub) {
      f32x4 acc[4];
#pragma unroll
      for (int i = 0; i < 4; ++i) acc[i] = f32x4{0.f, 0.f, 0.f, 0.f};
      sa3_mm64<512>(G2h, G2l, w * 256 + sub * 64, l, ah, al, acc);
#pragma unroll
      for (int ct = 0; ct < 4; ++ct) {
        int col = w * 256 + sub * 64 + ct * 16 + (l & 15);
        float v = fmaxf(fmaxf(acc[ct][0], acc[ct][1]), fmaxf(acc[ct][2], acc[ct][3]));
        v = fmaxf(v, __shfl_xor(v, 16, 64));
        v = fmaxf(v, __shfl_xor(v, 32, 64));
        if (l < 16) pout[col] = v + B2[col];  // relu deferred to heads (monotone)
      }
    }
  }
}

// ---------------------------------------------------------------- heads (8-way partial max + relu + dots)
__global__ __launch_bounds__(256) void heads_kernel(const float* __restrict__ partial,
                                                    const float* __restrict__ cw,
                                                    const float* __restrict__ cb,
                                                    const float* __restrict__ rw,
                                                    const float* __restrict__ rb,
                                                    float* __restrict__ out) {
  const int b = blockIdx.x, t = threadIdx.x;
  const float* pb = partial + (size_t)b * 8 * 1024;
  float a0 = 0, a1 = 0, a2 = 0, a3 = 0, a4 = 0;
  for (int k = t; k < 1024; k += 256) {
    float m = pb[k];
#pragma unroll
    for (int p = 1; p < 8; ++p) m = fmaxf(m, pb[p * 1024 + k]);
    float f = fmaxf(m, 0.f);
    a0 += f * cw[k];
    const float* r = rw + (size_t)k * 4;
    a1 += f * r[0]; a2 += f * r[1]; a3 += f * r[2]; a4 += f * r[3];
  }
#pragma unroll
  for (int m = 32; m >= 1; m >>= 1) {
    a0 += __shfl_xor(a0, m, 64); a1 += __shfl_xor(a1, m, 64);
    a2 += __shfl_xor(a2, m, 64); a3 += __shfl_xor(a3, m, 64);
    a4 += __shfl_xor(a4, m, 64);
  }
  __shared__ float red[4][5];
  const int wv = t >> 6, ln = t & 63;
  if (ln == 0) { red[wv][0] = a0; red[wv][1] = a1; red[wv][2] = a2; red[wv][3] = a3; red[wv][4] = a4; }
  __syncthreads();
  if (t == 0) {
    float s0 = red[0][0] + red[1][0] + red[2][0] + red[3][0];
    float s1 = red[0][1] + red[1][1] + red[2][1] + red[3][1];
    float s2 = red[0][2] + red[1][2] + red[2][2] + red[3][2];
    float s3 = red[0][3] + red[1][3] + red[2][3] + red[3][3];
    float s4 = red[0][4] + red[1][4] + red[2][4] + red[3][4];
    out[b] = s0 + cb[0];
    out[32 + b * 4 + 0] = s1 + rb[0];
    out[32 + b * 4 + 1] = s2 + rb[1];
    out[32 + b * 4 + 2] = s3 + rb[2];
    out[32 + b * 4 + 3] = s4 + rb[3];
  }
}

// ---------------------------------------------------------------- launch
extern "C" void kernel_launch(void* const* d_in, const int* in_sizes, int n_in,
                              void* d_out, int out_size, void* d_ws, size_t ws_size,
                              hipStream_t stream) {
  (void)in_sizes; (void)n_in; (void)out_size; (void)ws_size;
  const float* xyz  = (const float*)d_in[0];
  const float* s1w0 = (const float*)d_in[1];  const float* s1b0 = (const float*)d_in[2];
  const float* s1w1 = (const float*)d_in[3];  const float* s1b1 = (const float*)d_in[4];
  const float* s1w2 = (const float*)d_in[5];  const float* s1b2 = (const float*)d_in[6];
  const float* s2w0 = (const float*)d_in[7];  const float* s2b0 = (const float*)d_in[8];
  const float* s2w1 = (const float*)d_in[9];  const float* s2b1 = (const float*)d_in[10];
  const float* s2w2 = (const float*)d_in[11]; const float* s2b2 = (const float*)d_in[12];
  const float* s3w0 = (const float*)d_in[13]; const float* s3b0 = (const float*)d_in[14];
  const float* s3w1 = (const float*)d_in[15]; const float* s3b1 = (const float*)d_in[16];
  const float* s3w2 = (const float*)d_in[17]; const float* s3b2 = (const float*)d_in[18];
  const float* clsw = (const float*)d_in[19]; const float* clsb = (const float*)d_in[20];
  const float* regw = (const float*)d_in[21]; const float* regb = (const float*)d_in[22];

  char* ws = (char*)d_ws;
  float* nx1   = (float*)(ws + 0);          // 32*512*3
  int*   gidx1 = (int*)  (ws + 196608);     // 32*512*32
  float* f1    = (float*)(ws + 2293760);    // 32*512*128
  float* nx2   = (float*)(ws + 10682368);   // 32*128*3
  int*   gidx2 = (int*)  (ws + 10731520);   // 32*128*64
  float* f2    = (float*)(ws + 11780096);   // 32*128*256

  // SA1/SA2 prepped weights (u16 hi/lo, transposed [n][k])
  unsigned short* wt = (unsigned short*)(ws + 20168704);
  unsigned short* g11h = wt;            // 64*64
  unsigned short* g11l = wt + 4096;
  unsigned short* g12h = wt + 8192;     // 128*64
  unsigned short* g12l = wt + 16384;
  unsigned short* g20h = wt + 24576;    // 128*128 (rows 3..130 of s2w0)
  unsigned short* g20l = wt + 40960;
  unsigned short* g21h = wt + 57344;    // 128*128
  unsigned short* g21l = wt + 73728;
  unsigned short* g22h = wt + 90112;    // 256*128
  unsigned short* g22l = wt + 122880;   // ends at byte 20168704+311296 = 20480000
  // SA3 prepped weights
  unsigned short* g30h = (unsigned short*)(ws + 20480000);  // 256x256
  unsigned short* g30l = (unsigned short*)(ws + 20611072);
  unsigned short* g31h = (unsigned short*)(ws + 20742144);  // 512x256
  unsigned short* g31l = (unsigned short*)(ws + 21004288);
  unsigned short* g32h = (unsigned short*)(ws + 21266432);  // 1024x512
  unsigned short* g32l = (unsigned short*)(ws + 22315008);
  float* partial = (float*)(ws + 23363584);                 // 32*8*1024 f32 -> ends 24412160

  const float r21 = (float)(0.2 * 0.2);
  const float r22 = (float)(0.4 * 0.4);

  WPTab tab;
  int off = 0;
  auto set = [&](int i, const float* W, unsigned short* hi, unsigned short* lo,
                 int K, int N, int row0) {
    tab.e[i] = WPEnt{W, hi, lo, K, N, row0, off, off + K * N};
    off += K * N;
  };
  set(0, s1w1, g11h, g11l, 64, 64, 0);
  set(1, s1w2, g12h, g12l, 64, 128, 0);
  set(2, s2w0, g20h, g20l, 128, 128, 3);
  set(3, s2w1, g21h, g21l, 128, 128, 0);
  set(4, s2w2, g22h, g22l, 128, 256, 0);
  set(5, s3w0, g30h, g30l, 256, 256, 3);
  set(6, s3w1, g31h, g31l, 256, 512, 0);
  set(7, s3w2, g32h, g32l, 512, 1024, 0);
  wprep8_kernel<<<(off + 255) / 256, 256, 0, stream>>>(tab);

  fps_kernel<4096, 512, 256, 2><<<16, 256, 0, stream>>>(xyz, nx1);
  bq_kernel<4096, 32><<<4096, 256, 0, stream>>>(xyz, nx1, gidx1, 512, r21);
  sa1_kernel<4096, 512, 32, 2><<<8192, 256, 0, stream>>>(
      xyz, nx1, gidx1, s1w0, s1b0, g11h, g11l, s1b1, g12h, g12l, s1b2, f1);
  fps_kernel<512, 128, 64, 2><<<16, 64, 0, stream>>>(nx1, nx2);
  bq_kernel<512, 64><<<1024, 256, 0, stream>>>(nx1, nx2, gidx2, 128, r22);
  sa_mfma_kernel<512, 128, 64, 1, 128, 128, 128, 256><<<4096, 256, 0, stream>>>(
      nx1, nx2, gidx2, f1, s2w0, s2b0,
      g20h, g20l, g21h, g21l, s2b1, g22h, g22l, s2b2, f2);
  sa3f_kernel<<<256, 256, 0, stream>>>(nx2, f2, s3w0, g30h, g30l, s3b0,
                                       g31h, g31l, s3b1, g32h, g32l, s3b2, partial);
  heads_kernel<<<32, 256, 0, stream>>>(partial, clsw, clsb, regw, regb, (float*)d_out);
}

// Round 9
// 804.972 us; speedup vs baseline: 1.7941x; 1.2747x over previous
//
#include <hip/hip_runtime.h>

#define DEVINL __device__ __forceinline__

typedef __attribute__((ext_vector_type(8))) short bf16x8;
typedef __attribute__((ext_vector_type(8))) unsigned short u16x8;
typedef __attribute__((ext_vector_type(4))) float f32x4;

// RNE f32 -> bf16 bits (no NaN handling needed for this workload)
DEVINL unsigned short f2bh(float f){
  unsigned u = __float_as_uint(f);
  return (unsigned short)((u + 0x7FFFu + ((u >> 16) & 1u)) >> 16);
}
DEVINL float bh2f(unsigned short h){ return __uint_as_float(((unsigned)h) << 16); }

// Wave64 max-reduce of a u64 key via DPP (VALU latency, no DS pipe).
DEVINL unsigned long long dpp_max_u64(unsigned long long k) {
#define DPP_STEP(ctrl)                                                        \
  {                                                                           \
    int hi = (int)(k >> 32), lo = (int)(unsigned)k;                           \
    int oh = __builtin_amdgcn_update_dpp(0, hi, ctrl, 0xF, 0xF, 1);           \
    int ol = __builtin_amdgcn_update_dpp(0, lo, ctrl, 0xF, 0xF, 1);           \
    unsigned long long ok =                                                   \
        ((unsigned long long)(unsigned)oh << 32) | (unsigned)ol;              \
    if (ok > k) k = ok;                                                       \
  }
  DPP_STEP(0x111)  // row_shr:1
  DPP_STEP(0x112)  // row_shr:2
  DPP_STEP(0x114)  // row_shr:4
  DPP_STEP(0x118)  // row_shr:8
  DPP_STEP(0x142)  // row_bcast:15
  DPP_STEP(0x143)  // row_bcast:31
#undef DPP_STEP
  return k;
}

// ---------------------------------------------------------------- FPS
// R4-proven config (293 us at NT=256, one block per batch): no global stores
// in the loop, DPP wave argmax, one barrier per step, double-buffered u64
// wave candidates. NT=64 has no barrier/LDS exchange. One block per batch --
// batches are already parallel across CUs; never co-locate chain instances.
template<int N, int NP, int NT>
__global__ __launch_bounds__(NT) void fps_kernel(const float* __restrict__ xyz,
                                                 float* __restrict__ nxyz) {
  constexpr int PTS = N / NT;
  constexpr int NW = NT / 64;
  const int b = blockIdx.x, t = threadIdx.x;
  __shared__ float xs[N], ys[N], zs[N];
  __shared__ int farr[NP];
  __shared__ unsigned long long sk[2][(NW > 1 ? NW : 1)];
  float px[PTS], py[PTS], pz[PTS], dst[PTS];
  const float* base = xyz + (size_t)b * N * 3;
#pragma unroll
  for (int j = 0; j < PTS; ++j) {
    int i = t + j * NT;
    float x = base[i * 3 + 0], y = base[i * 3 + 1], z = base[i * 3 + 2];
    px[j] = x; py[j] = y; pz[j] = z;
    xs[i] = x; ys[i] = y; zs[i] = z;
    dst[j] = 1e10f;
  }
  __syncthreads();
  int far = 0;
  const int wv = t >> 6, ln = t & 63;
  for (int s = 0; s < NP; ++s) {
    float cx = xs[far], cy = ys[far], cz = zs[far];
    if (t == 0) farr[s] = far;
    float bv = -1.f; int bi = 0;
#pragma unroll
    for (int j = 0; j < PTS; ++j) {
      // no-fma, left-to-right: matches numpy elementwise + sum order
      float dx = __fsub_rn(px[j], cx), dy = __fsub_rn(py[j], cy), dz = __fsub_rn(pz[j], cz);
      float d = __fadd_rn(__fadd_rn(__fmul_rn(dx, dx), __fmul_rn(dy, dy)), __fmul_rn(dz, dz));
      float nd = fminf(dst[j], d);
      dst[j] = nd;
      int i = t + j * NT;
      if (nd > bv) { bv = nd; bi = i; }  // strict >: first max kept per thread
    }
    // pack: max key == max dist, tie -> larger ~idx == smaller idx
    unsigned long long key =
        ((unsigned long long)__float_as_uint(bv) << 32) | (unsigned)(~bi);
    key = dpp_max_u64(key);
    if constexpr (NW == 1) {
      int rl = __builtin_amdgcn_readlane((int)(unsigned)key, 63);
      far = (int)(~(unsigned)rl);
    } else {
      const int p = s & 1;
      if (ln == 63) sk[p][wv] = key;
      __syncthreads();
      unsigned long long m = sk[p][0];
#pragma unroll
      for (int q = 1; q < NW; ++q) {
        unsigned long long qk = sk[p][q];
        if (qk > m) m = qk;
      }
      far = (int)(~(unsigned)m);
    }
  }
  __syncthreads();
  for (int s2 = t; s2 < NP; s2 += NT) {
    int fi = farr[s2];
    float* o = nxyz + ((size_t)b * NP + s2) * 3;
    o[0] = xs[fi]; o[1] = ys[fi]; o[2] = zs[fi];
  }
}

// ---------------------------------------------------------------- ball query (unchanged)
template<int N, int NS>
__global__ __launch_bounds__(256) void bq_kernel(const float* __restrict__ pts,
                                                 const float* __restrict__ centers,
                                                 int* __restrict__ gidx, int Q, float r2) {
  const int wv = threadIdx.x >> 6, ln = threadIdx.x & 63;
  const int g = blockIdx.x * 4 + wv;
  const int b = g / Q, q = g % Q;
  const float* pb = pts + (size_t)b * N * 3;
  const float* c = centers + ((size_t)b * Q + q) * 3;
  const float cx = c[0], cy = c[1], cz = c[2];
  __shared__ int gbuf[4][NS];
  int taken = 0;
  for (int base = 0; base < N; base += 64) {
    if (taken >= NS) break;
    int i = base + ln;
    float dx = __fsub_rn(pb[i * 3 + 0], cx), dy = __fsub_rn(pb[i * 3 + 1], cy),
          dz = __fsub_rn(pb[i * 3 + 2], cz);
    float d = __fadd_rn(__fadd_rn(__fmul_rn(dx, dx), __fmul_rn(dy, dy)), __fmul_rn(dz, dz));
    bool in = (d <= r2);
    unsigned long long mk = __ballot(in);
    int rank = __popcll(mk & ((1ull << ln) - 1ull));
    int pos = taken + rank;
    if (in && pos < NS) gbuf[wv][pos] = i;
    taken += (int)__popcll(mk);
  }
  int total = taken < NS ? taken : NS;
  int first = gbuf[wv][0];
  int* out = gidx + ((size_t)b * Q + q) * NS;
  for (int j = ln; j < NS; j += 64) out[j] = (j < total) ? gbuf[wv][j] : first;
}

// ---------------------------------------------------------------- weight prep (all 8 matrices, one launch)
struct WPEnt { const float* W; unsigned short* hi; unsigned short* lo; int K, N, row0, beg, end; };
struct WPTab { WPEnt e[8]; };
__global__ __launch_bounds__(256) void wprep8_kernel(WPTab tab) {
  int idx = blockIdx.x * 256 + threadIdx.x;
#pragma unroll
  for (int i = 0; i < 8; ++i) {
    const WPEnt& E = tab.e[i];
    if (idx >= E.beg && idx < E.end) {
      int local = idx - E.beg;
      int k = local / E.N, n = local - k * E.N;
      float v = E.W[(size_t)(E.row0 + k) * E.N + n];
      unsigned short h = f2bh(v);
      E.hi[(size_t)n * E.K + k] = h;
      E.lo[(size_t)n * E.K + k] = f2bh(v - bh2f(h));
    }
  }
}

// ---------------------------------------------------------------- split-bf16 MFMA layer (R5-proven: W chunk-staged in LDS)
template<int K, int N, int AS, int WS, bool XYZC>
DEVINL void do_layer(const unsigned short* __restrict__ Ghi, const unsigned short* __restrict__ Glo,
                     const float* __restrict__ Wxyz,
                     const float* __restrict__ A, unsigned short* __restrict__ Whi,
                     unsigned short* __restrict__ Wlo, const float* __restrict__ sxyz,
                     f32x4* acc, int t) {
  constexpr int KT = K / 32;
  constexpr int NCH = N / 64;
  const int l = t & 63, wv = t >> 6;
  bf16x8 ahi[KT], alo[KT];
  {
    const int row = wv * 16 + (l & 15);
    const float* ap = A + row * AS + (l >> 4) * 8;
#pragma unroll
    for (int kt = 0; kt < KT; ++kt) {
      float4 v0 = *reinterpret_cast<const float4*>(ap + kt * 32);
      float4 v1 = *reinterpret_cast<const float4*>(ap + kt * 32 + 4);
      float f[8] = {v0.x, v0.y, v0.z, v0.w, v1.x, v1.y, v1.z, v1.w};
      bf16x8 h, lo2;
#pragma unroll
      for (int j = 0; j < 8; ++j) {
        unsigned short hb = f2bh(f[j]);
        h[j] = (short)hb;
        lo2[j] = (short)f2bh(f[j] - bh2f(hb));
      }
      ahi[kt] = h; alo[kt] = lo2;
    }
  }
#pragma unroll
  for (int i = 0; i < N / 16; ++i) acc[i] = f32x4{0.f, 0.f, 0.f, 0.f};

#pragma unroll
  for (int c = 0; c < NCH; ++c) {
    __syncthreads();
    {
      constexpr int K8 = K / 8;
      for (int u = t; u < 64 * K8; u += 256) {
        int nn = u / K8, k8 = (u - nn * K8) * 8;
        *reinterpret_cast<u16x8*>(Whi + nn * WS + k8) =
            *reinterpret_cast<const u16x8*>(Ghi + (size_t)(c * 64 + nn) * K + k8);
        *reinterpret_cast<u16x8*>(Wlo + nn * WS + k8) =
            *reinterpret_cast<const u16x8*>(Glo + (size_t)(c * 64 + nn) * K + k8);
      }
    }
    __syncthreads();
#pragma unroll
    for (int ct = 0; ct < 4; ++ct) {
      const unsigned short* wp = Whi + (ct * 16 + (l & 15)) * WS + (l >> 4) * 8;
      const unsigned short* wq = Wlo + (ct * 16 + (l & 15)) * WS + (l >> 4) * 8;
      f32x4 a = acc[c * 4 + ct];
#pragma unroll
      for (int kt = 0; kt < KT; ++kt) {
        bf16x8 wh = *reinterpret_cast<const bf16x8*>(wp + kt * 32);
        bf16x8 wl = *reinterpret_cast<const bf16x8*>(wq + kt * 32);
        a = __builtin_amdgcn_mfma_f32_16x16x32_bf16(ahi[kt], wh, a, 0, 0, 0);
        a = __builtin_amdgcn_mfma_f32_16x16x32_bf16(alo[kt], wh, a, 0, 0, 0);
        a = __builtin_amdgcn_mfma_f32_16x16x32_bf16(ahi[kt], wl, a, 0, 0, 0);
      }
      acc[c * 4 + ct] = a;
    }
  }
  if constexpr (XYZC) {
    float xr[4][3];
#pragma unroll
    for (int r = 0; r < 4; ++r) {
      int row = wv * 16 + (l >> 4) * 4 + r;
      xr[r][0] = sxyz[row * 4 + 0];
      xr[r][1] = sxyz[row * 4 + 1];
      xr[r][2] = sxyz[row * 4 + 2];
    }
#pragma unroll
    for (int gt = 0; gt < N / 16; ++gt) {
      int col = gt * 16 + (l & 15);
      float w0 = Wxyz[col], w1 = Wxyz[N + col], w2 = Wxyz[2 * N + col];
#pragma unroll
      for (int r = 0; r < 4; ++r)
        acc[gt][r] += xr[r][0] * w0 + xr[r][1] * w1 + xr[r][2] * w2;
    }
  }
}

// ---------------------------------------------------------------- SA2 fused (R5-proven structure)
template<int NPTS, int Q, int M, int GPB, int FD, int C1, int C2, int C3>
__global__ __launch_bounds__(256) void sa_mfma_kernel(
    const float* __restrict__ pts, const float* __restrict__ centers,
    const int* __restrict__ gidx, const float* __restrict__ feats,
    const float* __restrict__ W0, const float* __restrict__ B0,
    const unsigned short* __restrict__ G0h, const unsigned short* __restrict__ G0l,
    const unsigned short* __restrict__ G1h, const unsigned short* __restrict__ G1l,
    const float* __restrict__ B1,
    const unsigned short* __restrict__ G2h, const unsigned short* __restrict__ G2l,
    const float* __restrict__ B2,
    float* __restrict__ fout) {
  static_assert(M * GPB == 64, "");
  constexpr int MK1 = (FD > C1 ? FD : C1);
  constexpr int MAXK = (MK1 > C2 ? MK1 : C2);
  constexpr int AS = MAXK + 8;
  constexpr int WS = MAXK + 8;
  __shared__ __align__(16) float A[64 * AS];
  __shared__ __align__(16) unsigned short Whi[64 * WS];
  __shared__ __align__(16) unsigned short Wlo[64 * WS];
  __shared__ float sxyz[64 * 4];
  __shared__ int idxs[64];
  __shared__ float ctr[GPB][4];
  __shared__ float red[4][C3];

  const int t = threadIdx.x;
  const int blk = blockIdx.x;
  const int b = blk / (Q / GPB);
  const int q0 = (blk % (Q / GPB)) * GPB;
  const int l = t & 63, wv = t >> 6;

  if (t < GPB * 3) {
    int g = t / 3, c2 = t % 3;
    ctr[g][c2] = centers[((size_t)b * Q + q0 + g) * 3 + c2];
  }
  for (int m = t; m < 64; m += 256)
    idxs[m] = gidx[((size_t)b * Q + q0 + (m / M)) * M + (m % M)];
  __syncthreads();
  const float* pb = pts + (size_t)b * NPTS * 3;
  for (int m = t; m < 64; m += 256) {
    int g = m / M, i = idxs[m];
    sxyz[m * 4 + 0] = pb[i * 3 + 0] - ctr[g][0];
    sxyz[m * 4 + 1] = pb[i * 3 + 1] - ctr[g][1];
    sxyz[m * 4 + 2] = pb[i * 3 + 2] - ctr[g][2];
  }
  if constexpr (FD > 0) {
    const int m = t >> 2, co = (t & 3) * (FD / 4);
    const float* src = feats + ((size_t)b * NPTS + idxs[m]) * FD + co;
    float* dst = A + m * AS + co;
#pragma unroll
    for (int j = 0; j < FD / 4; j += 4)
      *reinterpret_cast<float4*>(dst + j) = *reinterpret_cast<const float4*>(src + j);
  }
  __syncthreads();

  f32x4 acc[C3 / 16];

  if constexpr (FD == 0) {
    for (int u = t; u < 64 * C1; u += 256) {
      int m = u / C1, c2 = u - m * C1;
      float v = B0[c2] + sxyz[m * 4 + 0] * W0[0 * C1 + c2]
                       + sxyz[m * 4 + 1] * W0[1 * C1 + c2]
                       + sxyz[m * 4 + 2] * W0[2 * C1 + c2];
      A[m * AS + c2] = fmaxf(v, 0.f);
    }
    __syncthreads();
  } else {
    do_layer<FD, C1, AS, WS, true>(G0h, G0l, W0, A, Whi, Wlo, sxyz, acc, t);
#pragma unroll
    for (int gt = 0; gt < C1 / 16; ++gt) {
      int col = gt * 16 + (l & 15);
      float bia = B0[col];
#pragma unroll
      for (int r = 0; r < 4; ++r)
        A[(wv * 16 + (l >> 4) * 4 + r) * AS + col] = fmaxf(acc[gt][r] + bia, 0.f);
    }
  }

  do_layer<C1, C2, AS, WS, false>(G1h, G1l, nullptr, A, Whi, Wlo, sxyz, acc, t);
#pragma unroll
  for (int gt = 0; gt < C2 / 16; ++gt) {
    int col = gt * 16 + (l & 15);
    float bia = B1[col];
#pragma unroll
    for (int r = 0; r < 4; ++r)
      A[(wv * 16 + (l >> 4) * 4 + r) * AS + col] = fmaxf(acc[gt][r] + bia, 0.f);
  }

  do_layer<C2, C3, AS, WS, false>(G2h, G2l, nullptr, A, Whi, Wlo, sxyz, acc, t);
#pragma unroll
  for (int gt = 0; gt < C3 / 16; ++gt) {
    int col = gt * 16 + (l & 15);
    float v = fmaxf(fmaxf(acc[gt][0], acc[gt][1]), fmaxf(acc[gt][2], acc[gt][3]));
    v = fmaxf(v, __shfl_xor(v, 16, 64));
    v = fmaxf(v, __shfl_xor(v, 32, 64));
    if (l < 16) red[wv][col] = v + B2[col];
  }
  __syncthreads();
  constexpr int WPG = 4 / GPB;
  for (int u = t; u < GPB * C3; u += 256) {
    int g = u / C3, c2 = u - g * C3;
    float v = red[g * WPG][c2];
#pragma unroll
    for (int w = 1; w < WPG; ++w) v = fmaxf(v, red[g * WPG + w][c2]);
    fout[((size_t)b * Q + q0 + g) * C3 + c2] = fmaxf(v, 0.f);
  }
}

// ---------------------------------------------------------------- SA1 fused, ALL weights staged in LDS once
template<int NPTS, int Q, int M, int GPB>
__global__ __launch_bounds__(256) void sa1_kernel(
    const float* __restrict__ pts, const float* __restrict__ centers,
    const int* __restrict__ gidx,
    const float* __restrict__ W0, const float* __restrict__ B0,
    const unsigned short* __restrict__ G1h, const unsigned short* __restrict__ G1l,
    const float* __restrict__ B1,
    const unsigned short* __restrict__ G2h, const unsigned short* __restrict__ G2l,
    const float* __restrict__ B2,
    float* __restrict__ fout) {
  static_assert(M * GPB == 64, "");
  constexpr int C1 = 64, C2 = 64, C3 = 128;
  constexpr int AS = 72;
  constexpr int WS = 72;
  constexpr int NC = C2 + C3;
  __shared__ __align__(16) float A[64 * AS];
  __shared__ __align__(16) unsigned short Wh[NC * WS];
  __shared__ __align__(16) unsigned short Wl[NC * WS];
  __shared__ float sxyz[64 * 4];
  __shared__ int idxs[64];
  __shared__ float ctr[GPB][4];
  __shared__ float red[4][C3];

  const int t = threadIdx.x, l = t & 63, wv = t >> 6;
  const int blk = blockIdx.x;
  const int b = blk / (Q / GPB);
  const int q0 = (blk % (Q / GPB)) * GPB;

  if (t < GPB * 3) {
    int g = t / 3, c2 = t % 3;
    ctr[g][c2] = centers[((size_t)b * Q + q0 + g) * 3 + c2];
  }
  for (int m = t; m < 64; m += 256)
    idxs[m] = gidx[((size_t)b * Q + q0 + (m / M)) * M + (m % M)];
  for (int u = t; u < NC * 8; u += 256) {
    int col = u >> 3, k8 = (u & 7) * 8;
    const unsigned short* sh = (col < C2) ? G1h + (size_t)col * 64 + k8
                                          : G2h + (size_t)(col - C2) * 64 + k8;
    const unsigned short* sl = (col < C2) ? G1l + (size_t)col * 64 + k8
                                          : G2l + (size_t)(col - C2) * 64 + k8;
    *reinterpret_cast<u16x8*>(Wh + col * WS + k8) = *reinterpret_cast<const u16x8*>(sh);
    *reinterpret_cast<u16x8*>(Wl + col * WS + k8) = *reinterpret_cast<const u16x8*>(sl);
  }
  __syncthreads();
  const float* pb = pts + (size_t)b * NPTS * 3;
  for (int m = t; m < 64; m += 256) {
    int g = m / M, i = idxs[m];
    sxyz[m * 4 + 0] = pb[i * 3 + 0] - ctr[g][0];
    sxyz[m * 4 + 1] = pb[i * 3 + 1] - ctr[g][1];
    sxyz[m * 4 + 2] = pb[i * 3 + 2] - ctr[g][2];
  }
  __syncthreads();

  // layer0: 3 -> 64 in exact f32 VALU
  for (int u = t; u < 64 * C1; u += 256) {
    int m = u / C1, c2 = u - m * C1;
    float v = B0[c2] + sxyz[m * 4 + 0] * W0[0 * C1 + c2]
                     + sxyz[m * 4 + 1] * W0[1 * C1 + c2]
                     + sxyz[m * 4 + 2] * W0[2 * C1 + c2];
    A[m * AS + c2] = fmaxf(v, 0.f);
  }
  __syncthreads();

  f32x4 acc[8];
  // ---- L2: 64 -> 64, W cols [0,64), barrier-free
  {
    bf16x8 ah[2], al[2];
    const float* ap = A + (wv * 16 + (l & 15)) * AS + (l >> 4) * 8;
#pragma unroll
    for (int kt = 0; kt < 2; ++kt) {
      float4 v0 = *reinterpret_cast<const float4*>(ap + kt * 32);
      float4 v1 = *reinterpret_cast<const float4*>(ap + kt * 32 + 4);
      float f[8] = {v0.x, v0.y, v0.z, v0.w, v1.x, v1.y, v1.z, v1.w};
      bf16x8 h, lo2;
#pragma unroll
      for (int j = 0; j < 8; ++j) {
        unsigned short hb = f2bh(f[j]);
        h[j] = (short)hb;
        lo2[j] = (short)f2bh(f[j] - bh2f(hb));
      }
      ah[kt] = h; al[kt] = lo2;
    }
#pragma unroll
    for (int i = 0; i < 4; ++i) acc[i] = f32x4{0.f, 0.f, 0.f, 0.f};
#pragma unroll
    for (int ct = 0; ct < 4; ++ct) {
      const unsigned short* wp = Wh + (ct * 16 + (l & 15)) * WS + (l >> 4) * 8;
      const unsigned short* wq = Wl + (ct * 16 + (l & 15)) * WS + (l >> 4) * 8;
      f32x4 a = acc[ct];
#pragma unroll
      for (int kt = 0; kt < 2; ++kt) {
        bf16x8 wh = *reinterpret_cast<const bf16x8*>(wp + kt * 32);
        bf16x8 wl = *reinterpret_cast<const bf16x8*>(wq + kt * 32);
        a = __builtin_amdgcn_mfma_f32_16x16x32_bf16(ah[kt], wh, a, 0, 0, 0);
        a = __builtin_amdgcn_mfma_f32_16x16x32_bf16(al[kt], wh, a, 0, 0, 0);
        a = __builtin_amdgcn_mfma_f32_16x16x32_bf16(ah[kt], wl, a, 0, 0, 0);
      }
      acc[ct] = a;
    }
#pragma unroll
    for (int gt = 0; gt < 4; ++gt) {
      int col = gt * 16 + (l & 15);
      float bia = B1[col];
#pragma unroll
      for (int r = 0; r < 4; ++r)
        A[(wv * 16 + (l >> 4) * 4 + r) * AS + col] = fmaxf(acc[gt][r] + bia, 0.f);
    }
  }

  // ---- L3: 64 -> 128, W cols [64,192), maxpool epilogue
  {
    bf16x8 ah[2], al[2];
    const float* ap = A + (wv * 16 + (l & 15)) * AS + (l >> 4) * 8;
#pragma unroll
    for (int kt = 0; kt < 2; ++kt) {
      float4 v0 = *reinterpret_cast<const float4*>(ap + kt * 32);
      float4 v1 = *reinterpret_cast<const float4*>(ap + kt * 32 + 4);
      float f[8] = {v0.x, v0.y, v0.z, v0.w, v1.x, v1.y, v1.z, v1.w};
      bf16x8 h, lo2;
#pragma unroll
      for (int j = 0; j < 8; ++j) {
        unsigned short hb = f2bh(f[j]);
        h[j] = (short)hb;
        lo2[j] = (short)f2bh(f[j] - bh2f(hb));
      }
      ah[kt] = h; al[kt] = lo2;
    }
#pragma unroll
    for (int i = 0; i < 8; ++i) acc[i] = f32x4{0.f, 0.f, 0.f, 0.f};
#pragma unroll
    for (int gt = 0; gt < 8; ++gt) {
      const unsigned short* wp = Wh + (C2 + gt * 16 + (l & 15)) * WS + (l >> 4) * 8;
      const unsigned short* wq = Wl + (C2 + gt * 16 + (l & 15)) * WS + (l >> 4) * 8;
      f32x4 a = acc[gt];
#pragma unroll
      for (int kt = 0; kt < 2; ++kt) {
        bf16x8 wh = *reinterpret_cast<const bf16x8*>(wp + kt * 32);
        bf16x8 wl = *reinterpret_cast<const bf16x8*>(wq + kt * 32);
        a = __builtin_amdgcn_mfma_f32_16x16x32_bf16(ah[kt], wh, a, 0, 0, 0);
        a = __builtin_amdgcn_mfma_f32_16x16x32_bf16(al[kt], wh, a, 0, 0, 0);
        a = __builtin_amdgcn_mfma_f32_16x16x32_bf16(ah[kt], wl, a, 0, 0, 0);
      }
      acc[gt] = a;
    }
#pragma unroll
    for (int gt = 0; gt < 8; ++gt) {
      int col = gt * 16 + (l & 15);
      float v = fmaxf(fmaxf(acc[gt][0], acc[gt][1]), fmaxf(acc[gt][2], acc[gt][3]));
      v = fmaxf(v, __shfl_xor(v, 16, 64));
      v = fmaxf(v, __shfl_xor(v, 32, 64));
      if (l < 16) red[wv][col] = v + B2[col];
    }
  }
  __syncthreads();
  constexpr int WPG = 4 / GPB;
  for (int u = t; u < GPB * C3; u += 256) {
    int g = u / C3, c2 = u - g * C3;
    float v = red[g * WPG][c2];
#pragma unroll
    for (int w = 1; w < WPG; ++w) v = fmaxf(v, red[g * WPG + w][c2]);
    fout[((size_t)b * Q + q0 + g) * C3 + c2] = fmaxf(v, 0.f);
  }
}

// ---------------------------------------------------------------- SA3 fused (split-bf16 MFMA, W frags from global)
DEVINL void sa3_frags(const float* __restrict__ A, int l, int KT, bf16x8* ahi, bf16x8* alo) {
  const float* ap = A + (l & 15) * 529 + (l >> 4) * 8;
  for (int kt = 0; kt < KT; ++kt) {
    float4 v0 = *reinterpret_cast<const float4*>(ap + kt * 32);
    float4 v1 = *reinterpret_cast<const float4*>(ap + kt * 32 + 4);
    float f[8] = {v0.x, v0.y, v0.z, v0.w, v1.x, v1.y, v1.z, v1.w};
    bf16x8 h, lo2;
#pragma unroll
    for (int j = 0; j < 8; ++j) {
      unsigned short hb = f2bh(f[j]);
      h[j] = (short)hb;
      lo2[j] = (short)f2bh(f[j] - bh2f(hb));
    }
    ahi[kt] = h; alo[kt] = lo2;
  }
}

template<int K>
DEVINL void sa3_mm64(const unsigned short* __restrict__ Gh, const unsigned short* __restrict__ Gl,
                     int ncol0, int l, const bf16x8* ahi, const bf16x8* alo, f32x4* acc4) {
  constexpr int KT = K / 32;
#pragma unroll
  for (int ct = 0; ct < 4; ++ct) {
    const unsigned short* hp = Gh + (size_t)(ncol0 + ct * 16 + (l & 15)) * K + (l >> 4) * 8;
    const unsigned short* lp = Gl + (size_t)(ncol0 + ct * 16 + (l & 15)) * K + (l >> 4) * 8;
    f32x4 a = acc4[ct];
#pragma unroll
    for (int kt = 0; kt < KT; ++kt) {
      bf16x8 wh = *reinterpret_cast<const bf16x8*>(hp + kt * 32);
      bf16x8 wl = *reinterpret_cast<const bf16x8*>(lp + kt * 32);
      a = __builtin_amdgcn_mfma_f32_16x16x32_bf16(ahi[kt], wh, a, 0, 0, 0);
      a = __builtin_amdgcn_mfma_f32_16x16x32_bf16(alo[kt], wh, a, 0, 0, 0);
      a = __builtin_amdgcn_mfma_f32_16x16x32_bf16(ahi[kt], wl, a, 0, 0, 0);
    }
    acc4[ct] = a;
  }
}

__global__ __launch_bounds__(256) void sa3f_kernel(
    const float* __restrict__ nx2, const float* __restrict__ f2,
    const float* __restrict__ W0full,
    const unsigned short* __restrict__ G0h, const unsigned short* __restrict__ G0l,
    const float* __restrict__ B0,
    const unsigned short* __restrict__ G1h, const unsigned short* __restrict__ G1l,
    const float* __restrict__ B1,
    const unsigned short* __restrict__ G2h, const unsigned short* __restrict__ G2l,
    const float* __restrict__ B2,
    float* __restrict__ partial) {
  constexpr int AS = 529;
  __shared__ __align__(16) float A[16 * AS];
  __shared__ float sxyz[16][4];
  const int t = threadIdx.x, l = t & 63, w = t >> 6;
  const int b = blockIdx.x >> 3, rb = blockIdx.x & 7;
  const int row0 = rb * 16;
  {
    int r = t >> 4, cc = (t & 15) * 16;
    const float* src = f2 + ((size_t)b * 128 + row0 + r) * 256 + cc;
    float* dstp = A + r * AS + cc;
#pragma unroll
    for (int j = 0; j < 16; j += 4)
      *reinterpret_cast<float4*>(dstp + j) = *reinterpret_cast<const float4*>(src + j);
    if (t < 16) {
      const float* s = nx2 + ((size_t)b * 128 + row0 + t) * 3;
      sxyz[t][0] = s[0]; sxyz[t][1] = s[1]; sxyz[t][2] = s[2];
    }
  }
  __syncthreads();

  {  // L1: K=256 MFMA + xyz f32 correction -> N=256 (wave cols 64)
    bf16x8 ah[8], al[8];
    sa3_frags(A, l, 8, ah, al);
    __syncthreads();
    f32x4 acc[4];
#pragma unroll
    for (int i = 0; i < 4; ++i) acc[i] = f32x4{0.f, 0.f, 0.f, 0.f};
    sa3_mm64<256>(G0h, G0l, w * 64, l, ah, al, acc);
    float xr[4][3];
#pragma unroll
    for (int r = 0; r < 4; ++r) {
      int row = (l >> 4) * 4 + r;
      xr[r][0] = sxyz[row][0]; xr[r][1] = sxyz[row][1]; xr[r][2] = sxyz[row][2];
    }
#pragma unroll
    for (int ct = 0; ct < 4; ++ct) {
      int col = w * 64 + ct * 16 + (l & 15);
      float w0 = W0full[col], w1 = W0full[256 + col], w2 = W0full[512 + col];
      float bia = B0[col];
#pragma unroll
      for (int r = 0; r < 4; ++r) {
        int row = (l >> 4) * 4 + r;
        float v = acc[ct][r] + xr[r][0] * w0 + xr[r][1] * w1 + xr[r][2] * w2 + bia;
        A[row * AS + col] = fmaxf(v, 0.f);
      }
    }
    __syncthreads();
  }

  {  // L2: K=256 -> N=512 (wave cols 128)
    bf16x8 ah[8], al[8];
    sa3_frags(A, l, 8, ah, al);
    __syncthreads();
    f32x4 acc[8];
#pragma unroll
    for (int i = 0; i < 8; ++i) acc[i] = f32x4{0.f, 0.f, 0.f, 0.f};
    sa3_mm64<256>(G1h, G1l, w * 128, l, ah, al, acc);
    sa3_mm64<256>(G1h, G1l, w * 128 + 64, l, ah, al, acc + 4);
#pragma unroll
    for (int cc = 0; cc < 8; ++cc) {
      int col = w * 128 + cc * 16 + (l & 15);
      float bia = B1[col];
#pragma unroll
      for (int r = 0; r < 4; ++r) {
        int row = (l >> 4) * 4 + r;
        A[row * AS + col] = fmaxf(acc[cc][r] + bia, 0.f);
      }
    }
    __syncthreads();
  }

  {  // L3: K=512 -> N=1024 (wave cols 256), maxpool 16 rows -> partial
    bf16x8 ah[16], al[16];
    sa3_frags(A, l, 16, ah, al);
    float* pout = partial + ((size_t)(b * 8 + rb)) * 1024;
#pragma unroll
    for (int sub = 0; sub < 4; ++sub) {
      f32x4 acc[4];
#pragma unroll
      for (int i = 0; i < 4; ++i) acc[i] = f32x4{0.f, 0.f, 0.f, 0.f};
      sa3_mm64<512>(G2h, G2l, w * 256 + sub * 64, l, ah, al, acc);
#pragma unroll
      for (int ct = 0; ct < 4; ++ct) {
        int col = w * 256 + sub * 64 + ct * 16 + (l & 15);
        float v = fmaxf(fmaxf(acc[ct][0], acc[ct][1]), fmaxf(acc[ct][2], acc[ct][3]));
        v = fmaxf(v, __shfl_xor(v, 16, 64));
        v = fmaxf(v, __shfl_xor(v, 32, 64));
        if (l < 16) pout[col] = v + B2[col];  // relu deferred to heads (monotone)
      }
    }
  }
}

// ---------------------------------------------------------------- heads (8-way partial max + relu + dots)
__global__ __launch_bounds__(256) void heads_kernel(const float* __restrict__ partial,
                                                    const float* __restrict__ cw,
                                                    const float* __restrict__ cb,
                                                    const float* __restrict__ rw,
                                                    const float* __restrict__ rb,
                                                    float* __restrict__ out) {
  const int b = blockIdx.x, t = threadIdx.x;
  const float* pb = partial + (size_t)b * 8 * 1024;
  float a0 = 0, a1 = 0, a2 = 0, a3 = 0, a4 = 0;
  for (int k = t; k < 1024; k += 256) {
    float m = pb[k];
#pragma unroll
    for (int p = 1; p < 8; ++p) m = fmaxf(m, pb[p * 1024 + k]);
    float f = fmaxf(m, 0.f);
    a0 += f * cw[k];
    const float* r = rw + (size_t)k * 4;
    a1 += f * r[0]; a2 += f * r[1]; a3 += f * r[2]; a4 += f * r[3];
  }
#pragma unroll
  for (int m = 32; m >= 1; m >>= 1) {
    a0 += __shfl_xor(a0, m, 64); a1 += __shfl_xor(a1, m, 64);
    a2 += __shfl_xor(a2, m, 64); a3 += __shfl_xor(a3, m, 64);
    a4 += __shfl_xor(a4, m, 64);
  }
  __shared__ float red[4][5];
  const int wv = t >> 6, ln = t & 63;
  if (ln == 0) { red[wv][0] = a0; red[wv][1] = a1; red[wv][2] = a2; red[wv][3] = a3; red[wv][4] = a4; }
  __syncthreads();
  if (t == 0) {
    float s0 = red[0][0] + red[1][0] + red[2][0] + red[3][0];
    float s1 = red[0][1] + red[1][1] + red[2][1] + red[3][1];
    float s2 = red[0][2] + red[1][2] + red[2][2] + red[3][2];
    float s3 = red[0][3] + red[1][3] + red[2][3] + red[3][3];
    float s4 = red[0][4] + red[1][4] + red[2][4] + red[3][4];
    out[b] = s0 + cb[0];
    out[32 + b * 4 + 0] = s1 + rb[0];
    out[32 + b * 4 + 1] = s2 + rb[1];
    out[32 + b * 4 + 2] = s3 + rb[2];
    out[32 + b * 4 + 3] = s4 + rb[3];
  }
}

// ---------------------------------------------------------------- launch
extern "C" void kernel_launch(void* const* d_in, const int* in_sizes, int n_in,
                              void* d_out, int out_size, void* d_ws, size_t ws_size,
                              hipStream_t stream) {
  (void)in_sizes; (void)n_in; (void)out_size; (void)ws_size;
  const float* xyz  = (const float*)d_in[0];
  const float* s1w0 = (const float*)d_in[1];  const float* s1b0 = (const float*)d_in[2];
  const float* s1w1 = (const float*)d_in[3];  const float* s1b1 = (const float*)d_in[4];
  const float* s1w2 = (const float*)d_in[5];  const float* s1b2 = (const float*)d_in[6];
  const float* s2w0 = (const float*)d_in[7];  const float* s2b0 = (const float*)d_in[8];
  const float* s2w1 = (const float*)d_in[9];  const float* s2b1 = (const float*)d_in[10];
  const float* s2w2 = (const float*)d_in[11]; const float* s2b2 = (const float*)d_in[12];
  const float* s3w0 = (const float*)d_in[13]; const float* s3b0 = (const float*)d_in[14];
  const float* s3w1 = (const float*)d_in[15]; const float* s3b1 = (const float*)d_in[16];
  const float* s3w2 = (const float*)d_in[17]; const float* s3b2 = (const float*)d_in[18];
  const float* clsw = (const float*)d_in[19]; const float* clsb = (const float*)d_in[20];
  const float* regw = (const float*)d_in[21]; const float* regb = (const float*)d_in[22];

  char* ws = (char*)d_ws;
  float* nx1   = (float*)(ws + 0);          // 32*512*3
  int*   gidx1 = (int*)  (ws + 196608);     // 32*512*32
  float* f1    = (float*)(ws + 2293760);    // 32*512*128
  float* nx2   = (float*)(ws + 10682368);   // 32*128*3
  int*   gidx2 = (int*)  (ws + 10731520);   // 32*128*64
  float* f2    = (float*)(ws + 11780096);   // 32*128*256

  // SA1/SA2 prepped weights (u16 hi/lo, transposed [n][k])
  unsigned short* wt = (unsigned short*)(ws + 20168704);
  unsigned short* g11h = wt;            // 64*64
  unsigned short* g11l = wt + 4096;
  unsigned short* g12h = wt + 8192;     // 128*64
  unsigned short* g12l = wt + 16384;
  unsigned short* g20h = wt + 24576;    // 128*128 (rows 3..130 of s2w0)
  unsigned short* g20l = wt + 40960;
  unsigned short* g21h = wt + 57344;    // 128*128
  unsigned short* g21l = wt + 73728;
  unsigned short* g22h = wt + 90112;    // 256*128
  unsigned short* g22l = wt + 122880;   // ends at byte 20168704+311296 = 20480000
  // SA3 prepped weights
  unsigned short* g30h = (unsigned short*)(ws + 20480000);  // 256x256
  unsigned short* g30l = (unsigned short*)(ws + 20611072);
  unsigned short* g31h = (unsigned short*)(ws + 20742144);  // 512x256
  unsigned short* g31l = (unsigned short*)(ws + 21004288);
  unsigned short* g32h = (unsigned short*)(ws + 21266432);  // 1024x512
  unsigned short* g32l = (unsigned short*)(ws + 22315008);
  float* partial = (float*)(ws + 23363584);                 // 32*8*1024 f32 -> ends 24412160

  const float r21 = (float)(0.2 * 0.2);
  const float r22 = (float)(0.4 * 0.4);

  WPTab tab;
  int off = 0;
  auto set = [&](int i, const float* W, unsigned short* hi, unsigned short* lo,
                 int K, int N, int row0) {
    tab.e[i] = WPEnt{W, hi, lo, K, N, row0, off, off + K * N};
    off += K * N;
  };
  set(0, s1w1, g11h, g11l, 64, 64, 0);
  set(1, s1w2, g12h, g12l, 64, 128, 0);
  set(2, s2w0, g20h, g20l, 128, 128, 3);
  set(3, s2w1, g21h, g21l, 128, 128, 0);
  set(4, s2w2, g22h, g22l, 128, 256, 0);
  set(5, s3w0, g30h, g30l, 256, 256, 3);
  set(6, s3w1, g31h, g31l, 256, 512, 0);
  set(7, s3w2, g32h, g32l, 512, 1024, 0);
  wprep8_kernel<<<(off + 255) / 256, 256, 0, stream>>>(tab);

  fps_kernel<4096, 512, 256><<<32, 256, 0, stream>>>(xyz, nx1);
  bq_kernel<4096, 32><<<4096, 256, 0, stream>>>(xyz, nx1, gidx1, 512, r21);
  sa1_kernel<4096, 512, 32, 2><<<8192, 256, 0, stream>>>(
      xyz, nx1, gidx1, s1w0, s1b0, g11h, g11l, s1b1, g12h, g12l, s1b2, f1);
  fps_kernel<512, 128, 64><<<32, 64, 0, stream>>>(nx1, nx2);
  bq_kernel<512, 64><<<1024, 256, 0, stream>>>(nx1, nx2, gidx2, 128, r22);
  sa_mfma_kernel<512, 128, 64, 1, 128, 128, 128, 256><<<4096, 256, 0, stream>>>(
      nx1, nx2, gidx2, f1, s2w0, s2b0,
      g20h, g20l, g21h, g21l, s2b1, g22h, g22l, s2b2, f2);
  sa3f_kernel<<<256, 256, 0, stream>>>(nx2, f2, s3w0, g30h, g30l, s3b0,
                                       g31h, g31l, s3b1, g32h, g32l, s3b2, partial);
  heads_kernel<<<32, 256, 0, stream>>>(partial, clsw, clsb, regw, regb, (float*)d_out);
}

// Round 10
// 800.465 us; speedup vs baseline: 1.8042x; 1.0056x over previous
//
#include <hip/hip_runtime.h>

#define DEVINL __device__ __forceinline__

typedef __attribute__((ext_vector_type(8))) short bf16x8;
typedef __attribute__((ext_vector_type(8))) unsigned short u16x8;
typedef __attribute__((ext_vector_type(4))) float f32x4;

// RNE f32 -> bf16 bits (no NaN handling needed for this workload)
DEVINL unsigned short f2bh(float f){
  unsigned u = __float_as_uint(f);
  return (unsigned short)((u + 0x7FFFu + ((u >> 16) & 1u)) >> 16);
}
DEVINL float bh2f(unsigned short h){ return __uint_as_float(((unsigned)h) << 16); }

// Wave64 max-reduce of a u64 key via DPP (VALU latency, no DS pipe).
DEVINL unsigned long long dpp_max_u64(unsigned long long k) {
#define DPP_STEP(ctrl)                                                        \
  {                                                                           \
    int hi = (int)(k >> 32), lo = (int)(unsigned)k;                           \
    int oh = __builtin_amdgcn_update_dpp(0, hi, ctrl, 0xF, 0xF, 1);           \
    int ol = __builtin_amdgcn_update_dpp(0, lo, ctrl, 0xF, 0xF, 1);           \
    unsigned long long ok =                                                   \
        ((unsigned long long)(unsigned)oh << 32) | (unsigned)ol;              \
    if (ok > k) k = ok;                                                       \
  }
  DPP_STEP(0x111)  // row_shr:1
  DPP_STEP(0x112)  // row_shr:2
  DPP_STEP(0x114)  // row_shr:4
  DPP_STEP(0x118)  // row_shr:8
  DPP_STEP(0x142)  // row_bcast:15
  DPP_STEP(0x143)  // row_bcast:31
#undef DPP_STEP
  return k;
}

// ---------------------------------------------------------------- FPS (FROZEN R4 config, 293 us)
template<int N, int NP, int NT>
__global__ __launch_bounds__(NT) void fps_kernel(const float* __restrict__ xyz,
                                                 float* __restrict__ nxyz) {
  constexpr int PTS = N / NT;
  constexpr int NW = NT / 64;
  const int b = blockIdx.x, t = threadIdx.x;
  __shared__ float xs[N], ys[N], zs[N];
  __shared__ int farr[NP];
  __shared__ unsigned long long sk[2][(NW > 1 ? NW : 1)];
  float px[PTS], py[PTS], pz[PTS], dst[PTS];
  const float* base = xyz + (size_t)b * N * 3;
#pragma unroll
  for (int j = 0; j < PTS; ++j) {
    int i = t + j * NT;
    float x = base[i * 3 + 0], y = base[i * 3 + 1], z = base[i * 3 + 2];
    px[j] = x; py[j] = y; pz[j] = z;
    xs[i] = x; ys[i] = y; zs[i] = z;
    dst[j] = 1e10f;
  }
  __syncthreads();
  int far = 0;
  const int wv = t >> 6, ln = t & 63;
  for (int s = 0; s < NP; ++s) {
    float cx = xs[far], cy = ys[far], cz = zs[far];
    if (t == 0) farr[s] = far;
    float bv = -1.f; int bi = 0;
#pragma unroll
    for (int j = 0; j < PTS; ++j) {
      // no-fma, left-to-right: matches numpy elementwise + sum order
      float dx = __fsub_rn(px[j], cx), dy = __fsub_rn(py[j], cy), dz = __fsub_rn(pz[j], cz);
      float d = __fadd_rn(__fadd_rn(__fmul_rn(dx, dx), __fmul_rn(dy, dy)), __fmul_rn(dz, dz));
      float nd = fminf(dst[j], d);
      dst[j] = nd;
      int i = t + j * NT;
      if (nd > bv) { bv = nd; bi = i; }  // strict >: first max kept per thread
    }
    // pack: max key == max dist, tie -> larger ~idx == smaller idx
    unsigned long long key =
        ((unsigned long long)__float_as_uint(bv) << 32) | (unsigned)(~bi);
    key = dpp_max_u64(key);
    if constexpr (NW == 1) {
      int rl = __builtin_amdgcn_readlane((int)(unsigned)key, 63);
      far = (int)(~(unsigned)rl);
    } else {
      const int p = s & 1;
      if (ln == 63) sk[p][wv] = key;
      __syncthreads();
      unsigned long long m = sk[p][0];
#pragma unroll
      for (int q = 1; q < NW; ++q) {
        unsigned long long qk = sk[p][q];
        if (qk > m) m = qk;
      }
      far = (int)(~(unsigned)m);
    }
  }
  __syncthreads();
  for (int s2 = t; s2 < NP; s2 += NT) {
    int fi = farr[s2];
    float* o = nxyz + ((size_t)b * NP + s2) * 3;
    o[0] = xs[fi]; o[1] = ys[fi]; o[2] = zs[fi];
  }
}

// ---------------------------------------------------------------- ball query (unchanged)
template<int N, int NS>
__global__ __launch_bounds__(256) void bq_kernel(const float* __restrict__ pts,
                                                 const float* __restrict__ centers,
                                                 int* __restrict__ gidx, int Q, float r2) {
  const int wv = threadIdx.x >> 6, ln = threadIdx.x & 63;
  const int g = blockIdx.x * 4 + wv;
  const int b = g / Q, q = g % Q;
  const float* pb = pts + (size_t)b * N * 3;
  const float* c = centers + ((size_t)b * Q + q) * 3;
  const float cx = c[0], cy = c[1], cz = c[2];
  __shared__ int gbuf[4][NS];
  int taken = 0;
  for (int base = 0; base < N; base += 64) {
    if (taken >= NS) break;
    int i = base + ln;
    float dx = __fsub_rn(pb[i * 3 + 0], cx), dy = __fsub_rn(pb[i * 3 + 1], cy),
          dz = __fsub_rn(pb[i * 3 + 2], cz);
    float d = __fadd_rn(__fadd_rn(__fmul_rn(dx, dx), __fmul_rn(dy, dy)), __fmul_rn(dz, dz));
    bool in = (d <= r2);
    unsigned long long mk = __ballot(in);
    int rank = __popcll(mk & ((1ull << ln) - 1ull));
    int pos = taken + rank;
    if (in && pos < NS) gbuf[wv][pos] = i;
    taken += (int)__popcll(mk);
  }
  int total = taken < NS ? taken : NS;
  int first = gbuf[wv][0];
  int* out = gidx + ((size_t)b * Q + q) * NS;
  for (int j = ln; j < NS; j += 64) out[j] = (j < total) ? gbuf[wv][j] : first;
}

// ---------------------------------------------------------------- weight prep (all 8 matrices, one launch)
struct WPEnt { const float* W; unsigned short* hi; unsigned short* lo; int K, N, row0, beg, end; };
struct WPTab { WPEnt e[8]; };
__global__ __launch_bounds__(256) void wprep8_kernel(WPTab tab) {
  int idx = blockIdx.x * 256 + threadIdx.x;
#pragma unroll
  for (int i = 0; i < 8; ++i) {
    const WPEnt& E = tab.e[i];
    if (idx >= E.beg && idx < E.end) {
      int local = idx - E.beg;
      int k = local / E.N, n = local - k * E.N;
      float v = E.W[(size_t)(E.row0 + k) * E.N + n];
      unsigned short h = f2bh(v);
      E.hi[(size_t)n * E.K + k] = h;
      E.lo[(size_t)n * E.K + k] = f2bh(v - bh2f(h));
    }
  }
}

// ---------------------------------------------------------------- split-bf16 MFMA layer (W chunk-staged in LDS)
template<int K, int N, int AS, int WS, bool XYZC>
DEVINL void do_layer(const unsigned short* __restrict__ Ghi, const unsigned short* __restrict__ Glo,
                     const float* __restrict__ Wxyz,
                     const float* __restrict__ A, unsigned short* __restrict__ Whi,
                     unsigned short* __restrict__ Wlo, const float* __restrict__ sxyz,
                     f32x4* acc, int t) {
  constexpr int KT = K / 32;
  constexpr int NCH = N / 64;
  const int l = t & 63, wv = t >> 6;
  bf16x8 ahi[KT], alo[KT];
  {
    const int row = wv * 16 + (l & 15);
    const float* ap = A + row * AS + (l >> 4) * 8;
#pragma unroll
    for (int kt = 0; kt < KT; ++kt) {
      float4 v0 = *reinterpret_cast<const float4*>(ap + kt * 32);
      float4 v1 = *reinterpret_cast<const float4*>(ap + kt * 32 + 4);
      float f[8] = {v0.x, v0.y, v0.z, v0.w, v1.x, v1.y, v1.z, v1.w};
      bf16x8 h, lo2;
#pragma unroll
      for (int j = 0; j < 8; ++j) {
        unsigned short hb = f2bh(f[j]);
        h[j] = (short)hb;
        lo2[j] = (short)f2bh(f[j] - bh2f(hb));
      }
      ahi[kt] = h; alo[kt] = lo2;
    }
  }
#pragma unroll
  for (int i = 0; i < N / 16; ++i) acc[i] = f32x4{0.f, 0.f, 0.f, 0.f};

#pragma unroll
  for (int c = 0; c < NCH; ++c) {
    __syncthreads();
    {
      constexpr int K8 = K / 8;
      for (int u = t; u < 64 * K8; u += 256) {
        int nn = u / K8, k8 = (u - nn * K8) * 8;
        *reinterpret_cast<u16x8*>(Whi + nn * WS + k8) =
            *reinterpret_cast<const u16x8*>(Ghi + (size_t)(c * 64 + nn) * K + k8);
        *reinterpret_cast<u16x8*>(Wlo + nn * WS + k8) =
            *reinterpret_cast<const u16x8*>(Glo + (size_t)(c * 64 + nn) * K + k8);
      }
    }
    __syncthreads();
#pragma unroll
    for (int ct = 0; ct < 4; ++ct) {
      const unsigned short* wp = Whi + (ct * 16 + (l & 15)) * WS + (l >> 4) * 8;
      const unsigned short* wq = Wlo + (ct * 16 + (l & 15)) * WS + (l >> 4) * 8;
      f32x4 a = acc[c * 4 + ct];
#pragma unroll
      for (int kt = 0; kt < KT; ++kt) {
        bf16x8 wh = *reinterpret_cast<const bf16x8*>(wp + kt * 32);
        bf16x8 wl = *reinterpret_cast<const bf16x8*>(wq + kt * 32);
        a = __builtin_amdgcn_mfma_f32_16x16x32_bf16(ahi[kt], wh, a, 0, 0, 0);
        a = __builtin_amdgcn_mfma_f32_16x16x32_bf16(alo[kt], wh, a, 0, 0, 0);
        a = __builtin_amdgcn_mfma_f32_16x16x32_bf16(ahi[kt], wl, a, 0, 0, 0);
      }
      acc[c * 4 + ct] = a;
    }
  }
  if constexpr (XYZC) {
    float xr[4][3];
#pragma unroll
    for (int r = 0; r < 4; ++r) {
      int row = wv * 16 + (l >> 4) * 4 + r;
      xr[r][0] = sxyz[row * 4 + 0];
      xr[r][1] = sxyz[row * 4 + 1];
      xr[r][2] = sxyz[row * 4 + 2];
    }
#pragma unroll
    for (int gt = 0; gt < N / 16; ++gt) {
      int col = gt * 16 + (l & 15);
      float w0 = Wxyz[col], w1 = Wxyz[N + col], w2 = Wxyz[2 * N + col];
#pragma unroll
      for (int r = 0; r < 4; ++r)
        acc[gt][r] += xr[r][0] * w0 + xr[r][1] * w1 + xr[r][2] * w2;
    }
  }
}

// ---------------------------------------------------------------- SA2 fused
// AS = MAXK+12: byte stride 560 = 35x16 (odd multiple of 16) -> A-frag
// ds_read_b128 across 16 lanes is 2-way bank-aliased (free) vs 4-way at +8.
template<int NPTS, int Q, int M, int GPB, int FD, int C1, int C2, int C3>
__global__ __launch_bounds__(256) void sa_mfma_kernel(
    const float* __restrict__ pts, const float* __restrict__ centers,
    const int* __restrict__ gidx, const float* __restrict__ feats,
    const float* __restrict__ W0, const float* __restrict__ B0,
    const unsigned short* __restrict__ G0h, const unsigned short* __restrict__ G0l,
    const unsigned short* __restrict__ G1h, const unsigned short* __restrict__ G1l,
    const float* __restrict__ B1,
    const unsigned short* __restrict__ G2h, const unsigned short* __restrict__ G2l,
    const float* __restrict__ B2,
    float* __restrict__ fout) {
  static_assert(M * GPB == 64, "");
  constexpr int MK1 = (FD > C1 ? FD : C1);
  constexpr int MAXK = (MK1 > C2 ? MK1 : C2);
  constexpr int AS = MAXK + 12;   // odd multiple of 16B (bank-conflict fix)
  constexpr int WS = MAXK + 8;    // u16: byte stride 272 = 17x16 odd, already free
  __shared__ __align__(16) float A[64 * AS];
  __shared__ __align__(16) unsigned short Whi[64 * WS];
  __shared__ __align__(16) unsigned short Wlo[64 * WS];
  __shared__ float sxyz[64 * 4];
  __shared__ int idxs[64];
  __shared__ float ctr[GPB][4];
  __shared__ float red[4][C3];

  const int t = threadIdx.x;
  const int blk = blockIdx.x;
  const int b = blk / (Q / GPB);
  const int q0 = (blk % (Q / GPB)) * GPB;
  const int l = t & 63, wv = t >> 6;

  if (t < GPB * 3) {
    int g = t / 3, c2 = t % 3;
    ctr[g][c2] = centers[((size_t)b * Q + q0 + g) * 3 + c2];
  }
  for (int m = t; m < 64; m += 256)
    idxs[m] = gidx[((size_t)b * Q + q0 + (m / M)) * M + (m % M)];
  __syncthreads();
  const float* pb = pts + (size_t)b * NPTS * 3;
  for (int m = t; m < 64; m += 256) {
    int g = m / M, i = idxs[m];
    sxyz[m * 4 + 0] = pb[i * 3 + 0] - ctr[g][0];
    sxyz[m * 4 + 1] = pb[i * 3 + 1] - ctr[g][1];
    sxyz[m * 4 + 2] = pb[i * 3 + 2] - ctr[g][2];
  }
  if constexpr (FD > 0) {
    const int m = t >> 2, co = (t & 3) * (FD / 4);
    const float* src = feats + ((size_t)b * NPTS + idxs[m]) * FD + co;
    float* dst = A + m * AS + co;
#pragma unroll
    for (int j = 0; j < FD / 4; j += 4)
      *reinterpret_cast<float4*>(dst + j) = *reinterpret_cast<const float4*>(src + j);
  }
  __syncthreads();

  f32x4 acc[C3 / 16];

  if constexpr (FD == 0) {
    for (int u = t; u < 64 * C1; u += 256) {
      int m = u / C1, c2 = u - m * C1;
      float v = B0[c2] + sxyz[m * 4 + 0] * W0[0 * C1 + c2]
                       + sxyz[m * 4 + 1] * W0[1 * C1 + c2]
                       + sxyz[m * 4 + 2] * W0[2 * C1 + c2];
      A[m * AS + c2] = fmaxf(v, 0.f);
    }
    __syncthreads();
  } else {
    do_layer<FD, C1, AS, WS, true>(G0h, G0l, W0, A, Whi, Wlo, sxyz, acc, t);
#pragma unroll
    for (int gt = 0; gt < C1 / 16; ++gt) {
      int col = gt * 16 + (l & 15);
      float bia = B0[col];
#pragma unroll
      for (int r = 0; r < 4; ++r)
        A[(wv * 16 + (l >> 4) * 4 + r) * AS + col] = fmaxf(acc[gt][r] + bia, 0.f);
    }
  }

  do_layer<C1, C2, AS, WS, false>(G1h, G1l, nullptr, A, Whi, Wlo, sxyz, acc, t);
#pragma unroll
  for (int gt = 0; gt < C2 / 16; ++gt) {
    int col = gt * 16 + (l & 15);
    float bia = B1[col];
#pragma unroll
    for (int r = 0; r < 4; ++r)
      A[(wv * 16 + (l >> 4) * 4 + r) * AS + col] = fmaxf(acc[gt][r] + bia, 0.f);
  }

  do_layer<C2, C3, AS, WS, false>(G2h, G2l, nullptr, A, Whi, Wlo, sxyz, acc, t);
#pragma unroll
  for (int gt = 0; gt < C3 / 16; ++gt) {
    int col = gt * 16 + (l & 15);
    float v = fmaxf(fmaxf(acc[gt][0], acc[gt][1]), fmaxf(acc[gt][2], acc[gt][3]));
    v = fmaxf(v, __shfl_xor(v, 16, 64));
    v = fmaxf(v, __shfl_xor(v, 32, 64));
    if (l < 16) red[wv][col] = v + B2[col];
  }
  __syncthreads();
  constexpr int WPG = 4 / GPB;
  for (int u = t; u < GPB * C3; u += 256) {
    int g = u / C3, c2 = u - g * C3;
    float v = red[g * WPG][c2];
#pragma unroll
    for (int w = 1; w < WPG; ++w) v = fmaxf(v, red[g * WPG + w][c2]);
    fout[((size_t)b * Q + q0 + g) * C3 + c2] = fmaxf(v, 0.f);
  }
}

// ---------------------------------------------------------------- SA1 fused, ALL weights staged in LDS once
// AS = 76: byte stride 304 = 19x16 odd -> A-frag reads 2-way (free) vs 4-way at 72.
template<int NPTS, int Q, int M, int GPB>
__global__ __launch_bounds__(256) void sa1_kernel(
    const float* __restrict__ pts, const float* __restrict__ centers,
    const int* __restrict__ gidx,
    const float* __restrict__ W0, const float* __restrict__ B0,
    const unsigned short* __restrict__ G1h, const unsigned short* __restrict__ G1l,
    const float* __restrict__ B1,
    const unsigned short* __restrict__ G2h, const unsigned short* __restrict__ G2l,
    const float* __restrict__ B2,
    float* __restrict__ fout) {
  static_assert(M * GPB == 64, "");
  constexpr int C1 = 64, C2 = 64, C3 = 128;
  constexpr int AS = 76;
  constexpr int WS = 72;   // u16: 144B = 9x16 odd, free
  constexpr int NC = C2 + C3;
  __shared__ __align__(16) float A[64 * AS];
  __shared__ __align__(16) unsigned short Wh[NC * WS];
  __shared__ __align__(16) unsigned short Wl[NC * WS];
  __shared__ float sxyz[64 * 4];
  __shared__ int idxs[64];
  __shared__ float ctr[GPB][4];
  __shared__ float red[4][C3];

  const int t = threadIdx.x, l = t & 63, wv = t >> 6;
  const int blk = blockIdx.x;
  const int b = blk / (Q / GPB);
  const int q0 = (blk % (Q / GPB)) * GPB;

  if (t < GPB * 3) {
    int g = t / 3, c2 = t % 3;
    ctr[g][c2] = centers[((size_t)b * Q + q0 + g) * 3 + c2];
  }
  for (int m = t; m < 64; m += 256)
    idxs[m] = gidx[((size_t)b * Q + q0 + (m / M)) * M + (m % M)];
  for (int u = t; u < NC * 8; u += 256) {
    int col = u >> 3, k8 = (u & 7) * 8;
    const unsigned short* sh = (col < C2) ? G1h + (size_t)col * 64 + k8
                                          : G2h + (size_t)(col - C2) * 64 + k8;
    const unsigned short* sl = (col < C2) ? G1l + (size_t)col * 64 + k8
                                          : G2l + (size_t)(col - C2) * 64 + k8;
    *reinterpret_cast<u16x8*>(Wh + col * WS + k8) = *reinterpret_cast<const u16x8*>(sh);
    *reinterpret_cast<u16x8*>(Wl + col * WS + k8) = *reinterpret_cast<const u16x8*>(sl);
  }
  __syncthreads();
  const float* pb = pts + (size_t)b * NPTS * 3;
  for (int m = t; m < 64; m += 256) {
    int g = m / M, i = idxs[m];
    sxyz[m * 4 + 0] = pb[i * 3 + 0] - ctr[g][0];
    sxyz[m * 4 + 1] = pb[i * 3 + 1] - ctr[g][1];
    sxyz[m * 4 + 2] = pb[i * 3 + 2] - ctr[g][2];
  }
  __syncthreads();

  // layer0: 3 -> 64 in exact f32 VALU
  for (int u = t; u < 64 * C1; u += 256) {
    int m = u / C1, c2 = u - m * C1;
    float v = B0[c2] + sxyz[m * 4 + 0] * W0[0 * C1 + c2]
                     + sxyz[m * 4 + 1] * W0[1 * C1 + c2]
                     + sxyz[m * 4 + 2] * W0[2 * C1 + c2];
    A[m * AS + c2] = fmaxf(v, 0.f);
  }
  __syncthreads();

  f32x4 acc[8];
  // ---- L2: 64 -> 64, W cols [0,64), barrier-free
  {
    bf16x8 ah[2], al[2];
    const float* ap = A + (wv * 16 + (l & 15)) * AS + (l >> 4) * 8;
#pragma unroll
    for (int kt = 0; kt < 2; ++kt) {
      float4 v0 = *reinterpret_cast<const float4*>(ap + kt * 32);
      float4 v1 = *reinterpret_cast<const float4*>(ap + kt * 32 + 4);
      float f[8] = {v0.x, v0.y, v0.z, v0.w, v1.x, v1.y, v1.z, v1.w};
      bf16x8 h, lo2;
#pragma unroll
      for (int j = 0; j < 8; ++j) {
        unsigned short hb = f2bh(f[j]);
        h[j] = (short)hb;
        lo2[j] = (short)f2bh(f[j] - bh2f(hb));
      }
      ah[kt] = h; al[kt] = lo2;
    }
#pragma unroll
    for (int i = 0; i < 4; ++i) acc[i] = f32x4{0.f, 0.f, 0.f, 0.f};
#pragma unroll
    for (int ct = 0; ct < 4; ++ct) {
      const unsigned short* wp = Wh + (ct * 16 + (l & 15)) * WS + (l >> 4) * 8;
      const unsigned short* wq = Wl + (ct * 16 + (l & 15)) * WS + (l >> 4) * 8;
      f32x4 a = acc[ct];
#pragma unroll
      for (int kt = 0; kt < 2; ++kt) {
        bf16x8 wh = *reinterpret_cast<const bf16x8*>(wp + kt * 32);
        bf16x8 wl = *reinterpret_cast<const bf16x8*>(wq + kt * 32);
        a = __builtin_amdgcn_mfma_f32_16x16x32_bf16(ah[kt], wh, a, 0, 0, 0);
        a = __builtin_amdgcn_mfma_f32_16x16x32_bf16(al[kt], wh, a, 0, 0, 0);
        a = __builtin_amdgcn_mfma_f32_16x16x32_bf16(ah[kt], wl, a, 0, 0, 0);
      }
      acc[ct] = a;
    }
#pragma unroll
    for (int gt = 0; gt < 4; ++gt) {
      int col = gt * 16 + (l & 15);
      float bia = B1[col];
#pragma unroll
      for (int r = 0; r < 4; ++r)
        A[(wv * 16 + (l >> 4) * 4 + r) * AS + col] = fmaxf(acc[gt][r] + bia, 0.f);
    }
  }

  // ---- L3: 64 -> 128, W cols [64,192), maxpool epilogue
  {
    bf16x8 ah[2], al[2];
    const float* ap = A + (wv * 16 + (l & 15)) * AS + (l >> 4) * 8;
#pragma unroll
    for (int kt = 0; kt < 2; ++kt) {
      float4 v0 = *reinterpret_cast<const float4*>(ap + kt * 32);
      float4 v1 = *reinterpret_cast<const float4*>(ap + kt * 32 + 4);
      float f[8] = {v0.x, v0.y, v0.z, v0.w, v1.x, v1.y, v1.z, v1.w};
      bf16x8 h, lo2;
#pragma unroll
      for (int j = 0; j < 8; ++j) {
        unsigned short hb = f2bh(f[j]);
        h[j] = (short)hb;
        lo2[j] = (short)f2bh(f[j] - bh2f(hb));
      }
      ah[kt] = h; al[kt] = lo2;
    }
#pragma unroll
    for (int i = 0; i < 8; ++i) acc[i] = f32x4{0.f, 0.f, 0.f, 0.f};
#pragma unroll
    for (int gt = 0; gt < 8; ++gt) {
      const unsigned short* wp = Wh + (C2 + gt * 16 + (l & 15)) * WS + (l >> 4) * 8;
      const unsigned short* wq = Wl + (C2 + gt * 16 + (l & 15)) * WS + (l >> 4) * 8;
      f32x4 a = acc[gt];
#pragma unroll
      for (int kt = 0; kt < 2; ++kt) {
        bf16x8 wh = *reinterpret_cast<const bf16x8*>(wp + kt * 32);
        bf16x8 wl = *reinterpret_cast<const bf16x8*>(wq + kt * 32);
        a = __builtin_amdgcn_mfma_f32_16x16x32_bf16(ah[kt], wh, a, 0, 0, 0);
        a = __builtin_amdgcn_mfma_f32_16x16x32_bf16(al[kt], wh, a, 0, 0, 0);
        a = __builtin_amdgcn_mfma_f32_16x16x32_bf16(ah[kt], wl, a, 0, 0, 0);
      }
      acc[gt] = a;
    }
#pragma unroll
    for (int gt = 0; gt < 8; ++gt) {
      int col = gt * 16 + (l & 15);
      float v = fmaxf(fmaxf(acc[gt][0], acc[gt][1]), fmaxf(acc[gt][2], acc[gt][3]));
      v = fmaxf(v, __shfl_xor(v, 16, 64));
      v = fmaxf(v, __shfl_xor(v, 32, 64));
      if (l < 16) red[wv][col] = v + B2[col];
    }
  }
  __syncthreads();
  constexpr int WPG = 4 / GPB;
  for (int u = t; u < GPB * C3; u += 256) {
    int g = u / C3, c2 = u - g * C3;
    float v = red[g * WPG][c2];
#pragma unroll
    for (int w = 1; w < WPG; ++w) v = fmaxf(v, red[g * WPG + w][c2]);
    fout[((size_t)b * Q + q0 + g) * C3 + c2] = fmaxf(v, 0.f);
  }
}

// ---------------------------------------------------------------- SA3 fused
// AS3 = 532: rows 16B-aligned (532*4 = 133x16) so float4 LDS ops are true
// b128 (at 529 rows were 4B-aligned -> scalar b32 expansion), and 133 odd
// -> 2-way bank aliasing (free).
constexpr int AS3 = 532;
DEVINL void sa3_frags(const float* __restrict__ A, int l, int KT, bf16x8* ahi, bf16x8* alo) {
  const float* ap = A + (l & 15) * AS3 + (l >> 4) * 8;
  for (int kt = 0; kt < KT; ++kt) {
    float4 v0 = *reinterpret_cast<const float4*>(ap + kt * 32);
    float4 v1 = *reinterpret_cast<const float4*>(ap + kt * 32 + 4);
    float f[8] = {v0.x, v0.y, v0.z, v0.w, v1.x, v1.y, v1.z, v1.w};
    bf16x8 h, lo2;
#pragma unroll
    for (int j = 0; j < 8; ++j) {
      unsigned short hb = f2bh(f[j]);
      h[j] = (short)hb;
      lo2[j] = (short)f2bh(f[j] - bh2f(hb));
    }
    ahi[kt] = h; alo[kt] = lo2;
  }
}

template<int K>
DEVINL void sa3_mm64(const unsigned short* __restrict__ Gh, const unsigned short* __restrict__ Gl,
                     int ncol0, int l, const bf16x8* ahi, const bf16x8* alo, f32x4* acc4) {
  constexpr int KT = K / 32;
#pragma unroll
  for (int ct = 0; ct < 4; ++ct) {
    const unsigned short* hp = Gh + (size_t)(ncol0 + ct * 16 + (l & 15)) * K + (l >> 4) * 8;
    const unsigned short* lp = Gl + (size_t)(ncol0 + ct * 16 + (l & 15)) * K + (l >> 4) * 8;
    f32x4 a = acc4[ct];
#pragma unroll
    for (int kt = 0; kt < KT; ++kt) {
      bf16x8 wh = *reinterpret_cast<const bf16x8*>(hp + kt * 32);
      bf16x8 wl = *reinterpret_cast<const bf16x8*>(lp + kt * 32);
      a = __builtin_amdgcn_mfma_f32_16x16x32_bf16(ahi[kt], wh, a, 0, 0, 0);
      a = __builtin_amdgcn_mfma_f32_16x16x32_bf16(alo[kt], wh, a, 0, 0, 0);
      a = __builtin_amdgcn_mfma_f32_16x16x32_bf16(ahi[kt], wl, a, 0, 0, 0);
    }
    acc4[ct] = a;
  }
}

__global__ __launch_bounds__(256) void sa3f_kernel(
    const float* __restrict__ nx2, const float* __restrict__ f2,
    const float* __restrict__ W0full,
    const unsigned short* __restrict__ G0h, const unsigned short* __restrict__ G0l,
    const float* __restrict__ B0,
    const unsigned short* __restrict__ G1h, const unsigned short* __restrict__ G1l,
    const float* __restrict__ B1,
    const unsigned short* __restrict__ G2h, const unsigned short* __restrict__ G2l,
    const float* __restrict__ B2,
    float* __restrict__ partial) {
  __shared__ __align__(16) float A[16 * AS3];
  __shared__ float sxyz[16][4];
  const int t = threadIdx.x, l = t & 63, w = t >> 6;
  const int b = blockIdx.x >> 3, rb = blockIdx.x & 7;
  const int row0 = rb * 16;
  {
    int r = t >> 4, cc = (t & 15) * 16;
    const float* src = f2 + ((size_t)b * 128 + row0 + r) * 256 + cc;
    float* dstp = A + r * AS3 + cc;
#pragma unroll
    for (int j = 0; j < 16; j += 4)
      *reinterpret_cast<float4*>(dstp + j) = *reinterpret_cast<const float4*>(src + j);
    if (t < 16) {
      const float* s = nx2 + ((size_t)b * 128 + row0 + t) * 3;
      sxyz[t][0] = s[0]; sxyz[t][1] = s[1]; sxyz[t][2] = s[2];
    }
  }
  __syncthreads();

  {  // L1: K=256 MFMA + xyz f32 correction -> N=256 (wave cols 64)
    bf16x8 ah[8], al[8];
    sa3_frags(A, l, 8, ah, al);
    __syncthreads();
    f32x4 acc[4];
#pragma unroll
    for (int i = 0; i < 4; ++i) acc[i] = f32x4{0.f, 0.f, 0.f, 0.f};
    sa3_mm64<256>(G0h, G0l, w * 64, l, ah, al, acc);
    float xr[4][3];
#pragma unroll
    for (int r = 0; r < 4; ++r) {
      int row = (l >> 4) * 4 + r;
      xr[r][0] = sxyz[row][0]; xr[r][1] = sxyz[row][1]; xr[r][2] = sxyz[row][2];
    }
#pragma unroll
    for (int ct = 0; ct < 4; ++ct) {
      int col = w * 64 + ct * 16 + (l & 15);
      float w0 = W0full[col], w1 = W0full[256 + col], w2 = W0full[512 + col];
      float bia = B0[col];
#pragma unroll
      for (int r = 0; r < 4; ++r) {
        int row = (l >> 4) * 4 + r;
        float v = acc[ct][r] + xr[r][0] * w0 + xr[r][1] * w1 + xr[r][2] * w2 + bia;
        A[row * AS3 + col] = fmaxf(v, 0.f);
      }
    }
    __syncthreads();
  }

  {  // L2: K=256 -> N=512 (wave cols 128)
    bf16x8 ah[8], al[8];
    sa3_frags(A, l, 8, ah, al);
    __syncthreads();
    f32x4 acc[8];
#pragma unroll
    for (int i = 0; i < 8; ++i) acc[i] = f32x4{0.f, 0.f, 0.f, 0.f};
    sa3_mm64<256>(G1h, G1l, w * 128, l, ah, al, acc);
    sa3_mm64<256>(G1h, G1l, w * 128 + 64, l, ah, al, acc + 4);
#pragma unroll
    for (int cc = 0; cc < 8; ++cc) {
      int col = w * 128 + cc * 16 + (l & 15);
      float bia = B1[col];
#pragma unroll
      for (int r = 0; r < 4; ++r) {
        int row = (l >> 4) * 4 + r;
        A[row * AS3 + col] = fmaxf(acc[cc][r] + bia, 0.f);
      }
    }
    __syncthreads();
  }

  {  // L3: K=512 -> N=1024 (wave cols 256), maxpool 16 rows -> partial
    bf16x8 ah[16], al[16];
    sa3_frags(A, l, 16, ah, al);
    float* pout = partial + ((size_t)(b * 8 + rb)) * 1024;
#pragma unroll
    for (int sub = 0; sub < 4; ++sub) {
      f32x4 acc[4];
#pragma unroll
      for (int i = 0; i < 4; ++i) acc[i] = f32x4{0.f, 0.f, 0.f, 0.f};
      sa3_mm64<512>(G2h, G2l, w * 256 + sub * 64, l, ah, al, acc);
#pragma unroll
      for (int ct = 0; ct < 4; ++ct) {
        int col = w * 256 + sub * 64 + ct * 16 + (l & 15);
        float v = fmaxf(fmaxf(acc[ct][0], acc[ct][1]), fmaxf(acc[ct][2], acc[ct][3]));
        v = fmaxf(v, __shfl_xor(v, 16, 64));
        v = fmaxf(v, __shfl_xor(v, 32, 64));
        if (l < 16) pout[col] = v + B2[col];  // relu deferred to heads (monotone)
      }
    }
  }
}

// ---------------------------------------------------------------- heads (8-way partial max + relu + dots)
__global__ __launch_bounds__(256) void heads_kernel(const float* __restrict__ partial,
                                                    const float* __restrict__ cw,
                                                    const float* __restrict__ cb,
                                                    const float* __restrict__ rw,
                                                    const float* __restrict__ rb,
                                                    float* __restrict__ out) {
  const int b = blockIdx.x, t = threadIdx.x;
  const float* pb = partial + (size_t)b * 8 * 1024;
  float a0 = 0, a1 = 0, a2 = 0, a3 = 0, a4 = 0;
  for (int k = t; k < 1024; k += 256) {
    float m = pb[k];
#pragma unroll
    for (int p = 1; p < 8; ++p) m = fmaxf(m, pb[p * 1024 + k]);
    float f = fmaxf(m, 0.f);
    a0 += f * cw[k];
    const float* r = rw + (size_t)k * 4;
    a1 += f * r[0]; a2 += f * r[1]; a3 += f * r[2]; a4 += f * r[3];
  }
#pragma unroll
  for (int m = 32; m >= 1; m >>= 1) {
    a0 += __shfl_xor(a0, m, 64); a1 += __shfl_xor(a1, m, 64);
    a2 += __shfl_xor(a2, m, 64); a3 += __shfl_xor(a3, m, 64);
    a4 += __shfl_xor(a4, m, 64);
  }
  __shared__ float red[4][5];
  const int wv = t >> 6, ln = t & 63;
  if (ln == 0) { red[wv][0] = a0; red[wv][1] = a1; red[wv][2] = a2; red[wv][3] = a3; red[wv][4] = a4; }
  __syncthreads();
  if (t == 0) {
    float s0 = red[0][0] + red[1][0] + red[2][0] + red[3][0];
    float s1 = red[0][1] + red[1][1] + red[2][1] + red[3][1];
    float s2 = red[0][2] + red[1][2] + red[2][2] + red[3][2];
    float s3 = red[0][3] + red[1][3] + red[2][3] + red[3][3];
    float s4 = red[0][4] + red[1][4] + red[2][4] + red[3][4];
    out[b] = s0 + cb[0];
    out[32 + b * 4 + 0] = s1 + rb[0];
    out[32 + b * 4 + 1] = s2 + rb[1];
    out[32 + b * 4 + 2] = s3 + rb[2];
    out[32 + b * 4 + 3] = s4 + rb[3];
  }
}

// ---------------------------------------------------------------- launch
extern "C" void kernel_launch(void* const* d_in, const int* in_sizes, int n_in,
                              void* d_out, int out_size, void* d_ws, size_t ws_size,
                              hipStream_t stream) {
  (void)in_sizes; (void)n_in; (void)out_size; (void)ws_size;
  const float* xyz  = (const float*)d_in[0];
  const float* s1w0 = (const float*)d_in[1];  const float* s1b0 = (const float*)d_in[2];
  const float* s1w1 = (const float*)d_in[3];  const float* s1b1 = (const float*)d_in[4];
  const float* s1w2 = (const float*)d_in[5];  const float* s1b2 = (const float*)d_in[6];
  const float* s2w0 = (const float*)d_in[7];  const float* s2b0 = (const float*)d_in[8];
  const float* s2w1 = (const float*)d_in[9];  const float* s2b1 = (const float*)d_in[10];
  const float* s2w2 = (const float*)d_in[11]; const float* s2b2 = (const float*)d_in[12];
  const float* s3w0 = (const float*)d_in[13]; const float* s3b0 = (const float*)d_in[14];
  const float* s3w1 = (const float*)d_in[15]; const float* s3b1 = (const float*)d_in[16];
  const float* s3w2 = (const float*)d_in[17]; const float* s3b2 = (const float*)d_in[18];
  const float* clsw = (const float*)d_in[19]; const float* clsb = (const float*)d_in[20];
  const float* regw = (const float*)d_in[21]; const float* regb = (const float*)d_in[22];

  char* ws = (char*)d_ws;
  float* nx1   = (float*)(ws + 0);          // 32*512*3
  int*   gidx1 = (int*)  (ws + 196608);     // 32*512*32
  float* f1    = (float*)(ws + 2293760);    // 32*512*128
  float* nx2   = (float*)(ws + 10682368);   // 32*128*3
  int*   gidx2 = (int*)  (ws + 10731520);   // 32*128*64
  float* f2    = (float*)(ws + 11780096);   // 32*128*256

  // SA1/SA2 prepped weights (u16 hi/lo, transposed [n][k])
  unsigned short* wt = (unsigned short*)(ws + 20168704);
  unsigned short* g11h = wt;            // 64*64
  unsigned short* g11l = wt + 4096;
  unsigned short* g12h = wt + 8192;     // 128*64
  unsigned short* g12l = wt + 16384;
  unsigned short* g20h = wt + 24576;    // 128*128 (rows 3..130 of s2w0)
  unsigned short* g20l = wt + 40960;
  unsigned short* g21h = wt + 57344;    // 128*128
  unsigned short* g21l = wt + 73728;
  unsigned short* g22h = wt + 90112;    // 256*128
  unsigned short* g22l = wt + 122880;   // ends at byte 20168704+311296 = 20480000
  // SA3 prepped weights
  unsigned short* g30h = (unsigned short*)(ws + 20480000);  // 256x256
  unsigned short* g30l = (unsigned short*)(ws + 20611072);
  unsigned short* g31h = (unsigned short*)(ws + 20742144);  // 512x256
  unsigned short* g31l = (unsigned short*)(ws + 21004288);
  unsigned short* g32h = (unsigned short*)(ws + 21266432);  // 1024x512
  unsigned short* g32l = (unsigned short*)(ws + 22315008);
  float* partial = (float*)(ws + 23363584);                 // 32*8*1024 f32 -> ends 24412160

  const float r21 = (float)(0.2 * 0.2);
  const float r22 = (float)(0.4 * 0.4);

  WPTab tab;
  int off = 0;
  auto set = [&](int i, const float* W, unsigned short* hi, unsigned short* lo,
                 int K, int N, int row0) {
    tab.e[i] = WPEnt{W, hi, lo, K, N, row0, off, off + K * N};
    off += K * N;
  };
  set(0, s1w1, g11h, g11l, 64, 64, 0);
  set(1, s1w2, g12h, g12l, 64, 128, 0);
  set(2, s2w0, g20h, g20l, 128, 128, 3);
  set(3, s2w1, g21h, g21l, 128, 128, 0);
  set(4, s2w2, g22h, g22l, 128, 256, 0);
  set(5, s3w0, g30h, g30l, 256, 256, 3);
  set(6, s3w1, g31h, g31l, 256, 512, 0);
  set(7, s3w2, g32h, g32l, 512, 1024, 0);
  wprep8_kernel<<<(off + 255) / 256, 256, 0, stream>>>(tab);

  fps_kernel<4096, 512, 256><<<32, 256, 0, stream>>>(xyz, nx1);
  bq_kernel<4096, 32><<<4096, 256, 0, stream>>>(xyz, nx1, gidx1, 512, r21);
  sa1_kernel<4096, 512, 32, 2><<<8192, 256, 0, stream>>>(
      xyz, nx1, gidx1, s1w0, s1b0, g11h, g11l, s1b1, g12h, g12l, s1b2, f1);
  fps_kernel<512, 128, 64><<<32, 64, 0, stream>>>(nx1, nx2);
  bq_kernel<512, 64><<<1024, 256, 0, stream>>>(nx1, nx2, gidx2, 128, r22);
  sa_mfma_kernel<512, 128, 64, 1, 128, 128, 128, 256><<<4096, 256, 0, stream>>>(
      nx1, nx2, gidx2, f1, s2w0, s2b0,
      g20h, g20l, g21h, g21l, s2b1, g22h, g22l, s2b2, f2);
  sa3f_kernel<<<256, 256, 0, stream>>>(nx2, f2, s3w0, g30h, g30l, s3b0,
                                       g31h, g31l, s3b1, g32h, g32l, s3b2, partial);
  heads_kernel<<<32, 256, 0, stream>>>(partial, clsw, clsb, regw, regb, (float*)d_out);
}

// Round 11
// 728.354 us; speedup vs baseline: 1.9828x; 1.0990x over previous
//
#include <hip/hip_runtime.h>

#define DEVINL __device__ __forceinline__

typedef __attribute__((ext_vector_type(8))) short bf16x8;
typedef __attribute__((ext_vector_type(8))) unsigned short u16x8;
typedef __attribute__((ext_vector_type(4))) float f32x4;

// RNE f32 -> bf16 bits (no NaN handling needed for this workload)
DEVINL unsigned short f2bh(float f){
  unsigned u = __float_as_uint(f);
  return (unsigned short)((u + 0x7FFFu + ((u >> 16) & 1u)) >> 16);
}
DEVINL float bh2f(unsigned short h){ return __uint_as_float(((unsigned)h) << 16); }

// Wave64 max-reduce of a u64 key via DPP (VALU latency, no DS pipe).
DEVINL unsigned long long dpp_max_u64(unsigned long long k) {
#define DPP_STEP(ctrl)                                                        \
  {                                                                           \
    int hi = (int)(k >> 32), lo = (int)(unsigned)k;                           \
    int oh = __builtin_amdgcn_update_dpp(0, hi, ctrl, 0xF, 0xF, 1);           \
    int ol = __builtin_amdgcn_update_dpp(0, lo, ctrl, 0xF, 0xF, 1);           \
    unsigned long long ok =                                                   \
        ((unsigned long long)(unsigned)oh << 32) | (unsigned)ol;              \
    if (ok > k) k = ok;                                                       \
  }
  DPP_STEP(0x111)  // row_shr:1
  DPP_STEP(0x112)  // row_shr:2
  DPP_STEP(0x114)  // row_shr:4
  DPP_STEP(0x118)  // row_shr:8
  DPP_STEP(0x142)  // row_bcast:15
  DPP_STEP(0x143)  // row_bcast:31
#undef DPP_STEP
  return k;
}

// ---------------------------------------------------------------- FPS body (R4-proven, 293 us)
template<int N, int NP, int NT>
DEVINL void fps_body(const float* __restrict__ xyz, float* __restrict__ nxyz,
                     int b, int t) {
  constexpr int PTS = N / NT;
  constexpr int NW = NT / 64;
  __shared__ float xs[N], ys[N], zs[N];
  __shared__ int farr[NP];
  __shared__ unsigned long long sk[2][(NW > 1 ? NW : 1)];
  float px[PTS], py[PTS], pz[PTS], dst[PTS];
  const float* base = xyz + (size_t)b * N * 3;
#pragma unroll
  for (int j = 0; j < PTS; ++j) {
    int i = t + j * NT;
    float x = base[i * 3 + 0], y = base[i * 3 + 1], z = base[i * 3 + 2];
    px[j] = x; py[j] = y; pz[j] = z;
    xs[i] = x; ys[i] = y; zs[i] = z;
    dst[j] = 1e10f;
  }
  __syncthreads();
  int far = 0;
  const int wv = t >> 6, ln = t & 63;
  for (int s = 0; s < NP; ++s) {
    float cx = xs[far], cy = ys[far], cz = zs[far];
    if (t == 0) farr[s] = far;
    float bv = -1.f; int bi = 0;
#pragma unroll
    for (int j = 0; j < PTS; ++j) {
      // no-fma, left-to-right: matches numpy elementwise + sum order
      float dx = __fsub_rn(px[j], cx), dy = __fsub_rn(py[j], cy), dz = __fsub_rn(pz[j], cz);
      float d = __fadd_rn(__fadd_rn(__fmul_rn(dx, dx), __fmul_rn(dy, dy)), __fmul_rn(dz, dz));
      float nd = fminf(dst[j], d);
      dst[j] = nd;
      int i = t + j * NT;
      if (nd > bv) { bv = nd; bi = i; }  // strict >: first max kept per thread
    }
    // pack: max key == max dist, tie -> larger ~idx == smaller idx
    unsigned long long key =
        ((unsigned long long)__float_as_uint(bv) << 32) | (unsigned)(~bi);
    key = dpp_max_u64(key);
    if constexpr (NW == 1) {
      int rl = __builtin_amdgcn_readlane((int)(unsigned)key, 63);
      far = (int)(~(unsigned)rl);
    } else {
      const int p = s & 1;
      if (ln == 63) sk[p][wv] = key;
      __syncthreads();
      unsigned long long m = sk[p][0];
#pragma unroll
      for (int q = 1; q < NW; ++q) {
        unsigned long long qk = sk[p][q];
        if (qk > m) m = qk;
      }
      far = (int)(~(unsigned)m);
    }
  }
  __syncthreads();
  for (int s2 = t; s2 < NP; s2 += NT) {
    int fi = farr[s2];
    float* o = nxyz + ((size_t)b * NP + s2) * 3;
    o[0] = xs[fi]; o[1] = ys[fi]; o[2] = zs[fi];
  }
}

// ---------------------------------------------------------------- ball query body (unchanged semantics)
template<int N, int NS>
DEVINL void bq_body(const float* __restrict__ pts, const float* __restrict__ centers,
                    int* __restrict__ gidx, int Q, float r2, int blk, int t) {
  const int wv = t >> 6, ln = t & 63;
  const int g = blk * 4 + wv;
  const int b = g / Q, q = g % Q;
  const float* pb = pts + (size_t)b * N * 3;
  const float* c = centers + ((size_t)b * Q + q) * 3;
  const float cx = c[0], cy = c[1], cz = c[2];
  __shared__ int gbuf[4][NS];
  int taken = 0;
  for (int base = 0; base < N; base += 64) {
    if (taken >= NS) break;
    int i = base + ln;
    float dx = __fsub_rn(pb[i * 3 + 0], cx), dy = __fsub_rn(pb[i * 3 + 1], cy),
          dz = __fsub_rn(pb[i * 3 + 2], cz);
    float d = __fadd_rn(__fadd_rn(__fmul_rn(dx, dx), __fmul_rn(dy, dy)), __fmul_rn(dz, dz));
    bool in = (d <= r2);
    unsigned long long mk = __ballot(in);
    int rank = __popcll(mk & ((1ull << ln) - 1ull));
    int pos = taken + rank;
    if (in && pos < NS) gbuf[wv][pos] = i;
    taken += (int)__popcll(mk);
  }
  int total = taken < NS ? taken : NS;
  int first = gbuf[wv][0];
  int* out = gidx + ((size_t)b * Q + q) * NS;
  for (int j = ln; j < NS; j += 64) out[j] = (j < total) ? gbuf[wv][j] : first;
}

// ---------------------------------------------------------------- weight prep body
struct WPEnt { const float* W; unsigned short* hi; unsigned short* lo; int K, N, row0, beg, end; };
struct WPTab { WPEnt e[8]; };
DEVINL void wprep_body(const WPTab& tab, int idx) {
#pragma unroll
  for (int i = 0; i < 8; ++i) {
    const WPEnt& E = tab.e[i];
    if (idx >= E.beg && idx < E.end) {
      int local = idx - E.beg;
      int k = local / E.N, n = local - k * E.N;
      float v = E.W[(size_t)(E.row0 + k) * E.N + n];
      unsigned short h = f2bh(v);
      E.hi[(size_t)n * E.K + k] = h;
      E.lo[(size_t)n * E.K + k] = f2bh(v - bh2f(h));
    }
  }
}

// ---------------------------------------------------------------- fused launches
// [fps1 || wprep]: independent (fps1 reads xyz; wprep reads weights).
__global__ __launch_bounds__(256) void fps1_wprep_kernel(const float* __restrict__ xyz,
                                                         float* __restrict__ nx1, WPTab tab) {
  if (blockIdx.x < 32) { fps_body<4096, 512, 256>(xyz, nx1, blockIdx.x, threadIdx.x); return; }
  wprep_body(tab, (blockIdx.x - 32) * 256 + threadIdx.x);
}

// [fps2 || bq1]: both need only nx1 (and xyz for bq1). fps2 at NT=256 (all
// threads participate in its barriers).
__global__ __launch_bounds__(256) void fps2_bq1_kernel(const float* __restrict__ xyz,
                                                       const float* __restrict__ nx1,
                                                       int* __restrict__ gidx1,
                                                       float* __restrict__ nx2, float r21) {
  if (blockIdx.x < 32) { fps_body<512, 128, 256>(nx1, nx2, blockIdx.x, threadIdx.x); return; }
  bq_body<4096, 32>(xyz, nx1, gidx1, 512, r21, blockIdx.x - 32, threadIdx.x);
}

// ---------------------------------------------------------------- split-bf16 MFMA layer
// T14 async-STAGE: prefetch chunk c+1's W into registers (static-indexed)
// before chunk c's MFMA cluster; LDS-write after the barrier. MFMA order
// unchanged -> bit-identical results.
template<int K, int N, int AS, int WS, bool XYZC>
DEVINL void do_layer(const unsigned short* __restrict__ Ghi, const unsigned short* __restrict__ Glo,
                     const float* __restrict__ Wxyz,
                     const float* __restrict__ A, unsigned short* __restrict__ Whi,
                     unsigned short* __restrict__ Wlo, const float* __restrict__ sxyz,
                     f32x4* acc, int t) {
  constexpr int KT = K / 32;
  constexpr int NCH = N / 64;
  constexpr int K8 = K / 8;
  constexpr int SI = (64 * K8) / 256;  // staging iterations (4 for K=128)
  const int l = t & 63, wv = t >> 6;

  // prefetch W chunk 0 early (flies under the A-frag split below)
  u16x8 rh[SI], rl[SI];
#pragma unroll
  for (int s = 0; s < SI; ++s) {
    int u = t + s * 256;
    int nn = u / K8, k8 = (u - nn * K8) * 8;
    rh[s] = *reinterpret_cast<const u16x8*>(Ghi + (size_t)nn * K + k8);
    rl[s] = *reinterpret_cast<const u16x8*>(Glo + (size_t)nn * K + k8);
  }

  bf16x8 ahi[KT], alo[KT];
  {
    const int row = wv * 16 + (l & 15);
    const float* ap = A + row * AS + (l >> 4) * 8;
#pragma unroll
    for (int kt = 0; kt < KT; ++kt) {
      float4 v0 = *reinterpret_cast<const float4*>(ap + kt * 32);
      float4 v1 = *reinterpret_cast<const float4*>(ap + kt * 32 + 4);
      float f[8] = {v0.x, v0.y, v0.z, v0.w, v1.x, v1.y, v1.z, v1.w};
      bf16x8 h, lo2;
#pragma unroll
      for (int j = 0; j < 8; ++j) {
        unsigned short hb = f2bh(f[j]);
        h[j] = (short)hb;
        lo2[j] = (short)f2bh(f[j] - bh2f(hb));
      }
      ahi[kt] = h; alo[kt] = lo2;
    }
  }
#pragma unroll
  for (int i = 0; i < N / 16; ++i) acc[i] = f32x4{0.f, 0.f, 0.f, 0.f};

#pragma unroll
  for (int c = 0; c < NCH; ++c) {
    __syncthreads();  // all waves done reading previous W contents
#pragma unroll
    for (int s = 0; s < SI; ++s) {
      int u = t + s * 256;
      int nn = u / K8, k8 = (u - nn * K8) * 8;
      *reinterpret_cast<u16x8*>(Whi + nn * WS + k8) = rh[s];
      *reinterpret_cast<u16x8*>(Wlo + nn * WS + k8) = rl[s];
    }
    if (c + 1 < NCH) {  // issue next chunk's loads; they fly under the MFMAs
#pragma unroll
      for (int s = 0; s < SI; ++s) {
        int u = t + s * 256;
        int nn = u / K8, k8 = (u - nn * K8) * 8;
        rh[s] = *reinterpret_cast<const u16x8*>(Ghi + (size_t)((c + 1) * 64 + nn) * K + k8);
        rl[s] = *reinterpret_cast<const u16x8*>(Glo + (size_t)((c + 1) * 64 + nn) * K + k8);
      }
    }
    __syncthreads();
#pragma unroll
    for (int ct = 0; ct < 4; ++ct) {
      const unsigned short* wp = Whi + (ct * 16 + (l & 15)) * WS + (l >> 4) * 8;
      const unsigned short* wq = Wlo + (ct * 16 + (l & 15)) * WS + (l >> 4) * 8;
      f32x4 a = acc[c * 4 + ct];
#pragma unroll
      for (int kt = 0; kt < KT; ++kt) {
        bf16x8 wh = *reinterpret_cast<const bf16x8*>(wp + kt * 32);
        bf16x8 wl = *reinterpret_cast<const bf16x8*>(wq + kt * 32);
        a = __builtin_amdgcn_mfma_f32_16x16x32_bf16(ahi[kt], wh, a, 0, 0, 0);
        a = __builtin_amdgcn_mfma_f32_16x16x32_bf16(alo[kt], wh, a, 0, 0, 0);
        a = __builtin_amdgcn_mfma_f32_16x16x32_bf16(ahi[kt], wl, a, 0, 0, 0);
      }
      acc[c * 4 + ct] = a;
    }
  }
  if constexpr (XYZC) {
    float xr[4][3];
#pragma unroll
    for (int r = 0; r < 4; ++r) {
      int row = wv * 16 + (l >> 4) * 4 + r;
      xr[r][0] = sxyz[row * 4 + 0];
      xr[r][1] = sxyz[row * 4 + 1];
      xr[r][2] = sxyz[row * 4 + 2];
    }
#pragma unroll
    for (int gt = 0; gt < N / 16; ++gt) {
      int col = gt * 16 + (l & 15);
      float w0 = Wxyz[col], w1 = Wxyz[N + col], w2 = Wxyz[2 * N + col];
#pragma unroll
      for (int r = 0; r < 4; ++r)
        acc[gt][r] += xr[r][0] * w0 + xr[r][1] * w1 + xr[r][2] * w2;
    }
  }
}

// ---------------------------------------------------------------- SA2 fused
template<int NPTS, int Q, int M, int GPB, int FD, int C1, int C2, int C3>
__global__ __launch_bounds__(256) void sa_mfma_kernel(
    const float* __restrict__ pts, const float* __restrict__ centers,
    const int* __restrict__ gidx, const float* __restrict__ feats,
    const float* __restrict__ W0, const float* __restrict__ B0,
    const unsigned short* __restrict__ G0h, const unsigned short* __restrict__ G0l,
    const unsigned short* __restrict__ G1h, const unsigned short* __restrict__ G1l,
    const float* __restrict__ B1,
    const unsigned short* __restrict__ G2h, const unsigned short* __restrict__ G2l,
    const float* __restrict__ B2,
    float* __restrict__ fout) {
  static_assert(M * GPB == 64, "");
  constexpr int MK1 = (FD > C1 ? FD : C1);
  constexpr int MAXK = (MK1 > C2 ? MK1 : C2);
  constexpr int AS = MAXK + 12;
  constexpr int WS = MAXK + 8;
  __shared__ __align__(16) float A[64 * AS];
  __shared__ __align__(16) unsigned short Whi[64 * WS];
  __shared__ __align__(16) unsigned short Wlo[64 * WS];
  __shared__ float sxyz[64 * 4];
  __shared__ int idxs[64];
  __shared__ float ctr[GPB][4];
  __shared__ float red[4][C3];

  const int t = threadIdx.x;
  const int blk = blockIdx.x;
  const int b = blk / (Q / GPB);
  const int q0 = (blk % (Q / GPB)) * GPB;
  const int l = t & 63, wv = t >> 6;

  if (t < GPB * 3) {
    int g = t / 3, c2 = t % 3;
    ctr[g][c2] = centers[((size_t)b * Q + q0 + g) * 3 + c2];
  }
  for (int m = t; m < 64; m += 256)
    idxs[m] = gidx[((size_t)b * Q + q0 + (m / M)) * M + (m % M)];
  __syncthreads();
  const float* pb = pts + (size_t)b * NPTS * 3;
  for (int m = t; m < 64; m += 256) {
    int g = m / M, i = idxs[m];
    sxyz[m * 4 + 0] = pb[i * 3 + 0] - ctr[g][0];
    sxyz[m * 4 + 1] = pb[i * 3 + 1] - ctr[g][1];
    sxyz[m * 4 + 2] = pb[i * 3 + 2] - ctr[g][2];
  }
  if constexpr (FD > 0) {
    const int m = t >> 2, co = (t & 3) * (FD / 4);
    const float* src = feats + ((size_t)b * NPTS + idxs[m]) * FD + co;
    float* dst = A + m * AS + co;
#pragma unroll
    for (int j = 0; j < FD / 4; j += 4)
      *reinterpret_cast<float4*>(dst + j) = *reinterpret_cast<const float4*>(src + j);
  }
  __syncthreads();

  f32x4 acc[C3 / 16];

  if constexpr (FD == 0) {
    for (int u = t; u < 64 * C1; u += 256) {
      int m = u / C1, c2 = u - m * C1;
      float v = B0[c2] + sxyz[m * 4 + 0] * W0[0 * C1 + c2]
                       + sxyz[m * 4 + 1] * W0[1 * C1 + c2]
                       + sxyz[m * 4 + 2] * W0[2 * C1 + c2];
      A[m * AS + c2] = fmaxf(v, 0.f);
    }
    __syncthreads();
  } else {
    do_layer<FD, C1, AS, WS, true>(G0h, G0l, W0, A, Whi, Wlo, sxyz, acc, t);
#pragma unroll
    for (int gt = 0; gt < C1 / 16; ++gt) {
      int col = gt * 16 + (l & 15);
      float bia = B0[col];
#pragma unroll
      for (int r = 0; r < 4; ++r)
        A[(wv * 16 + (l >> 4) * 4 + r) * AS + col] = fmaxf(acc[gt][r] + bia, 0.f);
    }
  }

  do_layer<C1, C2, AS, WS, false>(G1h, G1l, nullptr, A, Whi, Wlo, sxyz, acc, t);
#pragma unroll
  for (int gt = 0; gt < C2 / 16; ++gt) {
    int col = gt * 16 + (l & 15);
    float bia = B1[col];
#pragma unroll
    for (int r = 0; r < 4; ++r)
      A[(wv * 16 + (l >> 4) * 4 + r) * AS + col] = fmaxf(acc[gt][r] + bia, 0.f);
  }

  do_layer<C2, C3, AS, WS, false>(G2h, G2l, nullptr, A, Whi, Wlo, sxyz, acc, t);
#pragma unroll
  for (int gt = 0; gt < C3 / 16; ++gt) {
    int col = gt * 16 + (l & 15);
    float v = fmaxf(fmaxf(acc[gt][0], acc[gt][1]), fmaxf(acc[gt][2], acc[gt][3]));
    v = fmaxf(v, __shfl_xor(v, 16, 64));
    v = fmaxf(v, __shfl_xor(v, 32, 64));
    if (l < 16) red[wv][col] = v + B2[col];
  }
  __syncthreads();
  constexpr int WPG = 4 / GPB;
  for (int u = t; u < GPB * C3; u += 256) {
    int g = u / C3, c2 = u - g * C3;
    float v = red[g * WPG][c2];
#pragma unroll
    for (int w = 1; w < WPG; ++w) v = fmaxf(v, red[g * WPG + w][c2]);
    fout[((size_t)b * Q + q0 + g) * C3 + c2] = fmaxf(v, 0.f);
  }
}

// ---------------------------------------------------------------- SA1 body (LDS-staged-once, barrier-free layers)
template<int NPTS, int Q, int M, int GPB>
DEVINL void sa1_body(const float* __restrict__ pts, const float* __restrict__ centers,
                     const int* __restrict__ gidx,
                     const float* __restrict__ W0, const float* __restrict__ B0,
                     const unsigned short* __restrict__ G1h, const unsigned short* __restrict__ G1l,
                     const float* __restrict__ B1,
                     const unsigned short* __restrict__ G2h, const unsigned short* __restrict__ G2l,
                     const float* __restrict__ B2,
                     float* __restrict__ fout, int blk, int t) {
  static_assert(M * GPB == 64, "");
  constexpr int C1 = 64, C2 = 64, C3 = 128;
  constexpr int AS = 76;
  constexpr int WS = 72;
  constexpr int NC = C2 + C3;
  __shared__ __align__(16) float A[64 * AS];
  __shared__ __align__(16) unsigned short Wh[NC * WS];
  __shared__ __align__(16) unsigned short Wl[NC * WS];
  __shared__ float sxyz[64 * 4];
  __shared__ int idxs[64];
  __shared__ float ctr[GPB][4];
  __shared__ float red[4][C3];

  const int l = t & 63, wv = t >> 6;
  const int b = blk / (Q / GPB);
  const int q0 = (blk % (Q / GPB)) * GPB;

  if (t < GPB * 3) {
    int g = t / 3, c2 = t % 3;
    ctr[g][c2] = centers[((size_t)b * Q + q0 + g) * 3 + c2];
  }
  for (int m = t; m < 64; m += 256)
    idxs[m] = gidx[((size_t)b * Q + q0 + (m / M)) * M + (m % M)];
  for (int u = t; u < NC * 8; u += 256) {
    int col = u >> 3, k8 = (u & 7) * 8;
    const unsigned short* sh = (col < C2) ? G1h + (size_t)col * 64 + k8
                                          : G2h + (size_t)(col - C2) * 64 + k8;
    const unsigned short* sl = (col < C2) ? G1l + (size_t)col * 64 + k8
                                          : G2l + (size_t)(col - C2) * 64 + k8;
    *reinterpret_cast<u16x8*>(Wh + col * WS + k8) = *reinterpret_cast<const u16x8*>(sh);
    *reinterpret_cast<u16x8*>(Wl + col * WS + k8) = *reinterpret_cast<const u16x8*>(sl);
  }
  __syncthreads();
  const float* pb = pts + (size_t)b * NPTS * 3;
  for (int m = t; m < 64; m += 256) {
    int g = m / M, i = idxs[m];
    sxyz[m * 4 + 0] = pb[i * 3 + 0] - ctr[g][0];
    sxyz[m * 4 + 1] = pb[i * 3 + 1] - ctr[g][1];
    sxyz[m * 4 + 2] = pb[i * 3 + 2] - ctr[g][2];
  }
  __syncthreads();

  // layer0: 3 -> 64 in exact f32 VALU
  for (int u = t; u < 64 * C1; u += 256) {
    int m = u / C1, c2 = u - m * C1;
    float v = B0[c2] + sxyz[m * 4 + 0] * W0[0 * C1 + c2]
                     + sxyz[m * 4 + 1] * W0[1 * C1 + c2]
                     + sxyz[m * 4 + 2] * W0[2 * C1 + c2];
    A[m * AS + c2] = fmaxf(v, 0.f);
  }
  __syncthreads();

  f32x4 acc[8];
  // ---- L2: 64 -> 64, W cols [0,64), barrier-free
  {
    bf16x8 ah[2], al[2];
    const float* ap = A + (wv * 16 + (l & 15)) * AS + (l >> 4) * 8;
#pragma unroll
    for (int kt = 0; kt < 2; ++kt) {
      float4 v0 = *reinterpret_cast<const float4*>(ap + kt * 32);
      float4 v1 = *reinterpret_cast<const float4*>(ap + kt * 32 + 4);
      float f[8] = {v0.x, v0.y, v0.z, v0.w, v1.x, v1.y, v1.z, v1.w};
      bf16x8 h, lo2;
#pragma unroll
      for (int j = 0; j < 8; ++j) {
        unsigned short hb = f2bh(f[j]);
        h[j] = (short)hb;
        lo2[j] = (short)f2bh(f[j] - bh2f(hb));
      }
      ah[kt] = h; al[kt] = lo2;
    }
#pragma unroll
    for (int i = 0; i < 4; ++i) acc[i] = f32x4{0.f, 0.f, 0.f, 0.f};
#pragma unroll
    for (int ct = 0; ct < 4; ++ct) {
      const unsigned short* wp = Wh + (ct * 16 + (l & 15)) * WS + (l >> 4) * 8;
      const unsigned short* wq = Wl + (ct * 16 + (l & 15)) * WS + (l >> 4) * 8;
      f32x4 a = acc[ct];
#pragma unroll
      for (int kt = 0; kt < 2; ++kt) {
        bf16x8 wh = *reinterpret_cast<const bf16x8*>(wp + kt * 32);
        bf16x8 wl = *reinterpret_cast<const bf16x8*>(wq + kt * 32);
        a = __builtin_amdgcn_mfma_f32_16x16x32_bf16(ah[kt], wh, a, 0, 0, 0);
        a = __builtin_amdgcn_mfma_f32_16x16x32_bf16(al[kt], wh, a, 0, 0, 0);
        a = __builtin_amdgcn_mfma_f32_16x16x32_bf16(ah[kt], wl, a, 0, 0, 0);
      }
      acc[ct] = a;
    }
#pragma unroll
    for (int gt = 0; gt < 4; ++gt) {
      int col = gt * 16 + (l & 15);
      float bia = B1[col];
#pragma unroll
      for (int r = 0; r < 4; ++r)
        A[(wv * 16 + (l >> 4) * 4 + r) * AS + col] = fmaxf(acc[gt][r] + bia, 0.f);
    }
  }

  // ---- L3: 64 -> 128, W cols [64,192), maxpool epilogue
  {
    bf16x8 ah[2], al[2];
    const float* ap = A + (wv * 16 + (l & 15)) * AS + (l >> 4) * 8;
#pragma unroll
    for (int kt = 0; kt < 2; ++kt) {
      float4 v0 = *reinterpret_cast<const float4*>(ap + kt * 32);
      float4 v1 = *reinterpret_cast<const float4*>(ap + kt * 32 + 4);
      float f[8] = {v0.x, v0.y, v0.z, v0.w, v1.x, v1.y, v1.z, v1.w};
      bf16x8 h, lo2;
#pragma unroll
      for (int j = 0; j < 8; ++j) {
        unsigned short hb = f2bh(f[j]);
        h[j] = (short)hb;
        lo2[j] = (short)f2bh(f[j] - bh2f(hb));
      }
      ah[kt] = h; al[kt] = lo2;
    }
#pragma unroll
    for (int i = 0; i < 8; ++i) acc[i] = f32x4{0.f, 0.f, 0.f, 0.f};
#pragma unroll
    for (int gt = 0; gt < 8; ++gt) {
      const unsigned short* wp = Wh + (C2 + gt * 16 + (l & 15)) * WS + (l >> 4) * 8;
      const unsigned short* wq = Wl + (C2 + gt * 16 + (l & 15)) * WS + (l >> 4) * 8;
      f32x4 a = acc[gt];
#pragma unroll
      for (int kt = 0; kt < 2; ++kt) {
        bf16x8 wh = *reinterpret_cast<const bf16x8*>(wp + kt * 32);
        bf16x8 wl = *reinterpret_cast<const bf16x8*>(wq + kt * 32);
        a = __builtin_amdgcn_mfma_f32_16x16x32_bf16(ah[kt], wh, a, 0, 0, 0);
        a = __builtin_amdgcn_mfma_f32_16x16x32_bf16(al[kt], wh, a, 0, 0, 0);
        a = __builtin_amdgcn_mfma_f32_16x16x32_bf16(ah[kt], wl, a, 0, 0, 0);
      }
      acc[gt] = a;
    }
#pragma unroll
    for (int gt = 0; gt < 8; ++gt) {
      int col = gt * 16 + (l & 15);
      float v = fmaxf(fmaxf(acc[gt][0], acc[gt][1]), fmaxf(acc[gt][2], acc[gt][3]));
      v = fmaxf(v, __shfl_xor(v, 16, 64));
      v = fmaxf(v, __shfl_xor(v, 32, 64));
      if (l < 16) red[wv][col] = v + B2[col];
    }
  }
  __syncthreads();
  constexpr int WPG = 4 / GPB;
  for (int u = t; u < GPB * C3; u += 256) {
    int g = u / C3, c2 = u - g * C3;
    float v = red[g * WPG][c2];
#pragma unroll
    for (int w = 1; w < WPG; ++w) v = fmaxf(v, red[g * WPG + w][c2]);
    fout[((size_t)b * Q + q0 + g) * C3 + c2] = fmaxf(v, 0.f);
  }
}

// [bq2 || sa1]: bq2 needs nx1/nx2 only; sa1 needs gidx1 (prior launch).
__global__ __launch_bounds__(256) void bq2_sa1_kernel(
    const float* __restrict__ xyz, const float* __restrict__ nx1,
    const float* __restrict__ nx2, int* __restrict__ gidx2, float r22,
    const int* __restrict__ gidx1,
    const float* __restrict__ s1w0, const float* __restrict__ s1b0,
    const unsigned short* __restrict__ g11h, const unsigned short* __restrict__ g11l,
    const float* __restrict__ s1b1,
    const unsigned short* __restrict__ g12h, const unsigned short* __restrict__ g12l,
    const float* __restrict__ s1b2, float* __restrict__ f1) {
  if (blockIdx.x < 1024) {
    bq_body<512, 64>(nx1, nx2, gidx2, 128, r22, blockIdx.x, threadIdx.x);
    return;
  }
  sa1_body<4096, 512, 32, 2>(xyz, nx1, gidx1, s1w0, s1b0, g11h, g11l, s1b1,
                             g12h, g12l, s1b2, f1, blockIdx.x - 1024, threadIdx.x);
}

// ---------------------------------------------------------------- SA3 fused
constexpr int AS3 = 532;
DEVINL void sa3_frags(const float* __restrict__ A, int l, int KT, bf16x8* ahi, bf16x8* alo) {
  const float* ap = A + (l & 15) * AS3 + (l >> 4) * 8;
  for (int kt = 0; kt < KT; ++kt) {
    float4 v0 = *reinterpret_cast<const float4*>(ap + kt * 32);
    float4 v1 = *reinterpret_cast<const float4*>(ap + kt * 32 + 4);
    float f[8] = {v0.x, v0.y, v0.z, v0.w, v1.x, v1.y, v1.z, v1.w};
    bf16x8 h, lo2;
#pragma unroll
    for (int j = 0; j < 8; ++j) {
      unsigned short hb = f2bh(f[j]);
      h[j] = (short)hb;
      lo2[j] = (short)f2bh(f[j] - bh2f(hb));
    }
    ahi[kt] = h; alo[kt] = lo2;
  }
}

template<int K>
DEVINL void sa3_mm64(const unsigned short* __restrict__ Gh, const unsigned short* __restrict__ Gl,
                     int ncol0, int l, const bf16x8* ahi, const bf16x8* alo, f32x4* acc4) {
  constexpr int KT = K / 32;
#pragma unroll
  for (int ct = 0; ct < 4; ++ct) {
    const unsigned short* hp = Gh + (size_t)(ncol0 + ct * 16 + (l & 15)) * K + (l >> 4) * 8;
    const unsigned short* lp = Gl + (size_t)(ncol0 + ct * 16 + (l & 15)) * K + (l >> 4) * 8;
    f32x4 a = acc4[ct];
#pragma unroll
    for (int kt = 0; kt < KT; ++kt) {
      bf16x8 wh = *reinterpret_cast<const bf16x8*>(hp + kt * 32);
      bf16x8 wl = *reinterpret_cast<const bf16x8*>(lp + kt * 32);
      a = __builtin_amdgcn_mfma_f32_16x16x32_bf16(ahi[kt], wh, a, 0, 0, 0);
      a = __builtin_amdgcn_mfma_f32_16x16x32_bf16(alo[kt], wh, a, 0, 0, 0);
      a = __builtin_amdgcn_mfma_f32_16x16x32_bf16(ahi[kt], wl, a, 0, 0, 0);
    }
    acc4[ct] = a;
  }
}

__global__ __launch_bounds__(256) void sa3f_kernel(
    const float* __restrict__ nx2, const float* __restrict__ f2,
    const float* __restrict__ W0full,
    const unsigned short* __restrict__ G0h, const unsigned short* __restrict__ G0l,
    const float* __restrict__ B0,
    const unsigned short* __restrict__ G1h, const unsigned short* __restrict__ G1l,
    const float* __restrict__ B1,
    const unsigned short* __restrict__ G2h, const unsigned short* __restrict__ G2l,
    const float* __restrict__ B2,
    float* __restrict__ partial) {
  __shared__ __align__(16) float A[16 * AS3];
  __shared__ float sxyz[16][4];
  const int t = threadIdx.x, l = t & 63, w = t >> 6;
  const int b = blockIdx.x >> 3, rb = blockIdx.x & 7;
  const int row0 = rb * 16;
  {
    int r = t >> 4, cc = (t & 15) * 16;
    const float* src = f2 + ((size_t)b * 128 + row0 + r) * 256 + cc;
    float* dstp = A + r * AS3 + cc;
#pragma unroll
    for (int j = 0; j < 16; j += 4)
      *reinterpret_cast<float4*>(dstp + j) = *reinterpret_cast<const float4*>(src + j);
    if (t < 16) {
      const float* s = nx2 + ((size_t)b * 128 + row0 + t) * 3;
      sxyz[t][0] = s[0]; sxyz[t][1] = s[1]; sxyz[t][2] = s[2];
    }
  }
  __syncthreads();

  {  // L1: K=256 MFMA + xyz f32 correction -> N=256 (wave cols 64)
    bf16x8 ah[8], al[8];
    sa3_frags(A, l, 8, ah, al);
    __syncthreads();
    f32x4 acc[4];
#pragma unroll
    for (int i = 0; i < 4; ++i) acc[i] = f32x4{0.f, 0.f, 0.f, 0.f};
    sa3_mm64<256>(G0h, G0l, w * 64, l, ah, al, acc);
    float xr[4][3];
#pragma unroll
    for (int r = 0; r < 4; ++r) {
      int row = (l >> 4) * 4 + r;
      xr[r][0] = sxyz[row][0]; xr[r][1] = sxyz[row][1]; xr[r][2] = sxyz[row][2];
    }
#pragma unroll
    for (int ct = 0; ct < 4; ++ct) {
      int col = w * 64 + ct * 16 + (l & 15);
      float w0 = W0full[col], w1 = W0full[256 + col], w2 = W0full[512 + col];
      float bia = B0[col];
#pragma unroll
      for (int r = 0; r < 4; ++r) {
        int row = (l >> 4) * 4 + r;
        float v = acc[ct][r] + xr[r][0] * w0 + xr[r][1] * w1 + xr[r][2] * w2 + bia;
        A[row * AS3 + col] = fmaxf(v, 0.f);
      }
    }
    __syncthreads();
  }

  {  // L2: K=256 -> N=512 (wave cols 128)
    bf16x8 ah[8], al[8];
    sa3_frags(A, l, 8, ah, al);
    __syncthreads();
    f32x4 acc[8];
#pragma unroll
    for (int i = 0; i < 8; ++i) acc[i] = f32x4{0.f, 0.f, 0.f, 0.f};
    sa3_mm64<256>(G1h, G1l, w * 128, l, ah, al, acc);
    sa3_mm64<256>(G1h, G1l, w * 128 + 64, l, ah, al, acc + 4);
#pragma unroll
    for (int cc = 0; cc < 8; ++cc) {
      int col = w * 128 + cc * 16 + (l & 15);
      float bia = B1[col];
#pragma unroll
      for (int r = 0; r < 4; ++r) {
        int row = (l >> 4) * 4 + r;
        A[row * AS3 + col] = fmaxf(acc[cc][r] + bia, 0.f);
      }
    }
    __syncthreads();
  }

  {  // L3: K=512 -> N=1024 (wave cols 256), maxpool 16 rows -> partial
    bf16x8 ah[16], al[16];
    sa3_frags(A, l, 16, ah, al);
    float* pout = partial + ((size_t)(b * 8 + rb)) * 1024;
#pragma unroll
    for (int sub = 0; sub < 4; ++sub) {
      f32x4 acc[4];
#pragma unroll
      for (int i = 0; i < 4; ++i) acc[i] = f32x4{0.f, 0.f, 0.f, 0.f};
      sa3_mm64<512>(G2h, G2l, w * 256 + sub * 64, l, ah, al, acc);
#pragma unroll
      for (int ct = 0; ct < 4; ++ct) {
        int col = w * 256 + sub * 64 + ct * 16 + (l & 15);
        float v = fmaxf(fmaxf(acc[ct][0], acc[ct][1]), fmaxf(acc[ct][2], acc[ct][3]));
        v = fmaxf(v, __shfl_xor(v, 16, 64));
        v = fmaxf(v, __shfl_xor(v, 32, 64));
        if (l < 16) pout[col] = v + B2[col];  // relu deferred to heads (monotone)
      }
    }
  }
}

// ---------------------------------------------------------------- heads (8-way partial max + relu + dots)
__global__ __launch_bounds__(256) void heads_kernel(const float* __restrict__ partial,
                                                    const float* __restrict__ cw,
                                                    const float* __restrict__ cb,
                                                    const float* __restrict__ rw,
                                                    const float* __restrict__ rb,
                                                    float* __restrict__ out) {
  const int b = blockIdx.x, t = threadIdx.x;
  const float* pb = partial + (size_t)b * 8 * 1024;
  float a0 = 0, a1 = 0, a2 = 0, a3 = 0, a4 = 0;
  for (int k = t; k < 1024; k += 256) {
    float m = pb[k];
#pragma unroll
    for (int p = 1; p < 8; ++p) m = fmaxf(m, pb[p * 1024 + k]);
    float f = fmaxf(m, 0.f);
    a0 += f * cw[k];
    const float* r = rw + (size_t)k * 4;
    a1 += f * r[0]; a2 += f * r[1]; a3 += f * r[2]; a4 += f * r[3];
  }
#pragma unroll
  for (int m = 32; m >= 1; m >>= 1) {
    a0 += __shfl_xor(a0, m, 64); a1 += __shfl_xor(a1, m, 64);
    a2 += __shfl_xor(a2, m, 64); a3 += __shfl_xor(a3, m, 64);
    a4 += __shfl_xor(a4, m, 64);
  }
  __shared__ float red[4][5];
  const int wv = t >> 6, ln = t & 63;
  if (ln == 0) { red[wv][0] = a0; red[wv][1] = a1; red[wv][2] = a2; red[wv][3] = a3; red[wv][4] = a4; }
  __syncthreads();
  if (t == 0) {
    float s0 = red[0][0] + red[1][0] + red[2][0] + red[3][0];
    float s1 = red[0][1] + red[1][1] + red[2][1] + red[3][1];
    float s2 = red[0][2] + red[1][2] + red[2][2] + red[3][2];
    float s3 = red[0][3] + red[1][3] + red[2][3] + red[3][3];
    float s4 = red[0][4] + red[1][4] + red[2][4] + red[3][4];
    out[b] = s0 + cb[0];
    out[32 + b * 4 + 0] = s1 + rb[0];
    out[32 + b * 4 + 1] = s2 + rb[1];
    out[32 + b * 4 + 2] = s3 + rb[2];
    out[32 + b * 4 + 3] = s4 + rb[3];
  }
}

// ---------------------------------------------------------------- launch
extern "C" void kernel_launch(void* const* d_in, const int* in_sizes, int n_in,
                              void* d_out, int out_size, void* d_ws, size_t ws_size,
                              hipStream_t stream) {
  (void)in_sizes; (void)n_in; (void)out_size; (void)ws_size;
  const float* xyz  = (const float*)d_in[0];
  const float* s1w0 = (const float*)d_in[1];  const float* s1b0 = (const float*)d_in[2];
  const float* s1w1 = (const float*)d_in[3];  const float* s1b1 = (const float*)d_in[4];
  const float* s1w2 = (const float*)d_in[5];  const float* s1b2 = (const float*)d_in[6];
  const float* s2w0 = (const float*)d_in[7];  const float* s2b0 = (const float*)d_in[8];
  const float* s2w1 = (const float*)d_in[9];  const float* s2b1 = (const float*)d_in[10];
  const float* s2w2 = (const float*)d_in[11]; const float* s2b2 = (const float*)d_in[12];
  const float* s3w0 = (const float*)d_in[13]; const float* s3b0 = (const float*)d_in[14];
  const float* s3w1 = (const float*)d_in[15]; const float* s3b1 = (const float*)d_in[16];
  const float* s3w2 = (const float*)d_in[17]; const float* s3b2 = (const float*)d_in[18];
  const float* clsw = (const float*)d_in[19]; const float* clsb = (const float*)d_in[20];
  const float* regw = (const float*)d_in[21]; const float* regb = (const float*)d_in[22];

  char* ws = (char*)d_ws;
  float* nx1   = (float*)(ws + 0);          // 32*512*3
  int*   gidx1 = (int*)  (ws + 196608);     // 32*512*32
  float* f1    = (float*)(ws + 2293760);    // 32*512*128
  float* nx2   = (float*)(ws + 10682368);   // 32*128*3
  int*   gidx2 = (int*)  (ws + 10731520);   // 32*128*64
  float* f2    = (float*)(ws + 11780096);   // 32*128*256

  // SA1/SA2 prepped weights (u16 hi/lo, transposed [n][k])
  unsigned short* wt = (unsigned short*)(ws + 20168704);
  unsigned short* g11h = wt;            // 64*64
  unsigned short* g11l = wt + 4096;
  unsigned short* g12h = wt + 8192;     // 128*64
  unsigned short* g12l = wt + 16384;
  unsigned short* g20h = wt + 24576;    // 128*128 (rows 3..130 of s2w0)
  unsigned short* g20l = wt + 40960;
  unsigned short* g21h = wt + 57344;    // 128*128
  unsigned short* g21l = wt + 73728;
  unsigned short* g22h = wt + 90112;    // 256*128
  unsigned short* g22l = wt + 122880;   // ends at byte 20168704+311296 = 20480000
  // SA3 prepped weights
  unsigned short* g30h = (unsigned short*)(ws + 20480000);  // 256x256
  unsigned short* g30l = (unsigned short*)(ws + 20611072);
  unsigned short* g31h = (unsigned short*)(ws + 20742144);  // 512x256
  unsigned short* g31l = (unsigned short*)(ws + 21004288);
  unsigned short* g32h = (unsigned short*)(ws + 21266432);  // 1024x512
  unsigned short* g32l = (unsigned short*)(ws + 22315008);
  float* partial = (float*)(ws + 23363584);                 // 32*8*1024 f32 -> ends 24412160

  const float r21 = (float)(0.2 * 0.2);
  const float r22 = (float)(0.4 * 0.4);

  WPTab tab;
  int off = 0;
  auto set = [&](int i, const float* W, unsigned short* hi, unsigned short* lo,
                 int K, int N, int row0) {
    tab.e[i] = WPEnt{W, hi, lo, K, N, row0, off, off + K * N};
    off += K * N;
  };
  set(0, s1w1, g11h, g11l, 64, 64, 0);
  set(1, s1w2, g12h, g12l, 64, 128, 0);
  set(2, s2w0, g20h, g20l, 128, 128, 3);
  set(3, s2w1, g21h, g21l, 128, 128, 0);
  set(4, s2w2, g22h, g22l, 128, 256, 0);
  set(5, s3w0, g30h, g30l, 256, 256, 3);
  set(6, s3w1, g31h, g31l, 256, 512, 0);
  set(7, s3w2, g32h, g32l, 512, 1024, 0);
  const int wblocks = (off + 255) / 256;

  fps1_wprep_kernel<<<32 + wblocks, 256, 0, stream>>>(xyz, nx1, tab);
  fps2_bq1_kernel<<<32 + 4096, 256, 0, stream>>>(xyz, nx1, gidx1, nx2, r21);
  bq2_sa1_kernel<<<1024 + 8192, 256, 0, stream>>>(
      xyz, nx1, nx2, gidx2, r22, gidx1,
      s1w0, s1b0, g11h, g11l, s1b1, g12h, g12l, s1b2, f1);
  sa_mfma_kernel<512, 128, 64, 1, 128, 128, 128, 256><<<4096, 256, 0, stream>>>(
      nx1, nx2, gidx2, f1, s2w0, s2b0,
      g20h, g20l, g21h, g21l, s2b1, g22h, g22l, s2b2, f2);
  sa3f_kernel<<<256, 256, 0, stream>>>(nx2, f2, s3w0, g30h, g30l, s3b0,
                                       g31h, g31l, s3b1, g32h, g32l, s3b2, partial);
  heads_kernel<<<32, 256, 0, stream>>>(partial, clsw, clsb, regw, regb, (float*)d_out);
}

// Round 12
// 712.418 us; speedup vs baseline: 2.0272x; 1.0224x over previous
//
#include <hip/hip_runtime.h>

#define DEVINL __device__ __forceinline__

typedef __attribute__((ext_vector_type(8))) short bf16x8;
typedef __attribute__((ext_vector_type(8))) unsigned short u16x8;
typedef __attribute__((ext_vector_type(4))) float f32x4;

// RNE f32 -> bf16 bits (no NaN handling needed for this workload)
DEVINL unsigned short f2bh(float f){
  unsigned u = __float_as_uint(f);
  return (unsigned short)((u + 0x7FFFu + ((u >> 16) & 1u)) >> 16);
}
DEVINL float bh2f(unsigned short h){ return __uint_as_float(((unsigned)h) << 16); }

// Wave64 max-reduce of a u64 key via DPP (VALU latency, no DS pipe).
DEVINL unsigned long long dpp_max_u64(unsigned long long k) {
#define DPP_STEP(ctrl)                                                        \
  {                                                                           \
    int hi = (int)(k >> 32), lo = (int)(unsigned)k;                           \
    int oh = __builtin_amdgcn_update_dpp(0, hi, ctrl, 0xF, 0xF, 1);           \
    int ol = __builtin_amdgcn_update_dpp(0, lo, ctrl, 0xF, 0xF, 1);           \
    unsigned long long ok =                                                   \
        ((unsigned long long)(unsigned)oh << 32) | (unsigned)ol;              \
    if (ok > k) k = ok;                                                       \
  }
  DPP_STEP(0x111)  // row_shr:1
  DPP_STEP(0x112)  // row_shr:2
  DPP_STEP(0x114)  // row_shr:4
  DPP_STEP(0x118)  // row_shr:8
  DPP_STEP(0x142)  // row_bcast:15
  DPP_STEP(0x143)  // row_bcast:31
#undef DPP_STEP
  return k;
}

// ---------------------------------------------------------------- FPS body (R4-proven)
// NW==1: no barriers at all (single-wave LDS is program-ordered) -> callable
// by wave 0 only while other waves of the block retire immediately.
template<int N, int NP, int NT>
DEVINL void fps_body(const float* __restrict__ xyz, float* __restrict__ nxyz,
                     int b, int t) {
  constexpr int PTS = N / NT;
  constexpr int NW = NT / 64;
  __shared__ float xs[N], ys[N], zs[N];
  __shared__ int farr[NP];
  __shared__ unsigned long long sk[2][(NW > 1 ? NW : 1)];
  float px[PTS], py[PTS], pz[PTS], dst[PTS];
  const float* base = xyz + (size_t)b * N * 3;
#pragma unroll
  for (int j = 0; j < PTS; ++j) {
    int i = t + j * NT;
    float x = base[i * 3 + 0], y = base[i * 3 + 1], z = base[i * 3 + 2];
    px[j] = x; py[j] = y; pz[j] = z;
    xs[i] = x; ys[i] = y; zs[i] = z;
    dst[j] = 1e10f;
  }
  if constexpr (NW > 1) __syncthreads();
  int far = 0;
  const int wv = t >> 6, ln = t & 63;
  for (int s = 0; s < NP; ++s) {
    float cx = xs[far], cy = ys[far], cz = zs[far];
    if (t == 0) farr[s] = far;
    float bv = -1.f; int bi = 0;
#pragma unroll
    for (int j = 0; j < PTS; ++j) {
      // no-fma, left-to-right: matches numpy elementwise + sum order
      float dx = __fsub_rn(px[j], cx), dy = __fsub_rn(py[j], cy), dz = __fsub_rn(pz[j], cz);
      float d = __fadd_rn(__fadd_rn(__fmul_rn(dx, dx), __fmul_rn(dy, dy)), __fmul_rn(dz, dz));
      float nd = fminf(dst[j], d);
      dst[j] = nd;
      int i = t + j * NT;
      if (nd > bv) { bv = nd; bi = i; }  // strict >: first max kept per thread
    }
    // pack: max key == max dist, tie -> larger ~idx == smaller idx
    unsigned long long key =
        ((unsigned long long)__float_as_uint(bv) << 32) | (unsigned)(~bi);
    key = dpp_max_u64(key);
    if constexpr (NW == 1) {
      int rl = __builtin_amdgcn_readlane((int)(unsigned)key, 63);
      far = (int)(~(unsigned)rl);
    } else {
      const int p = s & 1;
      if (ln == 63) sk[p][wv] = key;
      __syncthreads();
      unsigned long long m = sk[p][0];
#pragma unroll
      for (int q = 1; q < NW; ++q) {
        unsigned long long qk = sk[p][q];
        if (qk > m) m = qk;
      }
      far = (int)(~(unsigned)m);
    }
  }
  if constexpr (NW > 1) __syncthreads();
  for (int s2 = t; s2 < NP; s2 += NT) {
    int fi = farr[s2];
    float* o = nxyz + ((size_t)b * NP + s2) * 3;
    o[0] = xs[fi]; o[1] = ys[fi]; o[2] = zs[fi];
  }
}

// ---------------------------------------------------------------- ball query body (unchanged semantics)
template<int N, int NS>
DEVINL void bq_body(const float* __restrict__ pts, const float* __restrict__ centers,
                    int* __restrict__ gidx, int Q, float r2, int blk, int t) {
  const int wv = t >> 6, ln = t & 63;
  const int g = blk * 4 + wv;
  const int b = g / Q, q = g % Q;
  const float* pb = pts + (size_t)b * N * 3;
  const float* c = centers + ((size_t)b * Q + q) * 3;
  const float cx = c[0], cy = c[1], cz = c[2];
  __shared__ int gbuf[4][NS];
  int taken = 0;
  for (int base = 0; base < N; base += 64) {
    if (taken >= NS) break;
    int i = base + ln;
    float dx = __fsub_rn(pb[i * 3 + 0], cx), dy = __fsub_rn(pb[i * 3 + 1], cy),
          dz = __fsub_rn(pb[i * 3 + 2], cz);
    float d = __fadd_rn(__fadd_rn(__fmul_rn(dx, dx), __fmul_rn(dy, dy)), __fmul_rn(dz, dz));
    bool in = (d <= r2);
    unsigned long long mk = __ballot(in);
    int rank = __popcll(mk & ((1ull << ln) - 1ull));
    int pos = taken + rank;
    if (in && pos < NS) gbuf[wv][pos] = i;
    taken += (int)__popcll(mk);
  }
  int total = taken < NS ? taken : NS;
  int first = gbuf[wv][0];
  int* out = gidx + ((size_t)b * Q + q) * NS;
  for (int j = ln; j < NS; j += 64) out[j] = (j < total) ? gbuf[wv][j] : first;
}

// ---------------------------------------------------------------- weight prep body
struct WPEnt { const float* W; unsigned short* hi; unsigned short* lo; int K, N, row0, beg, end; };
struct WPTab { WPEnt e[8]; };
DEVINL void wprep_body(const WPTab& tab, int idx) {
#pragma unroll
  for (int i = 0; i < 8; ++i) {
    const WPEnt& E = tab.e[i];
    if (idx >= E.beg && idx < E.end) {
      int local = idx - E.beg;
      int k = local / E.N, n = local - k * E.N;
      float v = E.W[(size_t)(E.row0 + k) * E.N + n];
      unsigned short h = f2bh(v);
      E.hi[(size_t)n * E.K + k] = h;
      E.lo[(size_t)n * E.K + k] = f2bh(v - bh2f(h));
    }
  }
}

// ---------------------------------------------------------------- fused launches
// [fps1 || wprep]
__global__ __launch_bounds__(256) void fps1_wprep_kernel(const float* __restrict__ xyz,
                                                         float* __restrict__ nx1, WPTab tab) {
  if (blockIdx.x < 32) { fps_body<4096, 512, 256>(xyz, nx1, blockIdx.x, threadIdx.x); return; }
  wprep_body(tab, (blockIdx.x - 32) * 256 + threadIdx.x);
}

// [fps2 || bq1]: fps2 as single wave (NT=64, barrier-free); waves 1-3 retire.
__global__ __launch_bounds__(256) void fps2_bq1_kernel(const float* __restrict__ xyz,
                                                       const float* __restrict__ nx1,
                                                       int* __restrict__ gidx1,
                                                       float* __restrict__ nx2, float r21) {
  if (blockIdx.x < 32) {
    if (threadIdx.x < 64) fps_body<512, 128, 64>(nx1, nx2, blockIdx.x, threadIdx.x);
    return;
  }
  bq_body<4096, 32>(xyz, nx1, gidx1, 512, r21, blockIdx.x - 32, threadIdx.x);
}

// ---------------------------------------------------------------- split-bf16 MFMA layer (generic thread count)
// T14 async-STAGE: prefetch chunk c+1's W into registers before chunk c's
// MFMA cluster; LDS-write after the barrier. MFMA order bit-identical.
template<int K, int N, int AS, int WS, bool XYZC, int NTH>
DEVINL void do_layer(const unsigned short* __restrict__ Ghi, const unsigned short* __restrict__ Glo,
                     const float* __restrict__ Wxyz,
                     const float* __restrict__ A, unsigned short* __restrict__ Whi,
                     unsigned short* __restrict__ Wlo, const float* __restrict__ sxyz,
                     f32x4* acc, int t) {
  constexpr int KT = K / 32;
  constexpr int NCH = N / 64;
  constexpr int K8 = K / 8;
  constexpr int SI = (64 * K8) / NTH;  // staging iterations
  const int l = t & 63, wv = t >> 6;

  u16x8 rh[SI], rl[SI];
#pragma unroll
  for (int s = 0; s < SI; ++s) {
    int u = t + s * NTH;
    int nn = u / K8, k8 = (u - nn * K8) * 8;
    rh[s] = *reinterpret_cast<const u16x8*>(Ghi + (size_t)nn * K + k8);
    rl[s] = *reinterpret_cast<const u16x8*>(Glo + (size_t)nn * K + k8);
  }

  bf16x8 ahi[KT], alo[KT];
  {
    const int row = wv * 16 + (l & 15);
    const float* ap = A + row * AS + (l >> 4) * 8;
#pragma unroll
    for (int kt = 0; kt < KT; ++kt) {
      float4 v0 = *reinterpret_cast<const float4*>(ap + kt * 32);
      float4 v1 = *reinterpret_cast<const float4*>(ap + kt * 32 + 4);
      float f[8] = {v0.x, v0.y, v0.z, v0.w, v1.x, v1.y, v1.z, v1.w};
      bf16x8 h, lo2;
#pragma unroll
      for (int j = 0; j < 8; ++j) {
        unsigned short hb = f2bh(f[j]);
        h[j] = (short)hb;
        lo2[j] = (short)f2bh(f[j] - bh2f(hb));
      }
      ahi[kt] = h; alo[kt] = lo2;
    }
  }
#pragma unroll
  for (int i = 0; i < N / 16; ++i) acc[i] = f32x4{0.f, 0.f, 0.f, 0.f};

#pragma unroll
  for (int c = 0; c < NCH; ++c) {
    __syncthreads();  // all waves done reading previous W contents
#pragma unroll
    for (int s = 0; s < SI; ++s) {
      int u = t + s * NTH;
      int nn = u / K8, k8 = (u - nn * K8) * 8;
      *reinterpret_cast<u16x8*>(Whi + nn * WS + k8) = rh[s];
      *reinterpret_cast<u16x8*>(Wlo + nn * WS + k8) = rl[s];
    }
    if (c + 1 < NCH) {
#pragma unroll
      for (int s = 0; s < SI; ++s) {
        int u = t + s * NTH;
        int nn = u / K8, k8 = (u - nn * K8) * 8;
        rh[s] = *reinterpret_cast<const u16x8*>(Ghi + (size_t)((c + 1) * 64 + nn) * K + k8);
        rl[s] = *reinterpret_cast<const u16x8*>(Glo + (size_t)((c + 1) * 64 + nn) * K + k8);
      }
    }
    __syncthreads();
#pragma unroll
    for (int ct = 0; ct < 4; ++ct) {
      const unsigned short* wp = Whi + (ct * 16 + (l & 15)) * WS + (l >> 4) * 8;
      const unsigned short* wq = Wlo + (ct * 16 + (l & 15)) * WS + (l >> 4) * 8;
      f32x4 a = acc[c * 4 + ct];
#pragma unroll
      for (int kt = 0; kt < KT; ++kt) {
        bf16x8 wh = *reinterpret_cast<const bf16x8*>(wp + kt * 32);
        bf16x8 wl = *reinterpret_cast<const bf16x8*>(wq + kt * 32);
        a = __builtin_amdgcn_mfma_f32_16x16x32_bf16(ahi[kt], wh, a, 0, 0, 0);
        a = __builtin_amdgcn_mfma_f32_16x16x32_bf16(alo[kt], wh, a, 0, 0, 0);
        a = __builtin_amdgcn_mfma_f32_16x16x32_bf16(ahi[kt], wl, a, 0, 0, 0);
      }
      acc[c * 4 + ct] = a;
    }
  }
  if constexpr (XYZC) {
    float xr[4][3];
#pragma unroll
    for (int r = 0; r < 4; ++r) {
      int row = wv * 16 + (l >> 4) * 4 + r;
      xr[r][0] = sxyz[row * 4 + 0];
      xr[r][1] = sxyz[row * 4 + 1];
      xr[r][2] = sxyz[row * 4 + 2];
    }
#pragma unroll
    for (int gt = 0; gt < N / 16; ++gt) {
      int col = gt * 16 + (l & 15);
      float w0 = Wxyz[col], w1 = Wxyz[N + col], w2 = Wxyz[2 * N + col];
#pragma unroll
      for (int r = 0; r < 4; ++r)
        acc[gt][r] += xr[r][0] * w0 + xr[r][1] * w1 + xr[r][2] * w2;
    }
  }
}

// ---------------------------------------------------------------- SA2 fused, 512 threads / 128 rows per block
// Each chunk-stage+barrier now serves 2x the samples; per-wave MFMA
// sequence identical to the 256-thread version (bit-identical results).
template<int NPTS, int Q, int M, int GPB, int FD, int C1, int C2, int C3>
__global__ __launch_bounds__(512) void sa2_kernel(
    const float* __restrict__ pts, const float* __restrict__ centers,
    const int* __restrict__ gidx, const float* __restrict__ feats,
    const float* __restrict__ W0, const float* __restrict__ B0,
    const unsigned short* __restrict__ G0h, const unsigned short* __restrict__ G0l,
    const unsigned short* __restrict__ G1h, const unsigned short* __restrict__ G1l,
    const float* __restrict__ B1,
    const unsigned short* __restrict__ G2h, const unsigned short* __restrict__ G2l,
    const float* __restrict__ B2,
    float* __restrict__ fout) {
  constexpr int NTH = 512;
  constexpr int ROWS = M * GPB;                 // 128
  constexpr int NWV = NTH / 64;                 // 8
  static_assert(ROWS == 16 * NWV, "wave owns 16 rows");
  constexpr int MK1 = (FD > C1 ? FD : C1);
  constexpr int MAXK = (MK1 > C2 ? MK1 : C2);
  constexpr int AS = MAXK + 12;
  constexpr int WS = MAXK + 8;
  __shared__ __align__(16) float A[ROWS * AS];
  __shared__ __align__(16) unsigned short Whi[64 * WS];
  __shared__ __align__(16) unsigned short Wlo[64 * WS];
  __shared__ float sxyz[ROWS * 4];
  __shared__ int idxs[ROWS];
  __shared__ float ctr[GPB][4];
  __shared__ float red[NWV][C3];

  const int t = threadIdx.x;
  const int blk = blockIdx.x;
  const int b = blk / (Q / GPB);
  const int q0 = (blk % (Q / GPB)) * GPB;
  const int l = t & 63, wv = t >> 6;

  if (t < GPB * 3) {
    int g = t / 3, c2 = t % 3;
    ctr[g][c2] = centers[((size_t)b * Q + q0 + g) * 3 + c2];
  }
  for (int m = t; m < ROWS; m += NTH)
    idxs[m] = gidx[((size_t)b * Q + q0 + (m / M)) * M + (m % M)];
  __syncthreads();
  const float* pb = pts + (size_t)b * NPTS * 3;
  for (int m = t; m < ROWS; m += NTH) {
    int g = m / M, i = idxs[m];
    sxyz[m * 4 + 0] = pb[i * 3 + 0] - ctr[g][0];
    sxyz[m * 4 + 1] = pb[i * 3 + 1] - ctr[g][1];
    sxyz[m * 4 + 2] = pb[i * 3 + 2] - ctr[g][2];
  }
  {  // FD=128 gather: thread t>>2 -> row, (t&3)*32 -> col chunk
    const int m = t >> 2, co = (t & 3) * (FD / 4);
    const float* src = feats + ((size_t)b * NPTS + idxs[m]) * FD + co;
    float* dst = A + m * AS + co;
#pragma unroll
    for (int j = 0; j < FD / 4; j += 4)
      *reinterpret_cast<float4*>(dst + j) = *reinterpret_cast<const float4*>(src + j);
  }
  __syncthreads();

  f32x4 acc[C3 / 16];

  do_layer<FD, C1, AS, WS, true, NTH>(G0h, G0l, W0, A, Whi, Wlo, sxyz, acc, t);
#pragma unroll
  for (int gt = 0; gt < C1 / 16; ++gt) {
    int col = gt * 16 + (l & 15);
    float bia = B0[col];
#pragma unroll
    for (int r = 0; r < 4; ++r)
      A[(wv * 16 + (l >> 4) * 4 + r) * AS + col] = fmaxf(acc[gt][r] + bia, 0.f);
  }

  do_layer<C1, C2, AS, WS, false, NTH>(G1h, G1l, nullptr, A, Whi, Wlo, sxyz, acc, t);
#pragma unroll
  for (int gt = 0; gt < C2 / 16; ++gt) {
    int col = gt * 16 + (l & 15);
    float bia = B1[col];
#pragma unroll
    for (int r = 0; r < 4; ++r)
      A[(wv * 16 + (l >> 4) * 4 + r) * AS + col] = fmaxf(acc[gt][r] + bia, 0.f);
  }

  do_layer<C2, C3, AS, WS, false, NTH>(G2h, G2l, nullptr, A, Whi, Wlo, sxyz, acc, t);
#pragma unroll
  for (int gt = 0; gt < C3 / 16; ++gt) {
    int col = gt * 16 + (l & 15);
    float v = fmaxf(fmaxf(acc[gt][0], acc[gt][1]), fmaxf(acc[gt][2], acc[gt][3]));
    v = fmaxf(v, __shfl_xor(v, 16, 64));
    v = fmaxf(v, __shfl_xor(v, 32, 64));
    if (l < 16) red[wv][col] = v + B2[col];
  }
  __syncthreads();
  constexpr int WPG = NWV / GPB;  // waves per group
  for (int u = t; u < GPB * C3; u += NTH) {
    int g = u / C3, c2 = u - g * C3;
    float v = red[g * WPG][c2];
#pragma unroll
    for (int w = 1; w < WPG; ++w) v = fmaxf(v, red[g * WPG + w][c2]);
    fout[((size_t)b * Q + q0 + g) * C3 + c2] = fmaxf(v, 0.f);
  }
}

// ---------------------------------------------------------------- SA1 body, grid-strided: stage W once, process TPB tiles
template<int NPTS, int Q, int M, int GPB, int TPB>
DEVINL void sa1_body(const float* __restrict__ pts, const float* __restrict__ centers,
                     const int* __restrict__ gidx,
                     const float* __restrict__ W0, const float* __restrict__ B0,
                     const unsigned short* __restrict__ G1h, const unsigned short* __restrict__ G1l,
                     const float* __restrict__ B1,
                     const unsigned short* __restrict__ G2h, const unsigned short* __restrict__ G2l,
                     const float* __restrict__ B2,
                     float* __restrict__ fout, int sblk, int t) {
  static_assert(M * GPB == 64, "");
  constexpr int C1 = 64, C2 = 64, C3 = 128;
  constexpr int AS = 76;
  constexpr int WS = 72;
  constexpr int NC = C2 + C3;
  __shared__ __align__(16) float A[64 * AS];
  __shared__ __align__(16) unsigned short Wh[NC * WS];
  __shared__ __align__(16) unsigned short Wl[NC * WS];
  __shared__ float sxyz[64 * 4];
  __shared__ int idxs[64];
  __shared__ float ctr[GPB][4];
  __shared__ float red[4][C3];

  const int l = t & 63, wv = t >> 6;

  // stage ALL weights once per block (shared by all TPB tiles)
  for (int u = t; u < NC * 8; u += 256) {
    int col = u >> 3, k8 = (u & 7) * 8;
    const unsigned short* sh = (col < C2) ? G1h + (size_t)col * 64 + k8
                                          : G2h + (size_t)(col - C2) * 64 + k8;
    const unsigned short* sl = (col < C2) ? G1l + (size_t)col * 64 + k8
                                          : G2l + (size_t)(col - C2) * 64 + k8;
    *reinterpret_cast<u16x8*>(Wh + col * WS + k8) = *reinterpret_cast<const u16x8*>(sh);
    *reinterpret_cast<u16x8*>(Wl + col * WS + k8) = *reinterpret_cast<const u16x8*>(sl);
  }

  for (int it = 0; it < TPB; ++it) {
    const int blk = sblk * TPB + it;
    const int b = blk / (Q / GPB);
    const int q0 = (blk % (Q / GPB)) * GPB;

    if (t < GPB * 3) {
      int g = t / 3, c2 = t % 3;
      ctr[g][c2] = centers[((size_t)b * Q + q0 + g) * 3 + c2];
    }
    for (int m = t; m < 64; m += 256)
      idxs[m] = gidx[((size_t)b * Q + q0 + (m / M)) * M + (m % M)];
    __syncthreads();  // W staged (1st iter) + ctr/idxs visible
    const float* pb = pts + (size_t)b * NPTS * 3;
    for (int m = t; m < 64; m += 256) {
      int g = m / M, i = idxs[m];
      sxyz[m * 4 + 0] = pb[i * 3 + 0] - ctr[g][0];
      sxyz[m * 4 + 1] = pb[i * 3 + 1] - ctr[g][1];
      sxyz[m * 4 + 2] = pb[i * 3 + 2] - ctr[g][2];
    }
    __syncthreads();

    // layer0: 3 -> 64 in exact f32 VALU
    for (int u = t; u < 64 * C1; u += 256) {
      int m = u / C1, c2 = u - m * C1;
      float v = B0[c2] + sxyz[m * 4 + 0] * W0[0 * C1 + c2]
                       + sxyz[m * 4 + 1] * W0[1 * C1 + c2]
                       + sxyz[m * 4 + 2] * W0[2 * C1 + c2];
      A[m * AS + c2] = fmaxf(v, 0.f);
    }
    __syncthreads();

    f32x4 acc[8];
    // ---- L2: 64 -> 64, W cols [0,64), barrier-free
    {
      bf16x8 ah[2], al[2];
      const float* ap = A + (wv * 16 + (l & 15)) * AS + (l >> 4) * 8;
#pragma unroll
      for (int kt = 0; kt < 2; ++kt) {
        float4 v0 = *reinterpret_cast<const float4*>(ap + kt * 32);
        float4 v1 = *reinterpret_cast<const float4*>(ap + kt * 32 + 4);
        float f[8] = {v0.x, v0.y, v0.z, v0.w, v1.x, v1.y, v1.z, v1.w};
        bf16x8 h, lo2;
#pragma unroll
        for (int j = 0; j < 8; ++j) {
          unsigned short hb = f2bh(f[j]);
          h[j] = (short)hb;
          lo2[j] = (short)f2bh(f[j] - bh2f(hb));
        }
        ah[kt] = h; al[kt] = lo2;
      }
#pragma unroll
      for (int i = 0; i < 4; ++i) acc[i] = f32x4{0.f, 0.f, 0.f, 0.f};
#pragma unroll
      for (int ct = 0; ct < 4; ++ct) {
        const unsigned short* wp = Wh + (ct * 16 + (l & 15)) * WS + (l >> 4) * 8;
        const unsigned short* wq = Wl + (ct * 16 + (l & 15)) * WS + (l >> 4) * 8;
        f32x4 a = acc[ct];
#pragma unroll
        for (int kt = 0; kt < 2; ++kt) {
          bf16x8 wh = *reinterpret_cast<const bf16x8*>(wp + kt * 32);
          bf16x8 wl = *reinterpret_cast<const bf16x8*>(wq + kt * 32);
          a = __builtin_amdgcn_mfma_f32_16x16x32_bf16(ah[kt], wh, a, 0, 0, 0);
          a = __builtin_amdgcn_mfma_f32_16x16x32_bf16(al[kt], wh, a, 0, 0, 0);
          a = __builtin_amdgcn_mfma_f32_16x16x32_bf16(ah[kt], wl, a, 0, 0, 0);
        }
        acc[ct] = a;
      }
#pragma unroll
      for (int gt = 0; gt < 4; ++gt) {
        int col = gt * 16 + (l & 15);
        float bia = B1[col];
#pragma unroll
        for (int r = 0; r < 4; ++r)
          A[(wv * 16 + (l >> 4) * 4 + r) * AS + col] = fmaxf(acc[gt][r] + bia, 0.f);
      }
    }

    // ---- L3: 64 -> 128, W cols [64,192), maxpool epilogue
    {
      bf16x8 ah[2], al[2];
      const float* ap = A + (wv * 16 + (l & 15)) * AS + (l >> 4) * 8;
#pragma unroll
      for (int kt = 0; kt < 2; ++kt) {
        float4 v0 = *reinterpret_cast<const float4*>(ap + kt * 32);
        float4 v1 = *reinterpret_cast<const float4*>(ap + kt * 32 + 4);
        float f[8] = {v0.x, v0.y, v0.z, v0.w, v1.x, v1.y, v1.z, v1.w};
        bf16x8 h, lo2;
#pragma unroll
        for (int j = 0; j < 8; ++j) {
          unsigned short hb = f2bh(f[j]);
          h[j] = (short)hb;
          lo2[j] = (short)f2bh(f[j] - bh2f(hb));
        }
        ah[kt] = h; al[kt] = lo2;
      }
#pragma unroll
      for (int i = 0; i < 8; ++i) acc[i] = f32x4{0.f, 0.f, 0.f, 0.f};
#pragma unroll
      for (int gt = 0; gt < 8; ++gt) {
        const unsigned short* wp = Wh + (C2 + gt * 16 + (l & 15)) * WS + (l >> 4) * 8;
        const unsigned short* wq = Wl + (C2 + gt * 16 + (l & 15)) * WS + (l >> 4) * 8;
        f32x4 a = acc[gt];
#pragma unroll
        for (int kt = 0; kt < 2; ++kt) {
          bf16x8 wh = *reinterpret_cast<const bf16x8*>(wp + kt * 32);
          bf16x8 wl = *reinterpret_cast<const bf16x8*>(wq + kt * 32);
          a = __builtin_amdgcn_mfma_f32_16x16x32_bf16(ah[kt], wh, a, 0, 0, 0);
          a = __builtin_amdgcn_mfma_f32_16x16x32_bf16(al[kt], wh, a, 0, 0, 0);
          a = __builtin_amdgcn_mfma_f32_16x16x32_bf16(ah[kt], wl, a, 0, 0, 0);
        }
        acc[gt] = a;
      }
#pragma unroll
      for (int gt = 0; gt < 8; ++gt) {
        int col = gt * 16 + (l & 15);
        float v = fmaxf(fmaxf(acc[gt][0], acc[gt][1]), fmaxf(acc[gt][2], acc[gt][3]));
        v = fmaxf(v, __shfl_xor(v, 16, 64));
        v = fmaxf(v, __shfl_xor(v, 32, 64));
        if (l < 16) red[wv][col] = v + B2[col];
      }
    }
    __syncthreads();
    constexpr int WPG = 4 / GPB;
    for (int u = t; u < GPB * C3; u += 256) {
      int g = u / C3, c2 = u - g * C3;
      float v = red[g * WPG][c2];
#pragma unroll
      for (int w = 1; w < WPG; ++w) v = fmaxf(v, red[g * WPG + w][c2]);
      fout[((size_t)b * Q + q0 + g) * C3 + c2] = fmaxf(v, 0.f);
    }
    __syncthreads();  // red/ctr/idxs/A reuse by next tile
  }
}

// [bq2 || sa1]: bq2 needs nx1/nx2 only; sa1 needs gidx1 (prior launch).
__global__ __launch_bounds__(256) void bq2_sa1_kernel(
    const float* __restrict__ xyz, const float* __restrict__ nx1,
    const float* __restrict__ nx2, int* __restrict__ gidx2, float r22,
    const int* __restrict__ gidx1,
    const float* __restrict__ s1w0, const float* __restrict__ s1b0,
    const unsigned short* __restrict__ g11h, const unsigned short* __restrict__ g11l,
    const float* __restrict__ s1b1,
    const unsigned short* __restrict__ g12h, const unsigned short* __restrict__ g12l,
    const float* __restrict__ s1b2, float* __restrict__ f1) {
  if (blockIdx.x < 1024) {
    bq_body<512, 64>(nx1, nx2, gidx2, 128, r22, blockIdx.x, threadIdx.x);
    return;
  }
  sa1_body<4096, 512, 32, 2, 4>(xyz, nx1, gidx1, s1w0, s1b0, g11h, g11l, s1b1,
                                g12h, g12l, s1b2, f1, blockIdx.x - 1024, threadIdx.x);
}

// ---------------------------------------------------------------- SA3 fused
constexpr int AS3 = 532;
DEVINL void sa3_frags(const float* __restrict__ A, int l, int KT, bf16x8* ahi, bf16x8* alo) {
  const float* ap = A + (l & 15) * AS3 + (l >> 4) * 8;
  for (int kt = 0; kt < KT; ++kt) {
    float4 v0 = *reinterpret_cast<const float4*>(ap + kt * 32);
    float4 v1 = *reinterpret_cast<const float4*>(ap + kt * 32 + 4);
    float f[8] = {v0.x, v0.y, v0.z, v0.w, v1.x, v1.y, v1.z, v1.w};
    bf16x8 h, lo2;
#pragma unroll
    for (int j = 0; j < 8; ++j) {
      unsigned short hb = f2bh(f[j]);
      h[j] = (short)hb;
      lo2[j] = (short)f2bh(f[j] - bh2f(hb));
    }
    ahi[kt] = h; alo[kt] = lo2;
  }
}

template<int K>
DEVINL void sa3_mm64(const unsigned short* __restrict__ Gh, const unsigned short* __restrict__ Gl,
                     int ncol0, int l, const bf16x8* ahi, const bf16x8* alo, f32x4* acc4) {
  constexpr int KT = K / 32;
#pragma unroll
  for (int ct = 0; ct < 4; ++ct) {
    const unsigned short* hp = Gh + (size_t)(ncol0 + ct * 16 + (l & 15)) * K + (l >> 4) * 8;
    const unsigned short* lp = Gl + (size_t)(ncol0 + ct * 16 + (l & 15)) * K + (l >> 4) * 8;
    f32x4 a = acc4[ct];
#pragma unroll
    for (int kt = 0; kt < KT; ++kt) {
      bf16x8 wh = *reinterpret_cast<const bf16x8*>(hp + kt * 32);
      bf16x8 wl = *reinterpret_cast<const bf16x8*>(lp + kt * 32);
      a = __builtin_amdgcn_mfma_f32_16x16x32_bf16(ahi[kt], wh, a, 0, 0, 0);
      a = __builtin_amdgcn_mfma_f32_16x16x32_bf16(alo[kt], wh, a, 0, 0, 0);
      a = __builtin_amdgcn_mfma_f32_16x16x32_bf16(ahi[kt], wl, a, 0, 0, 0);
    }
    acc4[ct] = a;
  }
}

__global__ __launch_bounds__(256) void sa3f_kernel(
    const float* __restrict__ nx2, const float* __restrict__ f2,
    const float* __restrict__ W0full,
    const unsigned short* __restrict__ G0h, const unsigned short* __restrict__ G0l,
    const float* __restrict__ B0,
    const unsigned short* __restrict__ G1h, const unsigned short* __restrict__ G1l,
    const float* __restrict__ B1,
    const unsigned short* __restrict__ G2h, const unsigned short* __restrict__ G2l,
    const float* __restrict__ B2,
    float* __restrict__ partial) {
  __shared__ __align__(16) float A[16 * AS3];
  __shared__ float sxyz[16][4];
  const int t = threadIdx.x, l = t & 63, w = t >> 6;
  const int b = blockIdx.x >> 3, rb = blockIdx.x & 7;
  const int row0 = rb * 16;
  {
    int r = t >> 4, cc = (t & 15) * 16;
    const float* src = f2 + ((size_t)b * 128 + row0 + r) * 256 + cc;
    float* dstp = A + r * AS3 + cc;
#pragma unroll
    for (int j = 0; j < 16; j += 4)
      *reinterpret_cast<float4*>(dstp + j) = *reinterpret_cast<const float4*>(src + j);
    if (t < 16) {
      const float* s = nx2 + ((size_t)b * 128 + row0 + t) * 3;
      sxyz[t][0] = s[0]; sxyz[t][1] = s[1]; sxyz[t][2] = s[2];
    }
  }
  __syncthreads();

  {  // L1: K=256 MFMA + xyz f32 correction -> N=256 (wave cols 64)
    bf16x8 ah[8], al[8];
    sa3_frags(A, l, 8, ah, al);
    __syncthreads();
    f32x4 acc[4];
#pragma unroll
    for (int i = 0; i < 4; ++i) acc[i] = f32x4{0.f, 0.f, 0.f, 0.f};
    sa3_mm64<256>(G0h, G0l, w * 64, l, ah, al, acc);
    float xr[4][3];
#pragma unroll
    for (int r = 0; r < 4; ++r) {
      int row = (l >> 4) * 4 + r;
      xr[r][0] = sxyz[row][0]; xr[r][1] = sxyz[row][1]; xr[r][2] = sxyz[row][2];
    }
#pragma unroll
    for (int ct = 0; ct < 4; ++ct) {
      int col = w * 64 + ct * 16 + (l & 15);
      float w0 = W0full[col], w1 = W0full[256 + col], w2 = W0full[512 + col];
      float bia = B0[col];
#pragma unroll
      for (int r = 0; r < 4; ++r) {
        int row = (l >> 4) * 4 + r;
        float v = acc[ct][r] + xr[r][0] * w0 + xr[r][1] * w1 + xr[r][2] * w2 + bia;
        A[row * AS3 + col] = fmaxf(v, 0.f);
      }
    }
    __syncthreads();
  }

  {  // L2: K=256 -> N=512 (wave cols 128)
    bf16x8 ah[8], al[8];
    sa3_frags(A, l, 8, ah, al);
    __syncthreads();
    f32x4 acc[8];
#pragma unroll
    for (int i = 0; i < 8; ++i) acc[i] = f32x4{0.f, 0.f, 0.f, 0.f};
    sa3_mm64<256>(G1h, G1l, w * 128, l, ah, al, acc);
    sa3_mm64<256>(G1h, G1l, w * 128 + 64, l, ah, al, acc + 4);
#pragma unroll
    for (int cc = 0; cc < 8; ++cc) {
      int col = w * 128 + cc * 16 + (l & 15);
      float bia = B1[col];
#pragma unroll
      for (int r = 0; r < 4; ++r) {
        int row = (l >> 4) * 4 + r;
        A[row * AS3 + col] = fmaxf(acc[cc][r] + bia, 0.f);
      }
    }
    __syncthreads();
  }

  {  // L3: K=512 -> N=1024 (wave cols 256), maxpool 16 rows -> partial
    bf16x8 ah[16], al[16];
    sa3_frags(A, l, 16, ah, al);
    float* pout = partial + ((size_t)(b * 8 + rb)) * 1024;
#pragma unroll
    for (int sub = 0; sub < 4; ++sub) {
      f32x4 acc[4];
#pragma unroll
      for (int i = 0; i < 4; ++i) acc[i] = f32x4{0.f, 0.f, 0.f, 0.f};
      sa3_mm64<512>(G2h, G2l, w * 256 + sub * 64, l, ah, al, acc);
#pragma unroll
      for (int ct = 0; ct < 4; ++ct) {
        int col = w * 256 + sub * 64 + ct * 16 + (l & 15);
        float v = fmaxf(fmaxf(acc[ct][0], acc[ct][1]), fmaxf(acc[ct][2], acc[ct][3]));
        v = fmaxf(v, __shfl_xor(v, 16, 64));
        v = fmaxf(v, __shfl_xor(v, 32, 64));
        if (l < 16) pout[col] = v + B2[col];  // relu deferred to heads (monotone)
      }
    }
  }
}

// ---------------------------------------------------------------- heads (8-way partial max + relu + dots)
__global__ __launch_bounds__(256) void heads_kernel(const float* __restrict__ partial,
                                                    const float* __restrict__ cw,
                                                    const float* __restrict__ cb,
                                                    const float* __restrict__ rw,
                                                    const float* __restrict__ rb,
                                                    float* __restrict__ out) {
  const int b = blockIdx.x, t = threadIdx.x;
  const float* pb = partial + (size_t)b * 8 * 1024;
  float a0 = 0, a1 = 0, a2 = 0, a3 = 0, a4 = 0;
  for (int k = t; k < 1024; k += 256) {
    float m = pb[k];
#pragma unroll
    for (int p = 1; p < 8; ++p) m = fmaxf(m, pb[p * 1024 + k]);
    float f = fmaxf(m, 0.f);
    a0 += f * cw[k];
    const float* r = rw + (size_t)k * 4;
    a1 += f * r[0]; a2 += f * r[1]; a3 += f * r[2]; a4 += f * r[3];
  }
#pragma unroll
  for (int m = 32; m >= 1; m >>= 1) {
    a0 += __shfl_xor(a0, m, 64); a1 += __shfl_xor(a1, m, 64);
    a2 += __shfl_xor(a2, m, 64); a3 += __shfl_xor(a3, m, 64);
    a4 += __shfl_xor(a4, m, 64);
  }
  __shared__ float red[4][5];
  const int wv = t >> 6, ln = t & 63;
  if (ln == 0) { red[wv][0] = a0; red[wv][1] = a1; red[wv][2] = a2; red[wv][3] = a3; red[wv][4] = a4; }
  __syncthreads();
  if (t == 0) {
    float s0 = red[0][0] + red[1][0] + red[2][0] + red[3][0];
    float s1 = red[0][1] + red[1][1] + red[2][1] + red[3][1];
    float s2 = red[0][2] + red[1][2] + red[2][2] + red[3][2];
    float s3 = red[0][3] + red[1][3] + red[2][3] + red[3][3];
    float s4 = red[0][4] + red[1][4] + red[2][4] + red[3][4];
    out[b] = s0 + cb[0];
    out[32 + b * 4 + 0] = s1 + rb[0];
    out[32 + b * 4 + 1] = s2 + rb[1];
    out[32 + b * 4 + 2] = s3 + rb[2];
    out[32 + b * 4 + 3] = s4 + rb[3];
  }
}

// ---------------------------------------------------------------- launch
extern "C" void kernel_launch(void* const* d_in, const int* in_sizes, int n_in,
                              void* d_out, int out_size, void* d_ws, size_t ws_size,
                              hipStream_t stream) {
  (void)in_sizes; (void)n_in; (void)out_size; (void)ws_size;
  const float* xyz  = (const float*)d_in[0];
  const float* s1w0 = (const float*)d_in[1];  const float* s1b0 = (const float*)d_in[2];
  const float* s1w1 = (const float*)d_in[3];  const float* s1b1 = (const float*)d_in[4];
  const float* s1w2 = (const float*)d_in[5];  const float* s1b2 = (const float*)d_in[6];
  const float* s2w0 = (const float*)d_in[7];  const float* s2b0 = (const float*)d_in[8];
  const float* s2w1 = (const float*)d_in[9];  const float* s2b1 = (const float*)d_in[10];
  const float* s2w2 = (const float*)d_in[11]; const float* s2b2 = (const float*)d_in[12];
  const float* s3w0 = (const float*)d_in[13]; const float* s3b0 = (const float*)d_in[14];
  const float* s3w1 = (const float*)d_in[15]; const float* s3b1 = (const float*)d_in[16];
  const float* s3w2 = (const float*)d_in[17]; const float* s3b2 = (const float*)d_in[18];
  const float* clsw = (const float*)d_in[19]; const float* clsb = (const float*)d_in[20];
  const float* regw = (const float*)d_in[21]; const float* regb = (const float*)d_in[22];

  char* ws = (char*)d_ws;
  float* nx1   = (float*)(ws + 0);          // 32*512*3
  int*   gidx1 = (int*)  (ws + 196608);     // 32*512*32
  float* f1    = (float*)(ws + 2293760);    // 32*512*128
  float* nx2   = (float*)(ws + 10682368);   // 32*128*3
  int*   gidx2 = (int*)  (ws + 10731520);   // 32*128*64
  float* f2    = (float*)(ws + 11780096);   // 32*128*256

  // SA1/SA2 prepped weights (u16 hi/lo, transposed [n][k])
  unsigned short* wt = (unsigned short*)(ws + 20168704);
  unsigned short* g11h = wt;            // 64*64
  unsigned short* g11l = wt + 4096;
  unsigned short* g12h = wt + 8192;     // 128*64
  unsigned short* g12l = wt + 16384;
  unsigned short* g20h = wt + 24576;    // 128*128 (rows 3..130 of s2w0)
  unsigned short* g20l = wt + 40960;
  unsigned short* g21h = wt + 57344;    // 128*128
  unsigned short* g21l = wt + 73728;
  unsigned short* g22h = wt + 90112;    // 256*128
  unsigned short* g22l = wt + 122880;   // ends at byte 20168704+311296 = 20480000
  // SA3 prepped weights
  unsigned short* g30h = (unsigned short*)(ws + 20480000);  // 256x256
  unsigned short* g30l = (unsigned short*)(ws + 20611072);
  unsigned short* g31h = (unsigned short*)(ws + 20742144);  // 512x256
  unsigned short* g31l = (unsigned short*)(ws + 21004288);
  unsigned short* g32h = (unsigned short*)(ws + 21266432);  // 1024x512
  unsigned short* g32l = (unsigned short*)(ws + 22315008);
  float* partial = (float*)(ws + 23363584);                 // 32*8*1024 f32 -> ends 24412160

  const float r21 = (float)(0.2 * 0.2);
  const float r22 = (float)(0.4 * 0.4);

  WPTab tab;
  int off = 0;
  auto set = [&](int i, const float* W, unsigned short* hi, unsigned short* lo,
                 int K, int N, int row0) {
    tab.e[i] = WPEnt{W, hi, lo, K, N, row0, off, off + K * N};
    off += K * N;
  };
  set(0, s1w1, g11h, g11l, 64, 64, 0);
  set(1, s1w2, g12h, g12l, 64, 128, 0);
  set(2, s2w0, g20h, g20l, 128, 128, 3);
  set(3, s2w1, g21h, g21l, 128, 128, 0);
  set(4, s2w2, g22h, g22l, 128, 256, 0);
  set(5, s3w0, g30h, g30l, 256, 256, 3);
  set(6, s3w1, g31h, g31l, 256, 512, 0);
  set(7, s3w2, g32h, g32l, 512, 1024, 0);
  const int wblocks = (off + 255) / 256;

  fps1_wprep_kernel<<<32 + wblocks, 256, 0, stream>>>(xyz, nx1, tab);
  fps2_bq1_kernel<<<32 + 4096, 256, 0, stream>>>(xyz, nx1, gidx1, nx2, r21);
  bq2_sa1_kernel<<<1024 + 2048, 256, 0, stream>>>(
      xyz, nx1, nx2, gidx2, r22, gidx1,
      s1w0, s1b0, g11h, g11l, s1b1, g12h, g12l, s1b2, f1);
  sa2_kernel<512, 128, 64, 2, 128, 128, 128, 256><<<2048, 512, 0, stream>>>(
      nx1, nx2, gidx2, f1, s2w0, s2b0,
      g20h, g20l, g21h, g21l, s2b1, g22h, g22l, s2b2, f2);
  sa3f_kernel<<<256, 256, 0, stream>>>(nx2, f2, s3w0, g30h, g30l, s3b0,
                                       g31h, g31l, s3b1, g32h, g32l, s3b2, partial);
  heads_kernel<<<32, 256, 0, stream>>>(partial, clsw, clsb, regw, regb, (float*)d_out);
}